// Round 5
// baseline (12555.175 us; speedup 1.0000x reference)
//
#include <hip/hip_runtime.h>

#define B_ 4
#define S_ 4096
#define D_ 512
#define H_ 8
#define L_ 6
#define M_ 2048
#define DH_ 64
#define NC_ 64   // number of chunks = S/C
#define C_ 64    // chunk length

// ---------------------------------------------------------------------------
// Embedding + sinusoidal positional encoding (f64 PE recipe — r3 fix)
// ---------------------------------------------------------------------------
__global__ __launch_bounds__(128) void embed_kernel(const int* __restrict__ tokens,
                                                    const float* __restrict__ emb,
                                                    float* __restrict__ x) {
  int row = blockIdx.x;            // b*S + s
  int s = row & (S_ - 1);
  int tok = tokens[row];
  const float4* e = (const float4*)(emb + (size_t)tok * D_);
  float4* xo = (float4*)(x + (size_t)row * D_);
  int t = threadIdx.x;             // 128 threads, 4 floats each
  float4 ev = e[t];
  int d0 = t * 4;
  const double c64 = -9.210340371976184 / 255.0;   // -ln(10000)/(half-1)
  float pe[4];
#pragma unroll
  for (int j = 0; j < 4; j++) {
    int d = d0 + j;
    int i = (d < 256) ? d : d - 256;
    double freq = exp((double)i * c64);
    double arg = (double)s * freq;
    pe[j] = (d < 256) ? (float)sin(arg) : (float)cos(arg);
  }
  float4 o;
  o.x = ev.x + pe[0];
  o.y = ev.y + pe[1];
  o.z = ev.z + pe[2];
  o.w = ev.w + pe[3];
  xo[t] = o;
}

// ---------------------------------------------------------------------------
// LayerNorm: one 64-thread wave per row of D=512
// ---------------------------------------------------------------------------
__global__ __launch_bounds__(64) void ln_kernel(const float* __restrict__ in,
                                                float* __restrict__ out,
                                                const float* __restrict__ sc,
                                                const float* __restrict__ bi) {
  int row = blockIdx.x;
  const float4* ir = (const float4*)(in + (size_t)row * D_);
  int t = threadIdx.x;
  float4 a = ir[t];
  float4 b4 = ir[t + 64];
  float sum = a.x + a.y + a.z + a.w + b4.x + b4.y + b4.z + b4.w;
  float sq  = a.x*a.x + a.y*a.y + a.z*a.z + a.w*a.w
            + b4.x*b4.x + b4.y*b4.y + b4.z*b4.z + b4.w*b4.w;
#pragma unroll
  for (int m = 1; m < 64; m <<= 1) {
    sum += __shfl_xor(sum, m);
    sq  += __shfl_xor(sq, m);
  }
  float mean = sum * (1.0f / 512.0f);
  float var  = sq * (1.0f / 512.0f) - mean * mean;
  float rstd = 1.0f / sqrtf(var + 1e-6f);
  float4 s1 = ((const float4*)sc)[t], s2 = ((const float4*)sc)[t + 64];
  float4 g1 = ((const float4*)bi)[t], g2 = ((const float4*)bi)[t + 64];
  float4 o1, o2;
  o1.x = (a.x - mean) * rstd * s1.x + g1.x;
  o1.y = (a.y - mean) * rstd * s1.y + g1.y;
  o1.z = (a.z - mean) * rstd * s1.z + g1.z;
  o1.w = (a.w - mean) * rstd * s1.w + g1.w;
  o2.x = (b4.x - mean) * rstd * s2.x + g2.x;
  o2.y = (b4.y - mean) * rstd * s2.y + g2.y;
  o2.z = (b4.z - mean) * rstd * s2.z + g2.z;
  o2.w = (b4.w - mean) * rstd * s2.w + g2.w;
  float4* orow = (float4*)(out + (size_t)row * D_);
  orow[t] = o1;
  orow[t + 64] = o2;
}

// ---------------------------------------------------------------------------
// f32 tiled GEMM: C[M,N] = op(A[M,K] @ W[K,N] + bias) (+ C residual)
// 128x128 tile, 256 threads, 8x8 micro-tile as 2x2 quadrants of 4x4.
// Quadrant layout: As reads broadcast per wave; Bs reads 2-way (free).
// ---------------------------------------------------------------------------
__device__ __forceinline__ float gelu_f(float v) {
  float v3 = v * v * v;
  return 0.5f * v * (1.0f + tanhf(0.7978845608028654f * (v + 0.044715f * v3)));
}

template <int HAS_BIAS, int RESID, int DO_GELU>
__global__ __launch_bounds__(256) void gemm_kernel(const float* __restrict__ A,
                                                   const float* __restrict__ W,
                                                   const float* __restrict__ bias,
                                                   float* __restrict__ C,
                                                   int M, int N, int K) {
  __shared__ float As[16][132];   // [k][m], padded
  __shared__ float Bs[16][132];   // [k][n], padded
  int tid = threadIdx.x;
  int bn = blockIdx.x, bm = blockIdx.y;
  int row0 = bm * 128, col0 = bn * 128;
  int tr = tid >> 4, tc = tid & 15;       // 16x16 threads
  float acc[2][2][4][4] = {};             // [mq][nq][i][j]

  int la_r = tid >> 1;               // 0..127  A row within tile
  int la_c = (tid & 1) * 8;          // 0 or 8
  int lb_r = tid >> 4;               // 0..15   B row within tile
  int lb_c = (tid & 15) * 8;         // 0..120

  for (int k0 = 0; k0 < K; k0 += 16) {
    const float* ap = A + (size_t)(row0 + la_r) * K + k0 + la_c;
    float4 a0 = *(const float4*)ap;
    float4 a1 = *(const float4*)(ap + 4);
    As[la_c + 0][la_r] = a0.x;
    As[la_c + 1][la_r] = a0.y;
    As[la_c + 2][la_r] = a0.z;
    As[la_c + 3][la_r] = a0.w;
    As[la_c + 4][la_r] = a1.x;
    As[la_c + 5][la_r] = a1.y;
    As[la_c + 6][la_r] = a1.z;
    As[la_c + 7][la_r] = a1.w;
    const float* wp = W + (size_t)(k0 + lb_r) * N + col0 + lb_c;
    *(float4*)&Bs[lb_r][lb_c] = *(const float4*)wp;
    *(float4*)&Bs[lb_r][lb_c + 4] = *(const float4*)(wp + 4);
    __syncthreads();
#pragma unroll
    for (int kk = 0; kk < 16; kk++) {
      float4 amq[2], bnq[2];
      amq[0] = *(const float4*)&As[kk][tr * 4];
      amq[1] = *(const float4*)&As[kk][64 + tr * 4];
      bnq[0] = *(const float4*)&Bs[kk][tc * 4];
      bnq[1] = *(const float4*)&Bs[kk][64 + tc * 4];
#pragma unroll
      for (int mq = 0; mq < 2; mq++) {
        float a0 = amq[mq].x, a1 = amq[mq].y, a2 = amq[mq].z, a3 = amq[mq].w;
#pragma unroll
        for (int nq = 0; nq < 2; nq++) {
          float b0 = bnq[nq].x, b1 = bnq[nq].y, b2 = bnq[nq].z, b3 = bnq[nq].w;
          acc[mq][nq][0][0] += a0 * b0; acc[mq][nq][0][1] += a0 * b1;
          acc[mq][nq][0][2] += a0 * b2; acc[mq][nq][0][3] += a0 * b3;
          acc[mq][nq][1][0] += a1 * b0; acc[mq][nq][1][1] += a1 * b1;
          acc[mq][nq][1][2] += a1 * b2; acc[mq][nq][1][3] += a1 * b3;
          acc[mq][nq][2][0] += a2 * b0; acc[mq][nq][2][1] += a2 * b1;
          acc[mq][nq][2][2] += a2 * b2; acc[mq][nq][2][3] += a2 * b3;
          acc[mq][nq][3][0] += a3 * b0; acc[mq][nq][3][1] += a3 * b1;
          acc[mq][nq][3][2] += a3 * b2; acc[mq][nq][3][3] += a3 * b3;
        }
      }
    }
    __syncthreads();
  }

  float4 bq[2] = {{0.f,0.f,0.f,0.f},{0.f,0.f,0.f,0.f}};
  if (HAS_BIAS) {
    bq[0] = *(const float4*)(bias + col0 + tc * 4);
    bq[1] = *(const float4*)(bias + col0 + 64 + tc * 4);
  }
#pragma unroll
  for (int mq = 0; mq < 2; mq++) {
#pragma unroll
    for (int i = 0; i < 4; i++) {
      int row = row0 + mq * 64 + tr * 4 + i;
#pragma unroll
      for (int nq = 0; nq < 2; nq++) {
        float* cp = C + (size_t)row * N + col0 + nq * 64 + tc * 4;
        float4 vv;
        vv.x = acc[mq][nq][i][0]; vv.y = acc[mq][nq][i][1];
        vv.z = acc[mq][nq][i][2]; vv.w = acc[mq][nq][i][3];
        if (HAS_BIAS) { vv.x += bq[nq].x; vv.y += bq[nq].y; vv.z += bq[nq].z; vv.w += bq[nq].w; }
        if (DO_GELU) { vv.x = gelu_f(vv.x); vv.y = gelu_f(vv.y); vv.z = gelu_f(vv.z); vv.w = gelu_f(vv.w); }
        if (RESID) {
          float4 old = *(const float4*)cp;
          vv.x += old.x; vv.y += old.y; vv.z += old.z; vv.w += old.w;
        }
        *(float4*)cp = vv;
      }
    }
  }
}

// ---------------------------------------------------------------------------
// rotW2[d][h*32+j] = sum_f Wq[d][h*64+f] * rot[h][f][j]  (f64 acc, f32 store)
// ---------------------------------------------------------------------------
__global__ __launch_bounds__(256) void rotw_kernel(const float* __restrict__ Wq,
                                                   const float* __restrict__ rot,
                                                   float* __restrict__ rotW2) {
  int idx = blockIdx.x * 256 + threadIdx.x;   // d*256 + h*32 + j, 512*256 total
  int n = idx & 255;
  int d = idx >> 8;
  int h = n >> 5;
  int j = n & 31;
  double a = 0.0;
#pragma unroll 8
  for (int f = 0; f < 64; f++) {
    a += (double)Wq[(size_t)d * D_ + h * 64 + f] * (double)rot[((size_t)h * 64 + f) * 32 + j];
  }
  rotW2[idx] = (float)a;
}

// ---------------------------------------------------------------------------
// Per-token bucket argmax over [r, -r] (first-index ties, like np.argmax).
// ---------------------------------------------------------------------------
__global__ __launch_bounds__(256) void argmax_kernel(const float* __restrict__ rbuf,
                                                     int* __restrict__ buckets) {
  int gid = blockIdx.x * 256 + threadIdx.x;   // b*H*S + h*S + s
  int s = gid & (S_ - 1);
  int bh = gid >> 12;
  int h = bh & (H_ - 1);
  int b = bh >> 3;
  const float* rp = rbuf + ((size_t)b * S_ + s) * 256 + h * 32;
  float r[32];
#pragma unroll
  for (int j4 = 0; j4 < 8; j4++) {
    float4 t4 = *(const float4*)(rp + j4 * 4);
    r[j4 * 4 + 0] = t4.x; r[j4 * 4 + 1] = t4.y;
    r[j4 * 4 + 2] = t4.z; r[j4 * 4 + 3] = t4.w;
  }
  float best = r[0];
  int bi = 0;
#pragma unroll
  for (int j = 1; j < 64; j++) {
    float val = (j < 32) ? r[j] : -r[j - 32];
    if (val > best) { best = val; bi = j; }
  }
  buckets[gid] = bi;
}

// ---------------------------------------------------------------------------
// Stable counting sort by bucket (== argsort(bucket*S + pos)).
// ---------------------------------------------------------------------------
__global__ __launch_bounds__(64) void sort_kernel(const int* __restrict__ buckets,
                                                  int* __restrict__ st) {
  __shared__ int hist[64][64];   // [thread][bucket]
  __shared__ int boff[64];
  int bh = blockIdx.x;
  const int* bk = buckets + (size_t)bh * S_;
  int* stb = st + (size_t)bh * S_;
  int t = threadIdx.x;
  for (int j = 0; j < 64; j++) hist[t][j] = 0;
  __syncthreads();
  for (int i = 0; i < 64; i++) {
    int s = t * 64 + i;
    hist[t][bk[s]]++;
  }
  __syncthreads();
  int run = 0;
  for (int tt = 0; tt < 64; tt++) {
    int c = hist[tt][t];
    hist[tt][t] = run;
    run += c;
  }
  boff[t] = run;
  __syncthreads();
  if (t == 0) {
    int acc = 0;
    for (int j = 0; j < 64; j++) { int c = boff[j]; boff[j] = acc; acc += c; }
  }
  __syncthreads();
  for (int i = 0; i < 64; i++) {
    int s = t * 64 + i;
    int bkt = bk[s];
    int pos = boff[bkt] + hist[t][bkt];
    hist[t][bkt] = hist[t][bkt] + 1;
    stb[pos] = s;
  }
}

// ---------------------------------------------------------------------------
// Chunked shared-QK attention. One block per (b,h,chunk).
// Keys: chunk n plus chunk n-1 (wrap). 64 queries x 128 keys.
// Bank-conflict fixes: pad rows to 68 floats; interleaved sub->key mapping
// (k = kk*4 + sub) so the 4 concurrent key rows are consecutive (distinct
// bank phases) instead of 32 apart (identical phase for any stride).
// ---------------------------------------------------------------------------
__global__ __launch_bounds__(256) void attn_kernel(const float* __restrict__ q,
                                                   const float* __restrict__ v,
                                                   const int* __restrict__ st,
                                                   float* __restrict__ o) {
  __shared__ float Ksh[128][68];
  __shared__ float Vsh[128][68];
  int blk = blockIdx.x;
  int n = blk & (NC_ - 1);
  int bh = blk >> 6;
  int h = bh & (H_ - 1);
  int b = bh >> 3;
  const int* stbh = st + (size_t)bh * S_;
  int tid = threadIdx.x;
  int pn = (n + NC_ - 1) & (NC_ - 1);
  for (int i = tid; i < 128 * 16; i += 256) {
    int r = i >> 4, c4 = i & 15;
    int si = (r < 64) ? (n * 64 + r) : (pn * 64 + (r - 64));
    int p = stbh[si];
    size_t base = ((size_t)b * S_ + p) * D_ + h * 64;
    ((float4*)Ksh[r])[c4] = *(const float4*)(q + base + c4 * 4);
    ((float4*)Vsh[r])[c4] = *(const float4*)(v + base + c4 * 4);
  }
  __syncthreads();
  int r = tid >> 2, sub = tid & 3;
  float qr[64];
#pragma unroll
  for (int f4 = 0; f4 < 16; f4++) {
    float4 t4 = ((const float4*)Ksh[r])[f4];
    qr[f4 * 4 + 0] = t4.x; qr[f4 * 4 + 1] = t4.y;
    qr[f4 * 4 + 2] = t4.z; qr[f4 * 4 + 3] = t4.w;
  }
  float lg[32];
  float mx = -1e30f;
#pragma unroll
  for (int kk = 0; kk < 32; kk++) {
    int k = kk * 4 + sub;
    float sdot = 0.f;
#pragma unroll
    for (int f4 = 0; f4 < 16; f4++) {
      float4 kv = ((const float4*)Ksh[k])[f4];
      sdot += qr[f4 * 4 + 0] * kv.x + qr[f4 * 4 + 1] * kv.y
            + qr[f4 * 4 + 2] * kv.z + qr[f4 * 4 + 3] * kv.w;
    }
    sdot *= 0.125f;
    lg[kk] = sdot;
    mx = fmaxf(mx, sdot);
  }
  mx = fmaxf(mx, __shfl_xor(mx, 1));
  mx = fmaxf(mx, __shfl_xor(mx, 2));
  float ssum = 0.f;
#pragma unroll
  for (int kk = 0; kk < 32; kk++) {
    float p = expf(lg[kk] - mx);
    lg[kk] = p;
    ssum += p;
  }
  ssum += __shfl_xor(ssum, 1);
  ssum += __shfl_xor(ssum, 2);
  float acc[64];
#pragma unroll
  for (int f = 0; f < 64; f++) acc[f] = 0.f;
#pragma unroll
  for (int kk = 0; kk < 32; kk++) {
    int k = kk * 4 + sub;
    float w = lg[kk];
#pragma unroll
    for (int f4 = 0; f4 < 16; f4++) {
      float4 vv = ((const float4*)Vsh[k])[f4];
      acc[f4 * 4 + 0] += w * vv.x;
      acc[f4 * 4 + 1] += w * vv.y;
      acc[f4 * 4 + 2] += w * vv.z;
      acc[f4 * 4 + 3] += w * vv.w;
    }
  }
  // reduce-scatter across the 4 sub-lanes (static register indices only)
  float red[32];
#pragma unroll
  for (int j = 0; j < 32; j++) {
    float lo = acc[j], hi = acc[32 + j];
    float keep = (sub & 1) ? hi : lo;
    float send = (sub & 1) ? lo : hi;
    red[j] = keep + __shfl_xor(send, 1);
  }
  float red2[16];
#pragma unroll
  for (int j = 0; j < 16; j++) {
    float lo = red[j], hi = red[16 + j];
    float keep = (sub & 2) ? hi : lo;
    float send = (sub & 2) ? lo : hi;
    red2[j] = keep + __shfl_xor(send, 2);
  }
  int seg = (sub & 1) * 32 + (sub & 2) * 8;   // 0->0, 1->32, 2->16, 3->48
  float inv = 1.0f / ssum;
  int p = stbh[n * 64 + r];
  float* orow = o + ((size_t)b * S_ + p) * D_ + h * 64 + seg;
#pragma unroll
  for (int f4 = 0; f4 < 4; f4++) {
    float4 w4;
    w4.x = red2[f4 * 4 + 0] * inv;
    w4.y = red2[f4 * 4 + 1] * inv;
    w4.z = red2[f4 * 4 + 2] * inv;
    w4.w = red2[f4 * 4 + 3] * inv;
    *(float4*)(orow + f4 * 4) = w4;
  }
}

// ---------------------------------------------------------------------------
extern "C" void kernel_launch(void* const* d_in, const int* in_sizes, int n_in,
                              void* d_out, int out_size, void* d_ws, size_t ws_size,
                              hipStream_t stream) {
  const int*   tokens = (const int*)d_in[0];
  const float* emb    = (const float*)d_in[1];
  const float* rot    = (const float*)d_in[2];
  const float* ln1_s  = (const float*)d_in[3];
  const float* ln1_b  = (const float*)d_in[4];
  const float* Wq     = (const float*)d_in[5];
  const float* Wv     = (const float*)d_in[6];
  const float* Wo     = (const float*)d_in[7];
  const float* ln2_s  = (const float*)d_in[8];
  const float* ln2_b  = (const float*)d_in[9];
  const float* W1     = (const float*)d_in[10];
  const float* b1     = (const float*)d_in[11];
  const float* W2     = (const float*)d_in[12];
  const float* b2     = (const float*)d_in[13];
  const float* lnf_s  = (const float*)d_in[14];
  const float* lnf_b  = (const float*)d_in[15];

  float* x = (float*)d_out;                  // residual stream lives in d_out
  float* ws = (float*)d_ws;
  const size_t RS = (size_t)B_ * S_ * D_;    // 8388608
  float* hbuf = ws;
  float* qbuf = hbuf + RS;
  float* vbuf = qbuf + RS;
  float* obuf = vbuf + RS;
  float* mid  = obuf + RS;                   // 4096*2048 chunk (FFN phase)
  float* rbuf = mid;                         // hash scores [16384][256] (aliases mid)
  int* buckets = (int*)(mid + (size_t)4096 * M_);
  int* stbuf   = buckets + B_ * H_ * S_;
  float* rotW2 = (float*)(stbuf + B_ * H_ * S_);   // [512][256] f32 fused hash weight

  const int rows = B_ * S_;                  // 16384

  embed_kernel<<<rows, 128, 0, stream>>>(tokens, emb, x);

  for (int l = 0; l < L_; l++) {
    ln_kernel<<<rows, 64, 0, stream>>>(x, hbuf, ln1_s + (size_t)l * D_, ln1_b + (size_t)l * D_);

    dim3 g1(D_ / 128, rows / 128);
    gemm_kernel<0, 0, 0><<<g1, 256, 0, stream>>>(hbuf, Wq + (size_t)l * D_ * D_, nullptr, qbuf, rows, D_, D_);
    gemm_kernel<0, 0, 0><<<g1, 256, 0, stream>>>(hbuf, Wv + (size_t)l * D_ * D_, nullptr, vbuf, rows, D_, D_);

    rotw_kernel<<<(D_ * 256) / 256, 256, 0, stream>>>(Wq + (size_t)l * D_ * D_,
                                                      rot + (size_t)l * H_ * DH_ * 32, rotW2);
    dim3 gh(256 / 128, rows / 128);
    gemm_kernel<0, 0, 0><<<gh, 256, 0, stream>>>(hbuf, rotW2, nullptr, rbuf, rows, 256, D_);
    argmax_kernel<<<(B_ * H_ * S_) / 256, 256, 0, stream>>>(rbuf, buckets);
    sort_kernel<<<B_ * H_, 64, 0, stream>>>(buckets, stbuf);
    attn_kernel<<<B_ * H_ * NC_, 256, 0, stream>>>(qbuf, vbuf, stbuf, obuf);

    gemm_kernel<0, 1, 0><<<g1, 256, 0, stream>>>(obuf, Wo + (size_t)l * D_ * D_, nullptr, x, rows, D_, D_);

    ln_kernel<<<rows, 64, 0, stream>>>(x, hbuf, ln2_s + (size_t)l * D_, ln2_b + (size_t)l * D_);

    for (int c = 0; c < 4; c++) {
      dim3 gf1(M_ / 128, 4096 / 128);
      gemm_kernel<1, 0, 1><<<gf1, 256, 0, stream>>>(hbuf + (size_t)c * 4096 * D_,
                                                    W1 + (size_t)l * D_ * M_, b1 + (size_t)l * M_,
                                                    mid, 4096, M_, D_);
      dim3 gf2(D_ / 128, 4096 / 128);
      gemm_kernel<1, 1, 0><<<gf2, 256, 0, stream>>>(mid,
                                                    W2 + (size_t)l * M_ * D_, b2 + (size_t)l * D_,
                                                    x + (size_t)c * 4096 * D_, 4096, D_, M_);
    }
  }

  ln_kernel<<<rows, 64, 0, stream>>>(x, x, lnf_s, lnf_b);
}

// Round 6
// 4854.535 us; speedup vs baseline: 2.5863x; 2.5863x over previous
//
#include <hip/hip_runtime.h>

#define B_ 4
#define S_ 4096
#define D_ 512
#define H_ 8
#define L_ 6
#define M_ 2048
#define DH_ 64
#define NC_ 64   // number of chunks = S/C
#define C_ 64    // chunk length

typedef _Float16 half8 __attribute__((ext_vector_type(8)));
typedef float f32x4 __attribute__((ext_vector_type(4)));

// ---------------------------------------------------------------------------
// Embedding + sinusoidal positional encoding (f64 PE recipe — r3 fix)
// ---------------------------------------------------------------------------
__global__ __launch_bounds__(128) void embed_kernel(const int* __restrict__ tokens,
                                                    const float* __restrict__ emb,
                                                    float* __restrict__ x) {
  int row = blockIdx.x;            // b*S + s
  int s = row & (S_ - 1);
  int tok = tokens[row];
  const float4* e = (const float4*)(emb + (size_t)tok * D_);
  float4* xo = (float4*)(x + (size_t)row * D_);
  int t = threadIdx.x;             // 128 threads, 4 floats each
  float4 ev = e[t];
  int d0 = t * 4;
  const double c64 = -9.210340371976184 / 255.0;   // -ln(10000)/(half-1)
  float pe[4];
#pragma unroll
  for (int j = 0; j < 4; j++) {
    int d = d0 + j;
    int i = (d < 256) ? d : d - 256;
    double freq = exp((double)i * c64);
    double arg = (double)s * freq;
    pe[j] = (d < 256) ? (float)sin(arg) : (float)cos(arg);
  }
  float4 o;
  o.x = ev.x + pe[0];
  o.y = ev.y + pe[1];
  o.z = ev.z + pe[2];
  o.w = ev.w + pe[3];
  xo[t] = o;
}

// ---------------------------------------------------------------------------
// LayerNorm: one 64-thread wave per row of D=512
// ---------------------------------------------------------------------------
__global__ __launch_bounds__(64) void ln_kernel(const float* __restrict__ in,
                                                float* __restrict__ out,
                                                const float* __restrict__ sc,
                                                const float* __restrict__ bi) {
  int row = blockIdx.x;
  const float4* ir = (const float4*)(in + (size_t)row * D_);
  int t = threadIdx.x;
  float4 a = ir[t];
  float4 b4 = ir[t + 64];
  float sum = a.x + a.y + a.z + a.w + b4.x + b4.y + b4.z + b4.w;
  float sq  = a.x*a.x + a.y*a.y + a.z*a.z + a.w*a.w
            + b4.x*b4.x + b4.y*b4.y + b4.z*b4.z + b4.w*b4.w;
#pragma unroll
  for (int m = 1; m < 64; m <<= 1) {
    sum += __shfl_xor(sum, m);
    sq  += __shfl_xor(sq, m);
  }
  float mean = sum * (1.0f / 512.0f);
  float var  = sq * (1.0f / 512.0f) - mean * mean;
  float rstd = 1.0f / sqrtf(var + 1e-6f);
  float4 s1 = ((const float4*)sc)[t], s2 = ((const float4*)sc)[t + 64];
  float4 g1 = ((const float4*)bi)[t], g2 = ((const float4*)bi)[t + 64];
  float4 o1, o2;
  o1.x = (a.x - mean) * rstd * s1.x + g1.x;
  o1.y = (a.y - mean) * rstd * s1.y + g1.y;
  o1.z = (a.z - mean) * rstd * s1.z + g1.z;
  o1.w = (a.w - mean) * rstd * s1.w + g1.w;
  o2.x = (b4.x - mean) * rstd * s2.x + g2.x;
  o2.y = (b4.y - mean) * rstd * s2.y + g2.y;
  o2.z = (b4.z - mean) * rstd * s2.z + g2.z;
  o2.w = (b4.w - mean) * rstd * s2.w + g2.w;
  float4* orow = (float4*)(out + (size_t)row * D_);
  orow[t] = o1;
  orow[t + 64] = o2;
}

__device__ __forceinline__ float gelu_f(float v) {
  float v3 = v * v * v;
  return 0.5f * v * (1.0f + tanhf(0.7978845608028654f * (v + 0.044715f * v3)));
}

// ---------------------------------------------------------------------------
// fp16x3 split MFMA GEMM: C[M,N] = op(A @ W + bias) (+ C residual)
// 128x128 tile, BK=32, 4 waves (2x2 of 64x64). a = a_hi + a_lo in fp16;
// A@W ~= Ah Bh + Ah Bl + Al Bh (f32 accumulate) — rel err ~2^-21, f32-class.
// Layouts (HW-verified m89): A row=lane&15,k=(lane>>4)*8+j; B col=lane&15,
// same k; D col=lane&15,row=(lane>>4)*4+reg. LDS stride 40 fp16 (80 B:
// 16B-aligned b128 reads, ~2-way banks).
// ---------------------------------------------------------------------------
template <int HAS_BIAS, int RESID, int DO_GELU>
__global__ __launch_bounds__(256) void gemm_mfma(const float* __restrict__ A,
                                                 const float* __restrict__ W,
                                                 const float* __restrict__ bias,
                                                 float* __restrict__ C,
                                                 int M, int N, int K) {
  __shared__ _Float16 As_hi[128 * 40];
  __shared__ _Float16 As_lo[128 * 40];
  __shared__ _Float16 Bs_hi[128 * 40];
  __shared__ _Float16 Bs_lo[128 * 40];
  int tid = threadIdx.x;
  int row0 = blockIdx.y * 128, col0 = blockIdx.x * 128;
  int lane = tid & 63, wid = tid >> 6;
  int wm = wid >> 1, wn = wid & 1;
  int fr = lane & 15, fk = (lane >> 4) * 8;

  int arow = tid >> 1, akc = (tid & 1) * 16;   // A stage: row, k-offset
  int bk = tid >> 3, bc = (tid & 7) * 16;      // B stage: k-row, col-offset

  const float* aptr = A + (size_t)(row0 + arow) * K + akc;
  const float* wptr = W + (size_t)bk * N + col0 + bc;

  f32x4 acc[4][4];
#pragma unroll
  for (int m = 0; m < 4; m++)
#pragma unroll
    for (int n = 0; n < 4; n++) acc[m][n] = (f32x4){0.f, 0.f, 0.f, 0.f};

  float4 Ar[4], Wr[4];
  {
    const float4* ap = (const float4*)aptr;
    Ar[0] = ap[0]; Ar[1] = ap[1]; Ar[2] = ap[2]; Ar[3] = ap[3];
    const float4* wp = (const float4*)wptr;
    Wr[0] = wp[0]; Wr[1] = wp[1]; Wr[2] = wp[2]; Wr[3] = wp[3];
  }

  int nst = K >> 5;
  for (int s = 0; s < nst; ++s) {
    __syncthreads();
    // ---- convert + write LDS (A: vector rows; B: transposed scatter) ----
    {
      float av[16] = {Ar[0].x, Ar[0].y, Ar[0].z, Ar[0].w,
                      Ar[1].x, Ar[1].y, Ar[1].z, Ar[1].w,
                      Ar[2].x, Ar[2].y, Ar[2].z, Ar[2].w,
                      Ar[3].x, Ar[3].y, Ar[3].z, Ar[3].w};
      half8 h0, h1, l0, l1;
#pragma unroll
      for (int j = 0; j < 8; j++) {
        _Float16 h = (_Float16)av[j];
        h0[j] = h; l0[j] = (_Float16)(av[j] - (float)h);
      }
#pragma unroll
      for (int j = 0; j < 8; j++) {
        _Float16 h = (_Float16)av[8 + j];
        h1[j] = h; l1[j] = (_Float16)(av[8 + j] - (float)h);
      }
      *(half8*)&As_hi[arow * 40 + akc] = h0;
      *(half8*)&As_hi[arow * 40 + akc + 8] = h1;
      *(half8*)&As_lo[arow * 40 + akc] = l0;
      *(half8*)&As_lo[arow * 40 + akc + 8] = l1;

      float wv[16] = {Wr[0].x, Wr[0].y, Wr[0].z, Wr[0].w,
                      Wr[1].x, Wr[1].y, Wr[1].z, Wr[1].w,
                      Wr[2].x, Wr[2].y, Wr[2].z, Wr[2].w,
                      Wr[3].x, Wr[3].y, Wr[3].z, Wr[3].w};
#pragma unroll
      for (int i = 0; i < 16; i++) {
        _Float16 h = (_Float16)wv[i];
        Bs_hi[(bc + i) * 40 + bk] = h;
        Bs_lo[(bc + i) * 40 + bk] = (_Float16)(wv[i] - (float)h);
      }
    }
    __syncthreads();
    // ---- prefetch next stage's globals (overlaps with MFMA below) ----
    if (s + 1 < nst) {
      const float4* ap = (const float4*)(aptr + (s + 1) * 32);
      Ar[0] = ap[0]; Ar[1] = ap[1]; Ar[2] = ap[2]; Ar[3] = ap[3];
      const float4* wp = (const float4*)(wptr + (size_t)(s + 1) * 32 * N);
      Wr[0] = wp[0]; Wr[1] = wp[1]; Wr[2] = wp[2]; Wr[3] = wp[3];
    }
    // ---- MFMA: 16 frag-pairs x 3 split products ----
    half8 bh[4], bl[4];
#pragma unroll
    for (int n = 0; n < 4; n++) {
      int col = wn * 64 + n * 16 + fr;
      bh[n] = *(half8*)&Bs_hi[col * 40 + fk];
      bl[n] = *(half8*)&Bs_lo[col * 40 + fk];
    }
#pragma unroll
    for (int m = 0; m < 4; m++) {
      int row = wm * 64 + m * 16 + fr;
      half8 ah = *(half8*)&As_hi[row * 40 + fk];
      half8 al = *(half8*)&As_lo[row * 40 + fk];
#pragma unroll
      for (int n = 0; n < 4; n++) {
        acc[m][n] = __builtin_amdgcn_mfma_f32_16x16x32_f16(ah, bh[n], acc[m][n], 0, 0, 0);
        acc[m][n] = __builtin_amdgcn_mfma_f32_16x16x32_f16(al, bh[n], acc[m][n], 0, 0, 0);
        acc[m][n] = __builtin_amdgcn_mfma_f32_16x16x32_f16(ah, bl[n], acc[m][n], 0, 0, 0);
      }
    }
  }

  // ---- epilogue ----
#pragma unroll
  for (int n = 0; n < 4; n++) {
    int col = col0 + wn * 64 + n * 16 + fr;
    float bv = HAS_BIAS ? bias[col] : 0.f;
#pragma unroll
    for (int m = 0; m < 4; m++) {
      int rowb = row0 + wm * 64 + m * 16 + (lane >> 4) * 4;
#pragma unroll
      for (int r = 0; r < 4; r++) {
        float val = acc[m][n][r] + bv;
        if (DO_GELU) val = gelu_f(val);
        float* cp = C + (size_t)(rowb + r) * N + col;
        if (RESID) val += *cp;
        *cp = val;
      }
    }
  }
}

// ---------------------------------------------------------------------------
// f32 tiled GEMM (hash path only — bucket decisions need f32-exact math).
// 128x128 tile, 256 threads, 8x8 micro-tile as 2x2 quadrants of 4x4.
// ---------------------------------------------------------------------------
template <int HAS_BIAS, int RESID, int DO_GELU>
__global__ __launch_bounds__(256) void gemm_kernel(const float* __restrict__ A,
                                                   const float* __restrict__ W,
                                                   const float* __restrict__ bias,
                                                   float* __restrict__ C,
                                                   int M, int N, int K) {
  __shared__ float As[16][132];   // [k][m], padded
  __shared__ float Bs[16][132];   // [k][n], padded
  int tid = threadIdx.x;
  int bn = blockIdx.x, bm = blockIdx.y;
  int row0 = bm * 128, col0 = bn * 128;
  int tr = tid >> 4, tc = tid & 15;       // 16x16 threads
  float acc[2][2][4][4] = {};             // [mq][nq][i][j]

  int la_r = tid >> 1;               // 0..127  A row within tile
  int la_c = (tid & 1) * 8;          // 0 or 8
  int lb_r = tid >> 4;               // 0..15   B row within tile
  int lb_c = (tid & 15) * 8;         // 0..120

  for (int k0 = 0; k0 < K; k0 += 16) {
    const float* ap = A + (size_t)(row0 + la_r) * K + k0 + la_c;
    float4 a0 = *(const float4*)ap;
    float4 a1 = *(const float4*)(ap + 4);
    As[la_c + 0][la_r] = a0.x;
    As[la_c + 1][la_r] = a0.y;
    As[la_c + 2][la_r] = a0.z;
    As[la_c + 3][la_r] = a0.w;
    As[la_c + 4][la_r] = a1.x;
    As[la_c + 5][la_r] = a1.y;
    As[la_c + 6][la_r] = a1.z;
    As[la_c + 7][la_r] = a1.w;
    const float* wp = W + (size_t)(k0 + lb_r) * N + col0 + lb_c;
    *(float4*)&Bs[lb_r][lb_c] = *(const float4*)wp;
    *(float4*)&Bs[lb_r][lb_c + 4] = *(const float4*)(wp + 4);
    __syncthreads();
#pragma unroll
    for (int kk = 0; kk < 16; kk++) {
      float4 amq[2], bnq[2];
      amq[0] = *(const float4*)&As[kk][tr * 4];
      amq[1] = *(const float4*)&As[kk][64 + tr * 4];
      bnq[0] = *(const float4*)&Bs[kk][tc * 4];
      bnq[1] = *(const float4*)&Bs[kk][64 + tc * 4];
#pragma unroll
      for (int mq = 0; mq < 2; mq++) {
        float a0f = amq[mq].x, a1f = amq[mq].y, a2f = amq[mq].z, a3f = amq[mq].w;
#pragma unroll
        for (int nq = 0; nq < 2; nq++) {
          float b0 = bnq[nq].x, b1 = bnq[nq].y, b2 = bnq[nq].z, b3 = bnq[nq].w;
          acc[mq][nq][0][0] += a0f * b0; acc[mq][nq][0][1] += a0f * b1;
          acc[mq][nq][0][2] += a0f * b2; acc[mq][nq][0][3] += a0f * b3;
          acc[mq][nq][1][0] += a1f * b0; acc[mq][nq][1][1] += a1f * b1;
          acc[mq][nq][1][2] += a1f * b2; acc[mq][nq][1][3] += a1f * b3;
          acc[mq][nq][2][0] += a2f * b0; acc[mq][nq][2][1] += a2f * b1;
          acc[mq][nq][2][2] += a2f * b2; acc[mq][nq][2][3] += a2f * b3;
          acc[mq][nq][3][0] += a3f * b0; acc[mq][nq][3][1] += a3f * b1;
          acc[mq][nq][3][2] += a3f * b2; acc[mq][nq][3][3] += a3f * b3;
        }
      }
    }
    __syncthreads();
  }

#pragma unroll
  for (int mq = 0; mq < 2; mq++) {
#pragma unroll
    for (int i = 0; i < 4; i++) {
      int row = row0 + mq * 64 + tr * 4 + i;
#pragma unroll
      for (int nq = 0; nq < 2; nq++) {
        float* cp = C + (size_t)row * N + col0 + nq * 64 + tc * 4;
        float4 vv;
        vv.x = acc[mq][nq][i][0]; vv.y = acc[mq][nq][i][1];
        vv.z = acc[mq][nq][i][2]; vv.w = acc[mq][nq][i][3];
        *(float4*)cp = vv;
      }
    }
  }
}

// ---------------------------------------------------------------------------
// rotW2[d][h*32+j] = sum_f Wq[d][h*64+f] * rot[h][f][j]  (f64 acc, f32 store)
// ---------------------------------------------------------------------------
__global__ __launch_bounds__(256) void rotw_kernel(const float* __restrict__ Wq,
                                                   const float* __restrict__ rot,
                                                   float* __restrict__ rotW2) {
  int idx = blockIdx.x * 256 + threadIdx.x;   // d*256 + h*32 + j, 512*256 total
  int n = idx & 255;
  int d = idx >> 8;
  int h = n >> 5;
  int j = n & 31;
  double a = 0.0;
#pragma unroll 8
  for (int f = 0; f < 64; f++) {
    a += (double)Wq[(size_t)d * D_ + h * 64 + f] * (double)rot[((size_t)h * 64 + f) * 32 + j];
  }
  rotW2[idx] = (float)a;
}

// ---------------------------------------------------------------------------
// Per-token bucket argmax over [r, -r] (first-index ties, like np.argmax).
// ---------------------------------------------------------------------------
__global__ __launch_bounds__(256) void argmax_kernel(const float* __restrict__ rbuf,
                                                     int* __restrict__ buckets) {
  int gid = blockIdx.x * 256 + threadIdx.x;   // b*H*S + h*S + s
  int s = gid & (S_ - 1);
  int bh = gid >> 12;
  int h = bh & (H_ - 1);
  int b = bh >> 3;
  const float* rp = rbuf + ((size_t)b * S_ + s) * 256 + h * 32;
  float r[32];
#pragma unroll
  for (int j4 = 0; j4 < 8; j4++) {
    float4 t4 = *(const float4*)(rp + j4 * 4);
    r[j4 * 4 + 0] = t4.x; r[j4 * 4 + 1] = t4.y;
    r[j4 * 4 + 2] = t4.z; r[j4 * 4 + 3] = t4.w;
  }
  float best = r[0];
  int bi = 0;
#pragma unroll
  for (int j = 1; j < 64; j++) {
    float val = (j < 32) ? r[j] : -r[j - 32];
    if (val > best) { best = val; bi = j; }
  }
  buckets[gid] = bi;
}

// ---------------------------------------------------------------------------
// Stable counting sort by bucket (== argsort(bucket*S + pos)).
// ---------------------------------------------------------------------------
__global__ __launch_bounds__(64) void sort_kernel(const int* __restrict__ buckets,
                                                  int* __restrict__ st) {
  __shared__ int hist[64][64];   // [thread][bucket]
  __shared__ int boff[64];
  int bh = blockIdx.x;
  const int* bk = buckets + (size_t)bh * S_;
  int* stb = st + (size_t)bh * S_;
  int t = threadIdx.x;
  for (int j = 0; j < 64; j++) hist[t][j] = 0;
  __syncthreads();
  for (int i = 0; i < 64; i++) {
    int s = t * 64 + i;
    hist[t][bk[s]]++;
  }
  __syncthreads();
  int run = 0;
  for (int tt = 0; tt < 64; tt++) {
    int c = hist[tt][t];
    hist[tt][t] = run;
    run += c;
  }
  boff[t] = run;
  __syncthreads();
  if (t == 0) {
    int acc = 0;
    for (int j = 0; j < 64; j++) { int c = boff[j]; boff[j] = acc; acc += c; }
  }
  __syncthreads();
  for (int i = 0; i < 64; i++) {
    int s = t * 64 + i;
    int bkt = bk[s];
    int pos = boff[bkt] + hist[t][bkt];
    hist[t][bkt] = hist[t][bkt] + 1;
    stb[pos] = s;
  }
}

// ---------------------------------------------------------------------------
// Chunked shared-QK attention. One block per (b,h,chunk).
// ---------------------------------------------------------------------------
__global__ __launch_bounds__(256) void attn_kernel(const float* __restrict__ q,
                                                   const float* __restrict__ v,
                                                   const int* __restrict__ st,
                                                   float* __restrict__ o) {
  __shared__ float Ksh[128][68];
  __shared__ float Vsh[128][68];
  int blk = blockIdx.x;
  int n = blk & (NC_ - 1);
  int bh = blk >> 6;
  int h = bh & (H_ - 1);
  int b = bh >> 3;
  const int* stbh = st + (size_t)bh * S_;
  int tid = threadIdx.x;
  int pn = (n + NC_ - 1) & (NC_ - 1);
  for (int i = tid; i < 128 * 16; i += 256) {
    int r = i >> 4, c4 = i & 15;
    int si = (r < 64) ? (n * 64 + r) : (pn * 64 + (r - 64));
    int p = stbh[si];
    size_t base = ((size_t)b * S_ + p) * D_ + h * 64;
    ((float4*)Ksh[r])[c4] = *(const float4*)(q + base + c4 * 4);
    ((float4*)Vsh[r])[c4] = *(const float4*)(v + base + c4 * 4);
  }
  __syncthreads();
  int r = tid >> 2, sub = tid & 3;
  float qr[64];
#pragma unroll
  for (int f4 = 0; f4 < 16; f4++) {
    float4 t4 = ((const float4*)Ksh[r])[f4];
    qr[f4 * 4 + 0] = t4.x; qr[f4 * 4 + 1] = t4.y;
    qr[f4 * 4 + 2] = t4.z; qr[f4 * 4 + 3] = t4.w;
  }
  float lg[32];
  float mx = -1e30f;
#pragma unroll
  for (int kk = 0; kk < 32; kk++) {
    int k = kk * 4 + sub;
    float sdot = 0.f;
#pragma unroll
    for (int f4 = 0; f4 < 16; f4++) {
      float4 kv = ((const float4*)Ksh[k])[f4];
      sdot += qr[f4 * 4 + 0] * kv.x + qr[f4 * 4 + 1] * kv.y
            + qr[f4 * 4 + 2] * kv.z + qr[f4 * 4 + 3] * kv.w;
    }
    sdot *= 0.125f;
    lg[kk] = sdot;
    mx = fmaxf(mx, sdot);
  }
  mx = fmaxf(mx, __shfl_xor(mx, 1));
  mx = fmaxf(mx, __shfl_xor(mx, 2));
  float ssum = 0.f;
#pragma unroll
  for (int kk = 0; kk < 32; kk++) {
    float p = expf(lg[kk] - mx);
    lg[kk] = p;
    ssum += p;
  }
  ssum += __shfl_xor(ssum, 1);
  ssum += __shfl_xor(ssum, 2);
  float acc[64];
#pragma unroll
  for (int f = 0; f < 64; f++) acc[f] = 0.f;
#pragma unroll
  for (int kk = 0; kk < 32; kk++) {
    int k = kk * 4 + sub;
    float w = lg[kk];
#pragma unroll
    for (int f4 = 0; f4 < 16; f4++) {
      float4 vv = ((const float4*)Vsh[k])[f4];
      acc[f4 * 4 + 0] += w * vv.x;
      acc[f4 * 4 + 1] += w * vv.y;
      acc[f4 * 4 + 2] += w * vv.z;
      acc[f4 * 4 + 3] += w * vv.w;
    }
  }
  float red[32];
#pragma unroll
  for (int j = 0; j < 32; j++) {
    float lo = acc[j], hi = acc[32 + j];
    float keep = (sub & 1) ? hi : lo;
    float send = (sub & 1) ? lo : hi;
    red[j] = keep + __shfl_xor(send, 1);
  }
  float red2[16];
#pragma unroll
  for (int j = 0; j < 16; j++) {
    float lo = red[j], hi = red[16 + j];
    float keep = (sub & 2) ? hi : lo;
    float send = (sub & 2) ? lo : hi;
    red2[j] = keep + __shfl_xor(send, 2);
  }
  int seg = (sub & 1) * 32 + (sub & 2) * 8;   // 0->0, 1->32, 2->16, 3->48
  float inv = 1.0f / ssum;
  int p = stbh[n * 64 + r];
  float* orow = o + ((size_t)b * S_ + p) * D_ + h * 64 + seg;
#pragma unroll
  for (int f4 = 0; f4 < 4; f4++) {
    float4 w4;
    w4.x = red2[f4 * 4 + 0] * inv;
    w4.y = red2[f4 * 4 + 1] * inv;
    w4.z = red2[f4 * 4 + 2] * inv;
    w4.w = red2[f4 * 4 + 3] * inv;
    *(float4*)(orow + f4 * 4) = w4;
  }
}

// ---------------------------------------------------------------------------
extern "C" void kernel_launch(void* const* d_in, const int* in_sizes, int n_in,
                              void* d_out, int out_size, void* d_ws, size_t ws_size,
                              hipStream_t stream) {
  const int*   tokens = (const int*)d_in[0];
  const float* emb    = (const float*)d_in[1];
  const float* rot    = (const float*)d_in[2];
  const float* ln1_s  = (const float*)d_in[3];
  const float* ln1_b  = (const float*)d_in[4];
  const float* Wq     = (const float*)d_in[5];
  const float* Wv     = (const float*)d_in[6];
  const float* Wo     = (const float*)d_in[7];
  const float* ln2_s  = (const float*)d_in[8];
  const float* ln2_b  = (const float*)d_in[9];
  const float* W1     = (const float*)d_in[10];
  const float* b1     = (const float*)d_in[11];
  const float* W2     = (const float*)d_in[12];
  const float* b2     = (const float*)d_in[13];
  const float* lnf_s  = (const float*)d_in[14];
  const float* lnf_b  = (const float*)d_in[15];

  float* x = (float*)d_out;                  // residual stream lives in d_out
  float* ws = (float*)d_ws;
  const size_t RS = (size_t)B_ * S_ * D_;    // 8388608 floats
  // Phase-aliased workspace (same footprint as r3-r5):
  //   hbuf  [RS]
  //   region[4*RS]: attn/hash phase = qbuf|vbuf|obuf|rbuf; FFN phase = mid[16384x2048]
  float* hbuf = ws;
  float* region = ws + RS;
  float* qbuf = region;
  float* vbuf = region + RS;
  float* obuf = region + 2 * RS;
  float* rbuf = region + 3 * RS;             // hash scores [16384][256] (4.2M floats)
  float* mid  = region;                      // FFN intermediate [16384][2048]
  int* buckets = (int*)(region + 4 * RS);
  int* stbuf   = buckets + B_ * H_ * S_;
  float* rotW2 = (float*)(stbuf + B_ * H_ * S_);   // [512][256] f32 fused hash weight

  const int rows = B_ * S_;                  // 16384

  embed_kernel<<<rows, 128, 0, stream>>>(tokens, emb, x);

  for (int l = 0; l < L_; l++) {
    ln_kernel<<<rows, 64, 0, stream>>>(x, hbuf, ln1_s + (size_t)l * D_, ln1_b + (size_t)l * D_);

    dim3 g1(D_ / 128, rows / 128);
    gemm_mfma<0, 0, 0><<<g1, 256, 0, stream>>>(hbuf, Wq + (size_t)l * D_ * D_, nullptr, qbuf, rows, D_, D_);
    gemm_mfma<0, 0, 0><<<g1, 256, 0, stream>>>(hbuf, Wv + (size_t)l * D_ * D_, nullptr, vbuf, rows, D_, D_);

    rotw_kernel<<<(D_ * 256) / 256, 256, 0, stream>>>(Wq + (size_t)l * D_ * D_,
                                                      rot + (size_t)l * H_ * DH_ * 32, rotW2);
    dim3 gh(256 / 128, rows / 128);
    gemm_kernel<0, 0, 0><<<gh, 256, 0, stream>>>(hbuf, rotW2, nullptr, rbuf, rows, 256, D_);
    argmax_kernel<<<(B_ * H_ * S_) / 256, 256, 0, stream>>>(rbuf, buckets);
    sort_kernel<<<B_ * H_, 64, 0, stream>>>(buckets, stbuf);
    attn_kernel<<<B_ * H_ * NC_, 256, 0, stream>>>(qbuf, vbuf, stbuf, obuf);

    gemm_mfma<0, 1, 0><<<g1, 256, 0, stream>>>(obuf, Wo + (size_t)l * D_ * D_, nullptr, x, rows, D_, D_);

    ln_kernel<<<rows, 64, 0, stream>>>(x, hbuf, ln2_s + (size_t)l * D_, ln2_b + (size_t)l * D_);

    dim3 gf1(M_ / 128, rows / 128);
    gemm_mfma<1, 0, 1><<<gf1, 256, 0, stream>>>(hbuf, W1 + (size_t)l * D_ * M_, b1 + (size_t)l * M_,
                                                mid, rows, M_, D_);
    dim3 gf2(D_ / 128, rows / 128);
    gemm_mfma<1, 1, 0><<<gf2, 256, 0, stream>>>(mid, W2 + (size_t)l * M_ * D_, b2 + (size_t)l * D_,
                                                x, rows, D_, M_);
  }

  ln_kernel<<<rows, 64, 0, stream>>>(x, x, lnf_s, lnf_b);
}

// Round 8
// 4371.527 us; speedup vs baseline: 2.8720x; 1.1105x over previous
//
#include <hip/hip_runtime.h>

#define B_ 4
#define S_ 4096
#define D_ 512
#define H_ 8
#define L_ 6
#define M_ 2048
#define DH_ 64
#define NC_ 64   // number of chunks = S/C
#define C_ 64    // chunk length

typedef _Float16 half8 __attribute__((ext_vector_type(8)));
typedef _Float16 half4 __attribute__((ext_vector_type(4)));
typedef float f32x4 __attribute__((ext_vector_type(4)));

// ---------------------------------------------------------------------------
// Embedding + sinusoidal positional encoding (f64 PE recipe — r3 fix)
// ---------------------------------------------------------------------------
__global__ __launch_bounds__(128) void embed_kernel(const int* __restrict__ tokens,
                                                    const float* __restrict__ emb,
                                                    float* __restrict__ x) {
  int row = blockIdx.x;            // b*S + s
  int s = row & (S_ - 1);
  int tok = tokens[row];
  const float4* e = (const float4*)(emb + (size_t)tok * D_);
  float4* xo = (float4*)(x + (size_t)row * D_);
  int t = threadIdx.x;             // 128 threads, 4 floats each
  float4 ev = e[t];
  int d0 = t * 4;
  const double c64 = -9.210340371976184 / 255.0;   // -ln(10000)/(half-1)
  float pe[4];
#pragma unroll
  for (int j = 0; j < 4; j++) {
    int d = d0 + j;
    int i = (d < 256) ? d : d - 256;
    double freq = exp((double)i * c64);
    double arg = (double)s * freq;
    pe[j] = (d < 256) ? (float)sin(arg) : (float)cos(arg);
  }
  float4 o;
  o.x = ev.x + pe[0];
  o.y = ev.y + pe[1];
  o.z = ev.z + pe[2];
  o.w = ev.w + pe[3];
  xo[t] = o;
}

// ---------------------------------------------------------------------------
// LayerNorm variants. ln_h writes fp16 hi/lo planes (GEMM inputs);
// ln_f writes f32 (final LN only).
// ---------------------------------------------------------------------------
__device__ __forceinline__ void ln_core(const float* __restrict__ in, int row, int t,
                                        const float* __restrict__ sc,
                                        const float* __restrict__ bi,
                                        float4& o1, float4& o2) {
  const float4* ir = (const float4*)(in + (size_t)row * D_);
  float4 a = ir[t];
  float4 b4 = ir[t + 64];
  float sum = a.x + a.y + a.z + a.w + b4.x + b4.y + b4.z + b4.w;
  float sq  = a.x*a.x + a.y*a.y + a.z*a.z + a.w*a.w
            + b4.x*b4.x + b4.y*b4.y + b4.z*b4.z + b4.w*b4.w;
#pragma unroll
  for (int m = 1; m < 64; m <<= 1) {
    sum += __shfl_xor(sum, m);
    sq  += __shfl_xor(sq, m);
  }
  float mean = sum * (1.0f / 512.0f);
  float var  = sq * (1.0f / 512.0f) - mean * mean;
  float rstd = 1.0f / sqrtf(var + 1e-6f);
  float4 s1 = ((const float4*)sc)[t], s2 = ((const float4*)sc)[t + 64];
  float4 g1 = ((const float4*)bi)[t], g2 = ((const float4*)bi)[t + 64];
  o1.x = (a.x - mean) * rstd * s1.x + g1.x;
  o1.y = (a.y - mean) * rstd * s1.y + g1.y;
  o1.z = (a.z - mean) * rstd * s1.z + g1.z;
  o1.w = (a.w - mean) * rstd * s1.w + g1.w;
  o2.x = (b4.x - mean) * rstd * s2.x + g2.x;
  o2.y = (b4.y - mean) * rstd * s2.y + g2.y;
  o2.z = (b4.z - mean) * rstd * s2.z + g2.z;
  o2.w = (b4.w - mean) * rstd * s2.w + g2.w;
}

__global__ __launch_bounds__(64) void ln_h(const float* __restrict__ in,
                                           _Float16* __restrict__ hi,
                                           _Float16* __restrict__ lo,
                                           const float* __restrict__ sc,
                                           const float* __restrict__ bi) {
  int row = blockIdx.x, t = threadIdx.x;
  float4 o1, o2;
  ln_core(in, row, t, sc, bi, o1, o2);
  float v1[4] = {o1.x, o1.y, o1.z, o1.w};
  float v2[4] = {o2.x, o2.y, o2.z, o2.w};
  half4 h1, l1, h2, l2;
#pragma unroll
  for (int j = 0; j < 4; j++) {
    _Float16 h = (_Float16)v1[j];
    h1[j] = h; l1[j] = (_Float16)(v1[j] - (float)h);
    _Float16 g = (_Float16)v2[j];
    h2[j] = g; l2[j] = (_Float16)(v2[j] - (float)g);
  }
  size_t base = (size_t)row * D_;
  *(half4*)&hi[base + t * 4] = h1;
  *(half4*)&hi[base + 256 + t * 4] = h2;
  *(half4*)&lo[base + t * 4] = l1;
  *(half4*)&lo[base + 256 + t * 4] = l2;
}

__global__ __launch_bounds__(64) void ln_f(const float* __restrict__ in,
                                           float* __restrict__ out,
                                           const float* __restrict__ sc,
                                           const float* __restrict__ bi) {
  int row = blockIdx.x, t = threadIdx.x;
  float4 o1, o2;
  ln_core(in, row, t, sc, bi, o1, o2);
  float4* orow = (float4*)(out + (size_t)row * D_);
  orow[t] = o1;
  orow[t + 64] = o2;
}

__device__ __forceinline__ float gelu_f(float v) {
  float v3 = v * v * v;
  return 0.5f * v * (1.0f + tanhf(0.7978845608028654f * (v + 0.044715f * v3)));
}

// ---------------------------------------------------------------------------
// Weight convert+transpose: src f32 [K][N] -> dst hi/lo fp16 [N][K].
// LDS 32x33-tiled, coalesced both sides. One launch per matrix per layer.
// ---------------------------------------------------------------------------
__global__ __launch_bounds__(256) void transp_cvt(const float* __restrict__ src,
                                                  _Float16* __restrict__ dhi,
                                                  _Float16* __restrict__ dlo,
                                                  int K, int N) {
  __shared__ float tile[32][33];
  int n0 = blockIdx.x * 32, k0 = blockIdx.y * 32;
  int tx = threadIdx.x & 31, ty = threadIdx.x >> 5;   // ty 0..7
#pragma unroll
  for (int i = 0; i < 4; i++)
    tile[ty + 8 * i][tx] = src[(size_t)(k0 + ty + 8 * i) * N + n0 + tx];
  __syncthreads();
#pragma unroll
  for (int i = 0; i < 4; i++) {
    int n = n0 + ty + 8 * i;
    float v = tile[tx][ty + 8 * i];
    _Float16 h = (_Float16)v;
    dhi[(size_t)n * K + k0 + tx] = h;
    dlo[(size_t)n * K + k0 + tx] = (_Float16)(v - (float)h);
  }
}

// ---------------------------------------------------------------------------
// fp16x3 split MFMA GEMM with pre-converted fp16 hi/lo inputs.
// A: [M][lda] planes, B: [N][ldb] planes (pre-transposed weights).
// K is the reduction length this pass (<= lda/ldb window).
// 128x128 tile, BK=32, 4 waves. LDS pitch 40 halfs. Zero conversion VALU.
// ---------------------------------------------------------------------------
template <int HAS_BIAS, int RESID, int DO_GELU, int OUT_HALF>
__global__ __launch_bounds__(256) void gemm_h(const _Float16* __restrict__ Ahi,
                                              const _Float16* __restrict__ Alo,
                                              const _Float16* __restrict__ Bhi,
                                              const _Float16* __restrict__ Blo,
                                              const float* __restrict__ bias,
                                              float* __restrict__ C,
                                              _Float16* __restrict__ Chi,
                                              _Float16* __restrict__ Clo,
                                              int M, int N, int K, int lda, int ldb) {
  __shared__ _Float16 Ah[128 * 40];
  __shared__ _Float16 Al[128 * 40];
  __shared__ _Float16 Bh[128 * 40];
  __shared__ _Float16 Bl[128 * 40];
  int tid = threadIdx.x;
  int row0 = blockIdx.y * 128, col0 = blockIdx.x * 128;
  int lane = tid & 63, wid = tid >> 6;
  int wm = wid >> 1, wn = wid & 1;
  int fr = lane & 15, fk = (lane >> 4) * 8;
  int sr = tid >> 1, sk = (tid & 1) * 16;

  const _Float16* pAh = Ahi + (size_t)(row0 + sr) * lda + sk;
  const _Float16* pAl = Alo + (size_t)(row0 + sr) * lda + sk;
  const _Float16* pBh = Bhi + (size_t)(col0 + sr) * ldb + sk;
  const _Float16* pBl = Blo + (size_t)(col0 + sr) * ldb + sk;

  f32x4 acc[4][4];
#pragma unroll
  for (int m = 0; m < 4; m++)
#pragma unroll
    for (int n = 0; n < 4; n++) acc[m][n] = (f32x4){0.f, 0.f, 0.f, 0.f};

  half8 rah0 = *(const half8*)pAh, rah1 = *(const half8*)(pAh + 8);
  half8 ral0 = *(const half8*)pAl, ral1 = *(const half8*)(pAl + 8);
  half8 rbh0 = *(const half8*)pBh, rbh1 = *(const half8*)(pBh + 8);
  half8 rbl0 = *(const half8*)pBl, rbl1 = *(const half8*)(pBl + 8);

  int nst = K >> 5;
  for (int s = 0; s < nst; ++s) {
    __syncthreads();
    *(half8*)&Ah[sr * 40 + sk] = rah0; *(half8*)&Ah[sr * 40 + sk + 8] = rah1;
    *(half8*)&Al[sr * 40 + sk] = ral0; *(half8*)&Al[sr * 40 + sk + 8] = ral1;
    *(half8*)&Bh[sr * 40 + sk] = rbh0; *(half8*)&Bh[sr * 40 + sk + 8] = rbh1;
    *(half8*)&Bl[sr * 40 + sk] = rbl0; *(half8*)&Bl[sr * 40 + sk + 8] = rbl1;
    __syncthreads();
    if (s + 1 < nst) {
      int off = (s + 1) * 32;
      rah0 = *(const half8*)(pAh + off); rah1 = *(const half8*)(pAh + off + 8);
      ral0 = *(const half8*)(pAl + off); ral1 = *(const half8*)(pAl + off + 8);
      rbh0 = *(const half8*)(pBh + off); rbh1 = *(const half8*)(pBh + off + 8);
      rbl0 = *(const half8*)(pBl + off); rbl1 = *(const half8*)(pBl + off + 8);
    }
    half8 bhf[4], blf[4];
#pragma unroll
    for (int n = 0; n < 4; n++) {
      int col = wn * 64 + n * 16 + fr;
      bhf[n] = *(half8*)&Bh[col * 40 + fk];
      blf[n] = *(half8*)&Bl[col * 40 + fk];
    }
#pragma unroll
    for (int m = 0; m < 4; m++) {
      int row = wm * 64 + m * 16 + fr;
      half8 ah = *(half8*)&Ah[row * 40 + fk];
      half8 al = *(half8*)&Al[row * 40 + fk];
      // 3 separate n-sweeps: 4 independent MFMAs between dependent pairs
#pragma unroll
      for (int n = 0; n < 4; n++)
        acc[m][n] = __builtin_amdgcn_mfma_f32_16x16x32_f16(ah, bhf[n], acc[m][n], 0, 0, 0);
#pragma unroll
      for (int n = 0; n < 4; n++)
        acc[m][n] = __builtin_amdgcn_mfma_f32_16x16x32_f16(al, bhf[n], acc[m][n], 0, 0, 0);
#pragma unroll
      for (int n = 0; n < 4; n++)
        acc[m][n] = __builtin_amdgcn_mfma_f32_16x16x32_f16(ah, blf[n], acc[m][n], 0, 0, 0);
    }
  }

  // ---- epilogue ----
#pragma unroll
  for (int n = 0; n < 4; n++) {
    int col = col0 + wn * 64 + n * 16 + fr;
    float bv = HAS_BIAS ? bias[col] : 0.f;
#pragma unroll
    for (int m = 0; m < 4; m++) {
      int rowb = row0 + wm * 64 + m * 16 + (lane >> 4) * 4;
#pragma unroll
      for (int r = 0; r < 4; r++) {
        float val = acc[m][n][r] + bv;
        if (DO_GELU) val = gelu_f(val);
        size_t idx = (size_t)(rowb + r) * N + col;
        if (OUT_HALF) {
          _Float16 h = (_Float16)val;
          Chi[idx] = h;
          Clo[idx] = (_Float16)(val - (float)h);
        } else {
          if (RESID) val += C[idx];
          C[idx] = val;
        }
      }
    }
  }
}

// ---------------------------------------------------------------------------
// f32 hash GEMM: A reconstructed from hi/lo planes (exact f32 sum),
// W (rotW2) f32. 128x128 tile, 8x8 micro-tile. Bucket-decision path.
// ---------------------------------------------------------------------------
__global__ __launch_bounds__(256) void gemm_hash(const _Float16* __restrict__ Ahi,
                                                 const _Float16* __restrict__ Alo,
                                                 const float* __restrict__ W,
                                                 float* __restrict__ Cout,
                                                 int M, int N, int K) {
  __shared__ float As[16][132];   // [k][m], padded
  __shared__ float Bs[16][132];   // [k][n], padded
  int tid = threadIdx.x;
  int bn = blockIdx.x, bm = blockIdx.y;
  int row0 = bm * 128, col0 = bn * 128;
  int tr = tid >> 4, tc = tid & 15;       // 16x16 threads
  float acc[2][2][4][4] = {};             // [mq][nq][i][j]

  int la_r = tid >> 1;               // 0..127  A row within tile
  int la_c = (tid & 1) * 8;          // 0 or 8
  int lb_r = tid >> 4;               // 0..15   B row within tile
  int lb_c = (tid & 15) * 8;         // 0..120

  for (int k0 = 0; k0 < K; k0 += 16) {
    half8 hv = *(const half8*)(Ahi + (size_t)(row0 + la_r) * K + k0 + la_c);
    half8 lv = *(const half8*)(Alo + (size_t)(row0 + la_r) * K + k0 + la_c);
#pragma unroll
    for (int j = 0; j < 8; j++)
      As[la_c + j][la_r] = (float)hv[j] + (float)lv[j];
    const float* wp = W + (size_t)(k0 + lb_r) * N + col0 + lb_c;
    *(float4*)&Bs[lb_r][lb_c] = *(const float4*)wp;
    *(float4*)&Bs[lb_r][lb_c + 4] = *(const float4*)(wp + 4);
    __syncthreads();
#pragma unroll
    for (int kk = 0; kk < 16; kk++) {
      float4 amq[2], bnq[2];
      amq[0] = *(const float4*)&As[kk][tr * 4];
      amq[1] = *(const float4*)&As[kk][64 + tr * 4];
      bnq[0] = *(const float4*)&Bs[kk][tc * 4];
      bnq[1] = *(const float4*)&Bs[kk][64 + tc * 4];
#pragma unroll
      for (int mq = 0; mq < 2; mq++) {
        float a0f = amq[mq].x, a1f = amq[mq].y, a2f = amq[mq].z, a3f = amq[mq].w;
#pragma unroll
        for (int nq = 0; nq < 2; nq++) {
          float b0 = bnq[nq].x, b1 = bnq[nq].y, b2 = bnq[nq].z, b3 = bnq[nq].w;
          acc[mq][nq][0][0] += a0f * b0; acc[mq][nq][0][1] += a0f * b1;
          acc[mq][nq][0][2] += a0f * b2; acc[mq][nq][0][3] += a0f * b3;
          acc[mq][nq][1][0] += a1f * b0; acc[mq][nq][1][1] += a1f * b1;
          acc[mq][nq][1][2] += a1f * b2; acc[mq][nq][1][3] += a1f * b3;
          acc[mq][nq][2][0] += a2f * b0; acc[mq][nq][2][1] += a2f * b1;
          acc[mq][nq][2][2] += a2f * b2; acc[mq][nq][2][3] += a2f * b3;
          acc[mq][nq][3][0] += a3f * b0; acc[mq][nq][3][1] += a3f * b1;
          acc[mq][nq][3][2] += a3f * b2; acc[mq][nq][3][3] += a3f * b3;
        }
      }
    }
    __syncthreads();
  }

#pragma unroll
  for (int mq = 0; mq < 2; mq++) {
#pragma unroll
    for (int i = 0; i < 4; i++) {
      int row = row0 + mq * 64 + tr * 4 + i;
#pragma unroll
      for (int nq = 0; nq < 2; nq++) {
        float* cp = Cout + (size_t)row * N + col0 + nq * 64 + tc * 4;
        float4 vv;
        vv.x = acc[mq][nq][i][0]; vv.y = acc[mq][nq][i][1];
        vv.z = acc[mq][nq][i][2]; vv.w = acc[mq][nq][i][3];
        *(float4*)cp = vv;
      }
    }
  }
}

// ---------------------------------------------------------------------------
// rotW2[d][h*32+j] = sum_f Wq[d][h*64+f] * rot[h][f][j]  (f64 acc, f32 store)
// ---------------------------------------------------------------------------
__global__ __launch_bounds__(256) void rotw_kernel(const float* __restrict__ Wq,
                                                   const float* __restrict__ rot,
                                                   float* __restrict__ rotW2) {
  int idx = blockIdx.x * 256 + threadIdx.x;   // d*256 + h*32 + j, 512*256 total
  int n = idx & 255;
  int d = idx >> 8;
  int h = n >> 5;
  int j = n & 31;
  double a = 0.0;
#pragma unroll 8
  for (int f = 0; f < 64; f++) {
    a += (double)Wq[(size_t)d * D_ + h * 64 + f] * (double)rot[((size_t)h * 64 + f) * 32 + j];
  }
  rotW2[idx] = (float)a;
}

// ---------------------------------------------------------------------------
// Per-token bucket argmax over [r, -r] (first-index ties, like np.argmax).
// ---------------------------------------------------------------------------
__global__ __launch_bounds__(256) void argmax_kernel(const float* __restrict__ rbuf,
                                                     int* __restrict__ buckets) {
  int gid = blockIdx.x * 256 + threadIdx.x;   // b*H*S + h*S + s
  int s = gid & (S_ - 1);
  int bh = gid >> 12;
  int h = bh & (H_ - 1);
  int b = bh >> 3;
  const float* rp = rbuf + ((size_t)b * S_ + s) * 256 + h * 32;
  float r[32];
#pragma unroll
  for (int j4 = 0; j4 < 8; j4++) {
    float4 t4 = *(const float4*)(rp + j4 * 4);
    r[j4 * 4 + 0] = t4.x; r[j4 * 4 + 1] = t4.y;
    r[j4 * 4 + 2] = t4.z; r[j4 * 4 + 3] = t4.w;
  }
  float best = r[0];
  int bi = 0;
#pragma unroll
  for (int j = 1; j < 64; j++) {
    float val = (j < 32) ? r[j] : -r[j - 32];
    if (val > best) { best = val; bi = j; }
  }
  buckets[gid] = bi;
}

// ---------------------------------------------------------------------------
// Stable counting sort by bucket (== argsort(bucket*S + pos)).
// ---------------------------------------------------------------------------
__global__ __launch_bounds__(64) void sort_kernel(const int* __restrict__ buckets,
                                                  int* __restrict__ st) {
  __shared__ int hist[64][64];   // [thread][bucket]
  __shared__ int boff[64];
  int bh = blockIdx.x;
  const int* bk = buckets + (size_t)bh * S_;
  int* stb = st + (size_t)bh * S_;
  int t = threadIdx.x;
  for (int j = 0; j < 64; j++) hist[t][j] = 0;
  __syncthreads();
  for (int i = 0; i < 64; i++) {
    int s = t * 64 + i;
    hist[t][bk[s]]++;
  }
  __syncthreads();
  int run = 0;
  for (int tt = 0; tt < 64; tt++) {
    int c = hist[tt][t];
    hist[tt][t] = run;
    run += c;
  }
  boff[t] = run;
  __syncthreads();
  if (t == 0) {
    int acc = 0;
    for (int j = 0; j < 64; j++) { int c = boff[j]; boff[j] = acc; acc += c; }
  }
  __syncthreads();
  for (int i = 0; i < 64; i++) {
    int s = t * 64 + i;
    int bkt = bk[s];
    int pos = boff[bkt] + hist[t][bkt];
    hist[t][bkt] = hist[t][bkt] + 1;
    stb[pos] = s;
  }
}

// ---------------------------------------------------------------------------
// Chunked shared-QK attention. One block per (b,h,chunk).
// Output written as fp16 hi/lo planes (feeds Wo GEMM directly).
// ---------------------------------------------------------------------------
__global__ __launch_bounds__(256) void attn_kernel(const float* __restrict__ q,
                                                   const float* __restrict__ v,
                                                   const int* __restrict__ st,
                                                   _Float16* __restrict__ ohi,
                                                   _Float16* __restrict__ olo) {
  __shared__ float Ksh[128][68];
  __shared__ float Vsh[128][68];
  int blk = blockIdx.x;
  int n = blk & (NC_ - 1);
  int bh = blk >> 6;
  int h = bh & (H_ - 1);
  int b = bh >> 3;
  const int* stbh = st + (size_t)bh * S_;
  int tid = threadIdx.x;
  int pn = (n + NC_ - 1) & (NC_ - 1);
  for (int i = tid; i < 128 * 16; i += 256) {
    int r = i >> 4, c4 = i & 15;
    int si = (r < 64) ? (n * 64 + r) : (pn * 64 + (r - 64));
    int p = stbh[si];
    size_t base = ((size_t)b * S_ + p) * D_ + h * 64;
    ((float4*)Ksh[r])[c4] = *(const float4*)(q + base + c4 * 4);
    ((float4*)Vsh[r])[c4] = *(const float4*)(v + base + c4 * 4);
  }
  __syncthreads();
  int r = tid >> 2, sub = tid & 3;
  float qr[64];
#pragma unroll
  for (int f4 = 0; f4 < 16; f4++) {
    float4 t4 = ((const float4*)Ksh[r])[f4];
    qr[f4 * 4 + 0] = t4.x; qr[f4 * 4 + 1] = t4.y;
    qr[f4 * 4 + 2] = t4.z; qr[f4 * 4 + 3] = t4.w;
  }
  float lg[32];
  float mx = -1e30f;
#pragma unroll
  for (int kk = 0; kk < 32; kk++) {
    int k = kk * 4 + sub;
    float sdot = 0.f;
#pragma unroll
    for (int f4 = 0; f4 < 16; f4++) {
      float4 kv = ((const float4*)Ksh[k])[f4];
      sdot += qr[f4 * 4 + 0] * kv.x + qr[f4 * 4 + 1] * kv.y
            + qr[f4 * 4 + 2] * kv.z + qr[f4 * 4 + 3] * kv.w;
    }
    sdot *= 0.125f;
    lg[kk] = sdot;
    mx = fmaxf(mx, sdot);
  }
  mx = fmaxf(mx, __shfl_xor(mx, 1));
  mx = fmaxf(mx, __shfl_xor(mx, 2));
  float ssum = 0.f;
#pragma unroll
  for (int kk = 0; kk < 32; kk++) {
    float p = expf(lg[kk] - mx);
    lg[kk] = p;
    ssum += p;
  }
  ssum += __shfl_xor(ssum, 1);
  ssum += __shfl_xor(ssum, 2);
  float acc[64];
#pragma unroll
  for (int f = 0; f < 64; f++) acc[f] = 0.f;
#pragma unroll
  for (int kk = 0; kk < 32; kk++) {
    int k = kk * 4 + sub;
    float w = lg[kk];
#pragma unroll
    for (int f4 = 0; f4 < 16; f4++) {
      float4 vv = ((const float4*)Vsh[k])[f4];
      acc[f4 * 4 + 0] += w * vv.x;
      acc[f4 * 4 + 1] += w * vv.y;
      acc[f4 * 4 + 2] += w * vv.z;
      acc[f4 * 4 + 3] += w * vv.w;
    }
  }
  float red[32];
#pragma unroll
  for (int j = 0; j < 32; j++) {
    float lo = acc[j], hi = acc[32 + j];
    float keep = (sub & 1) ? hi : lo;
    float send = (sub & 1) ? lo : hi;
    red[j] = keep + __shfl_xor(send, 1);
  }
  float red2[16];
#pragma unroll
  for (int j = 0; j < 16; j++) {
    float lo = red[j], hi = red[16 + j];
    float keep = (sub & 2) ? hi : lo;
    float send = (sub & 2) ? lo : hi;
    red2[j] = keep + __shfl_xor(send, 2);
  }
  int seg = (sub & 1) * 32 + (sub & 2) * 8;   // 0->0, 1->32, 2->16, 3->48
  float inv = 1.0f / ssum;
  int p = stbh[n * 64 + r];
  size_t obase = ((size_t)b * S_ + p) * D_ + h * 64 + seg;
#pragma unroll
  for (int f4 = 0; f4 < 4; f4++) {
    float vv[4];
    vv[0] = red2[f4 * 4 + 0] * inv;
    vv[1] = red2[f4 * 4 + 1] * inv;
    vv[2] = red2[f4 * 4 + 2] * inv;
    vv[3] = red2[f4 * 4 + 3] * inv;
    half4 hv, lv;
#pragma unroll
    for (int j = 0; j < 4; j++) {
      _Float16 h16 = (_Float16)vv[j];
      hv[j] = h16;
      lv[j] = (_Float16)(vv[j] - (float)h16);
    }
    *(half4*)&ohi[obase + f4 * 4] = hv;
    *(half4*)&olo[obase + f4 * 4] = lv;
  }
}

// ---------------------------------------------------------------------------
extern "C" void kernel_launch(void* const* d_in, const int* in_sizes, int n_in,
                              void* d_out, int out_size, void* d_ws, size_t ws_size,
                              hipStream_t stream) {
  const int*   tokens = (const int*)d_in[0];
  const float* emb    = (const float*)d_in[1];
  const float* rot    = (const float*)d_in[2];
  const float* ln1_s  = (const float*)d_in[3];
  const float* ln1_b  = (const float*)d_in[4];
  const float* Wq     = (const float*)d_in[5];
  const float* Wv     = (const float*)d_in[6];
  const float* Wo     = (const float*)d_in[7];
  const float* ln2_s  = (const float*)d_in[8];
  const float* ln2_b  = (const float*)d_in[9];
  const float* W1     = (const float*)d_in[10];
  const float* b1     = (const float*)d_in[11];
  const float* W2     = (const float*)d_in[12];
  const float* b2     = (const float*)d_in[13];
  const float* lnf_s  = (const float*)d_in[14];
  const float* lnf_b  = (const float*)d_in[15];

  float* x = (float*)d_out;                  // residual stream lives in d_out
  const size_t RS = (size_t)B_ * S_ * D_;    // 8388608 elements
  const size_t WTOT = 3 * (size_t)D_ * D_ + 2 * (size_t)D_ * M_;  // 2883584

  char* wsb = (char*)d_ws;
  // region: 3.5RS floats (14RS bytes), phase-aliased.
  //   attn phase: qbuf[RS f32] | vbuf[RS f32] | obuf hi/lo[2RS half] | rbuf[0.5RS f32]
  //   FFN phase:  mid hi/lo planes [16384][1024] each (2RS floats worth)
  float* region = (float*)wsb;
  float* qbuf = region;
  float* vbuf = region + RS;
  _Float16* obuf_hi = (_Float16*)(region + 2 * RS);
  _Float16* obuf_lo = obuf_hi + RS;
  float* rbuf = region + 3 * RS;                      // 16384*256 f32 = 0.5RS
  _Float16* mid_hi = (_Float16*)region;               // [16384*1024] halfs
  _Float16* mid_lo = mid_hi + (size_t)B_ * S_ * (M_ / 2);
  // hbuf planes at 14RS bytes
  _Float16* hbuf_hi = (_Float16*)(wsb + 14 * RS);
  _Float16* hbuf_lo = hbuf_hi + RS;
  // weight planes (per layer, transposed [n][k]) at 18RS bytes
  _Float16* whi = (_Float16*)(wsb + 18 * RS);
  _Float16* wlo = whi + WTOT;
  float* rotW2 = (float*)(wlo + WTOT);                // [512*256] f32
  int* buckets = (int*)(rotW2 + 512 * 256);
  int* stbuf   = buckets + B_ * H_ * S_;
  // total: 18RS bytes (151.0MB) + 11.5MB + 1.6MB ~= 164.1MB

  const size_t OQ = 0;
  const size_t OV = (size_t)D_ * D_;
  const size_t OO = 2 * (size_t)D_ * D_;
  const size_t O1 = 3 * (size_t)D_ * D_;              // W1_T: [M][D]
  const size_t O2 = O1 + (size_t)D_ * M_;             // W2_T: [D][M]

  const int rows = B_ * S_;                  // 16384
  const int Mh = M_ / 2;                     // 1024

  embed_kernel<<<rows, 128, 0, stream>>>(tokens, emb, x);

  for (int l = 0; l < L_; l++) {
    // weight convert+transpose for this layer
    transp_cvt<<<dim3(D_ / 32, D_ / 32), 256, 0, stream>>>(Wq + (size_t)l * D_ * D_, whi + OQ, wlo + OQ, D_, D_);
    transp_cvt<<<dim3(D_ / 32, D_ / 32), 256, 0, stream>>>(Wv + (size_t)l * D_ * D_, whi + OV, wlo + OV, D_, D_);
    transp_cvt<<<dim3(D_ / 32, D_ / 32), 256, 0, stream>>>(Wo + (size_t)l * D_ * D_, whi + OO, wlo + OO, D_, D_);
    transp_cvt<<<dim3(M_ / 32, D_ / 32), 256, 0, stream>>>(W1 + (size_t)l * D_ * M_, whi + O1, wlo + O1, D_, M_);
    transp_cvt<<<dim3(D_ / 32, M_ / 32), 256, 0, stream>>>(W2 + (size_t)l * M_ * D_, whi + O2, wlo + O2, M_, D_);

    ln_h<<<rows, 64, 0, stream>>>(x, hbuf_hi, hbuf_lo, ln1_s + (size_t)l * D_, ln1_b + (size_t)l * D_);

    dim3 g1(D_ / 128, rows / 128);
    gemm_h<0, 0, 0, 0><<<g1, 256, 0, stream>>>(hbuf_hi, hbuf_lo, whi + OQ, wlo + OQ, nullptr,
                                               qbuf, nullptr, nullptr, rows, D_, D_, D_, D_);
    gemm_h<0, 0, 0, 0><<<g1, 256, 0, stream>>>(hbuf_hi, hbuf_lo, whi + OV, wlo + OV, nullptr,
                                               vbuf, nullptr, nullptr, rows, D_, D_, D_, D_);

    rotw_kernel<<<(D_ * 256) / 256, 256, 0, stream>>>(Wq + (size_t)l * D_ * D_,
                                                      rot + (size_t)l * H_ * DH_ * 32, rotW2);
    dim3 gh(256 / 128, rows / 128);
    gemm_hash<<<gh, 256, 0, stream>>>(hbuf_hi, hbuf_lo, rotW2, rbuf, rows, 256, D_);
    argmax_kernel<<<(B_ * H_ * S_) / 256, 256, 0, stream>>>(rbuf, buckets);
    sort_kernel<<<B_ * H_, 64, 0, stream>>>(buckets, stbuf);
    attn_kernel<<<B_ * H_ * NC_, 256, 0, stream>>>(qbuf, vbuf, stbuf, obuf_hi, obuf_lo);

    gemm_h<0, 1, 0, 0><<<g1, 256, 0, stream>>>(obuf_hi, obuf_lo, whi + OO, wlo + OO, nullptr,
                                               x, nullptr, nullptr, rows, D_, D_, D_, D_);

    ln_h<<<rows, 64, 0, stream>>>(x, hbuf_hi, hbuf_lo, ln2_s + (size_t)l * D_, ln2_b + (size_t)l * D_);

    // FFN in two 1024-column halves (mid planes sized [rows][1024])
    for (int ch = 0; ch < 2; ch++) {
      dim3 gf1(Mh / 128, rows / 128);
      gemm_h<1, 0, 1, 1><<<gf1, 256, 0, stream>>>(hbuf_hi, hbuf_lo,
                                                  whi + O1 + (size_t)ch * Mh * D_,
                                                  wlo + O1 + (size_t)ch * Mh * D_,
                                                  b1 + (size_t)l * M_ + ch * Mh,
                                                  nullptr, mid_hi, mid_lo, rows, Mh, D_, D_, D_);
      dim3 gf2(D_ / 128, rows / 128);
      if (ch == 0) {
        gemm_h<0, 1, 0, 0><<<gf2, 256, 0, stream>>>(mid_hi, mid_lo,
                                                    whi + O2 + (size_t)ch * Mh,
                                                    wlo + O2 + (size_t)ch * Mh,
                                                    nullptr, x, nullptr, nullptr,
                                                    rows, D_, Mh, Mh, M_);
      } else {
        gemm_h<1, 1, 0, 0><<<gf2, 256, 0, stream>>>(mid_hi, mid_lo,
                                                    whi + O2 + (size_t)ch * Mh,
                                                    wlo + O2 + (size_t)ch * Mh,
                                                    b2 + (size_t)l * D_, x, nullptr, nullptr,
                                                    rows, D_, Mh, Mh, M_);
      }
    }
  }

  ln_f<<<rows, 64, 0, stream>>>(x, x, lnf_s, lnf_b);
}

// Round 9
// 3877.340 us; speedup vs baseline: 3.2381x; 1.1275x over previous
//
#include <hip/hip_runtime.h>

#define B_ 4
#define S_ 4096
#define D_ 512
#define H_ 8
#define L_ 6
#define M_ 2048
#define DH_ 64
#define NC_ 64   // number of chunks = S/C
#define C_ 64    // chunk length

typedef _Float16 half8 __attribute__((ext_vector_type(8)));
typedef _Float16 half4 __attribute__((ext_vector_type(4)));
typedef float f32x4 __attribute__((ext_vector_type(4)));

// ---------------------------------------------------------------------------
// Embedding + sinusoidal positional encoding (f64 PE recipe — r3 fix)
// ---------------------------------------------------------------------------
__global__ __launch_bounds__(128) void embed_kernel(const int* __restrict__ tokens,
                                                    const float* __restrict__ emb,
                                                    float* __restrict__ x) {
  int row = blockIdx.x;            // b*S + s
  int s = row & (S_ - 1);
  int tok = tokens[row];
  const float4* e = (const float4*)(emb + (size_t)tok * D_);
  float4* xo = (float4*)(x + (size_t)row * D_);
  int t = threadIdx.x;             // 128 threads, 4 floats each
  float4 ev = e[t];
  int d0 = t * 4;
  const double c64 = -9.210340371976184 / 255.0;   // -ln(10000)/(half-1)
  float pe[4];
#pragma unroll
  for (int j = 0; j < 4; j++) {
    int d = d0 + j;
    int i = (d < 256) ? d : d - 256;
    double freq = exp((double)i * c64);
    double arg = (double)s * freq;
    pe[j] = (d < 256) ? (float)sin(arg) : (float)cos(arg);
  }
  float4 o;
  o.x = ev.x + pe[0];
  o.y = ev.y + pe[1];
  o.z = ev.z + pe[2];
  o.w = ev.w + pe[3];
  xo[t] = o;
}

// ---------------------------------------------------------------------------
// LayerNorm variants. ln_h writes fp16 hi/lo planes (GEMM inputs);
// ln_f writes f32 (final LN only).
// ---------------------------------------------------------------------------
__device__ __forceinline__ void ln_core(const float* __restrict__ in, int row, int t,
                                        const float* __restrict__ sc,
                                        const float* __restrict__ bi,
                                        float4& o1, float4& o2) {
  const float4* ir = (const float4*)(in + (size_t)row * D_);
  float4 a = ir[t];
  float4 b4 = ir[t + 64];
  float sum = a.x + a.y + a.z + a.w + b4.x + b4.y + b4.z + b4.w;
  float sq  = a.x*a.x + a.y*a.y + a.z*a.z + a.w*a.w
            + b4.x*b4.x + b4.y*b4.y + b4.z*b4.z + b4.w*b4.w;
#pragma unroll
  for (int m = 1; m < 64; m <<= 1) {
    sum += __shfl_xor(sum, m);
    sq  += __shfl_xor(sq, m);
  }
  float mean = sum * (1.0f / 512.0f);
  float var  = sq * (1.0f / 512.0f) - mean * mean;
  float rstd = 1.0f / sqrtf(var + 1e-6f);
  float4 s1 = ((const float4*)sc)[t], s2 = ((const float4*)sc)[t + 64];
  float4 g1 = ((const float4*)bi)[t], g2 = ((const float4*)bi)[t + 64];
  o1.x = (a.x - mean) * rstd * s1.x + g1.x;
  o1.y = (a.y - mean) * rstd * s1.y + g1.y;
  o1.z = (a.z - mean) * rstd * s1.z + g1.z;
  o1.w = (a.w - mean) * rstd * s1.w + g1.w;
  o2.x = (b4.x - mean) * rstd * s2.x + g2.x;
  o2.y = (b4.y - mean) * rstd * s2.y + g2.y;
  o2.z = (b4.z - mean) * rstd * s2.z + g2.z;
  o2.w = (b4.w - mean) * rstd * s2.w + g2.w;
}

__global__ __launch_bounds__(64) void ln_h(const float* __restrict__ in,
                                           _Float16* __restrict__ hi,
                                           _Float16* __restrict__ lo,
                                           const float* __restrict__ sc,
                                           const float* __restrict__ bi) {
  int row = blockIdx.x, t = threadIdx.x;
  float4 o1, o2;
  ln_core(in, row, t, sc, bi, o1, o2);
  float v1[4] = {o1.x, o1.y, o1.z, o1.w};
  float v2[4] = {o2.x, o2.y, o2.z, o2.w};
  half4 h1, l1, h2, l2;
#pragma unroll
  for (int j = 0; j < 4; j++) {
    _Float16 h = (_Float16)v1[j];
    h1[j] = h; l1[j] = (_Float16)(v1[j] - (float)h);
    _Float16 g = (_Float16)v2[j];
    h2[j] = g; l2[j] = (_Float16)(v2[j] - (float)g);
  }
  size_t base = (size_t)row * D_;
  *(half4*)&hi[base + t * 4] = h1;
  *(half4*)&hi[base + 256 + t * 4] = h2;
  *(half4*)&lo[base + t * 4] = l1;
  *(half4*)&lo[base + 256 + t * 4] = l2;
}

__global__ __launch_bounds__(64) void ln_f(const float* __restrict__ in,
                                           float* __restrict__ out,
                                           const float* __restrict__ sc,
                                           const float* __restrict__ bi) {
  int row = blockIdx.x, t = threadIdx.x;
  float4 o1, o2;
  ln_core(in, row, t, sc, bi, o1, o2);
  float4* orow = (float4*)(out + (size_t)row * D_);
  orow[t] = o1;
  orow[t + 64] = o2;
}

__device__ __forceinline__ float gelu_f(float v) {
  float v3 = v * v * v;
  return 0.5f * v * (1.0f + tanhf(0.7978845608028654f * (v + 0.044715f * v3)));
}

// ---------------------------------------------------------------------------
// Weight convert+transpose: src f32 [K][N] -> dst hi/lo fp16 [N][K].
// ---------------------------------------------------------------------------
__global__ __launch_bounds__(256) void transp_cvt(const float* __restrict__ src,
                                                  _Float16* __restrict__ dhi,
                                                  _Float16* __restrict__ dlo,
                                                  int K, int N) {
  __shared__ float tile[32][33];
  int n0 = blockIdx.x * 32, k0 = blockIdx.y * 32;
  int tx = threadIdx.x & 31, ty = threadIdx.x >> 5;   // ty 0..7
#pragma unroll
  for (int i = 0; i < 4; i++)
    tile[ty + 8 * i][tx] = src[(size_t)(k0 + ty + 8 * i) * N + n0 + tx];
  __syncthreads();
#pragma unroll
  for (int i = 0; i < 4; i++) {
    int n = n0 + ty + 8 * i;
    float v = tile[tx][ty + 8 * i];
    _Float16 h = (_Float16)v;
    dhi[(size_t)n * K + k0 + tx] = h;
    dlo[(size_t)n * K + k0 + tx] = (_Float16)(v - (float)h);
  }
}

// ---------------------------------------------------------------------------
// fp16x3 split MFMA GEMM with pre-converted fp16 hi/lo inputs.
// A: [M][lda] planes, B: [N][ldb] planes (pre-transposed weights).
// ---------------------------------------------------------------------------
template <int HAS_BIAS, int RESID, int DO_GELU, int OUT_HALF>
__global__ __launch_bounds__(256) void gemm_h(const _Float16* __restrict__ Ahi,
                                              const _Float16* __restrict__ Alo,
                                              const _Float16* __restrict__ Bhi,
                                              const _Float16* __restrict__ Blo,
                                              const float* __restrict__ bias,
                                              float* __restrict__ C,
                                              _Float16* __restrict__ Chi,
                                              _Float16* __restrict__ Clo,
                                              int M, int N, int K, int lda, int ldb) {
  __shared__ _Float16 Ah[128 * 40];
  __shared__ _Float16 Al[128 * 40];
  __shared__ _Float16 Bh[128 * 40];
  __shared__ _Float16 Bl[128 * 40];
  int tid = threadIdx.x;
  int row0 = blockIdx.y * 128, col0 = blockIdx.x * 128;
  int lane = tid & 63, wid = tid >> 6;
  int wm = wid >> 1, wn = wid & 1;
  int fr = lane & 15, fk = (lane >> 4) * 8;
  int sr = tid >> 1, sk = (tid & 1) * 16;

  const _Float16* pAh = Ahi + (size_t)(row0 + sr) * lda + sk;
  const _Float16* pAl = Alo + (size_t)(row0 + sr) * lda + sk;
  const _Float16* pBh = Bhi + (size_t)(col0 + sr) * ldb + sk;
  const _Float16* pBl = Blo + (size_t)(col0 + sr) * ldb + sk;

  f32x4 acc[4][4];
#pragma unroll
  for (int m = 0; m < 4; m++)
#pragma unroll
    for (int n = 0; n < 4; n++) acc[m][n] = (f32x4){0.f, 0.f, 0.f, 0.f};

  half8 rah0 = *(const half8*)pAh, rah1 = *(const half8*)(pAh + 8);
  half8 ral0 = *(const half8*)pAl, ral1 = *(const half8*)(pAl + 8);
  half8 rbh0 = *(const half8*)pBh, rbh1 = *(const half8*)(pBh + 8);
  half8 rbl0 = *(const half8*)pBl, rbl1 = *(const half8*)(pBl + 8);

  int nst = K >> 5;
  for (int s = 0; s < nst; ++s) {
    __syncthreads();
    *(half8*)&Ah[sr * 40 + sk] = rah0; *(half8*)&Ah[sr * 40 + sk + 8] = rah1;
    *(half8*)&Al[sr * 40 + sk] = ral0; *(half8*)&Al[sr * 40 + sk + 8] = ral1;
    *(half8*)&Bh[sr * 40 + sk] = rbh0; *(half8*)&Bh[sr * 40 + sk + 8] = rbh1;
    *(half8*)&Bl[sr * 40 + sk] = rbl0; *(half8*)&Bl[sr * 40 + sk + 8] = rbl1;
    __syncthreads();
    if (s + 1 < nst) {
      int off = (s + 1) * 32;
      rah0 = *(const half8*)(pAh + off); rah1 = *(const half8*)(pAh + off + 8);
      ral0 = *(const half8*)(pAl + off); ral1 = *(const half8*)(pAl + off + 8);
      rbh0 = *(const half8*)(pBh + off); rbh1 = *(const half8*)(pBh + off + 8);
      rbl0 = *(const half8*)(pBl + off); rbl1 = *(const half8*)(pBl + off + 8);
    }
    half8 bhf[4], blf[4];
#pragma unroll
    for (int n = 0; n < 4; n++) {
      int col = wn * 64 + n * 16 + fr;
      bhf[n] = *(half8*)&Bh[col * 40 + fk];
      blf[n] = *(half8*)&Bl[col * 40 + fk];
    }
#pragma unroll
    for (int m = 0; m < 4; m++) {
      int row = wm * 64 + m * 16 + fr;
      half8 ah = *(half8*)&Ah[row * 40 + fk];
      half8 al = *(half8*)&Al[row * 40 + fk];
#pragma unroll
      for (int n = 0; n < 4; n++)
        acc[m][n] = __builtin_amdgcn_mfma_f32_16x16x32_f16(ah, bhf[n], acc[m][n], 0, 0, 0);
#pragma unroll
      for (int n = 0; n < 4; n++)
        acc[m][n] = __builtin_amdgcn_mfma_f32_16x16x32_f16(al, bhf[n], acc[m][n], 0, 0, 0);
#pragma unroll
      for (int n = 0; n < 4; n++)
        acc[m][n] = __builtin_amdgcn_mfma_f32_16x16x32_f16(ah, blf[n], acc[m][n], 0, 0, 0);
    }
  }

  // ---- epilogue ----
#pragma unroll
  for (int n = 0; n < 4; n++) {
    int col = col0 + wn * 64 + n * 16 + fr;
    float bv = HAS_BIAS ? bias[col] : 0.f;
#pragma unroll
    for (int m = 0; m < 4; m++) {
      int rowb = row0 + wm * 64 + m * 16 + (lane >> 4) * 4;
#pragma unroll
      for (int r = 0; r < 4; r++) {
        float val = acc[m][n][r] + bv;
        if (DO_GELU) val = gelu_f(val);
        size_t idx = (size_t)(rowb + r) * N + col;
        if (OUT_HALF) {
          _Float16 h = (_Float16)val;
          Chi[idx] = h;
          Clo[idx] = (_Float16)(val - (float)h);
        } else {
          if (RESID) val += C[idx];
          C[idx] = val;
        }
      }
    }
  }
}

// ---------------------------------------------------------------------------
// f32 hash GEMM: A reconstructed from hi/lo planes (exact f32 sum),
// W (rotW2) f32. Bucket-decision path.
// ---------------------------------------------------------------------------
__global__ __launch_bounds__(256) void gemm_hash(const _Float16* __restrict__ Ahi,
                                                 const _Float16* __restrict__ Alo,
                                                 const float* __restrict__ W,
                                                 float* __restrict__ Cout,
                                                 int M, int N, int K) {
  __shared__ float As[16][132];   // [k][m], padded
  __shared__ float Bs[16][132];   // [k][n], padded
  int tid = threadIdx.x;
  int bn = blockIdx.x, bm = blockIdx.y;
  int row0 = bm * 128, col0 = bn * 128;
  int tr = tid >> 4, tc = tid & 15;       // 16x16 threads
  float acc[2][2][4][4] = {};             // [mq][nq][i][j]

  int la_r = tid >> 1;               // 0..127  A row within tile
  int la_c = (tid & 1) * 8;          // 0 or 8
  int lb_r = tid >> 4;               // 0..15   B row within tile
  int lb_c = (tid & 15) * 8;         // 0..120

  for (int k0 = 0; k0 < K; k0 += 16) {
    half8 hv = *(const half8*)(Ahi + (size_t)(row0 + la_r) * K + k0 + la_c);
    half8 lv = *(const half8*)(Alo + (size_t)(row0 + la_r) * K + k0 + la_c);
#pragma unroll
    for (int j = 0; j < 8; j++)
      As[la_c + j][la_r] = (float)hv[j] + (float)lv[j];
    const float* wp = W + (size_t)(k0 + lb_r) * N + col0 + lb_c;
    *(float4*)&Bs[lb_r][lb_c] = *(const float4*)wp;
    *(float4*)&Bs[lb_r][lb_c + 4] = *(const float4*)(wp + 4);
    __syncthreads();
#pragma unroll
    for (int kk = 0; kk < 16; kk++) {
      float4 amq[2], bnq[2];
      amq[0] = *(const float4*)&As[kk][tr * 4];
      amq[1] = *(const float4*)&As[kk][64 + tr * 4];
      bnq[0] = *(const float4*)&Bs[kk][tc * 4];
      bnq[1] = *(const float4*)&Bs[kk][64 + tc * 4];
#pragma unroll
      for (int mq = 0; mq < 2; mq++) {
        float a0f = amq[mq].x, a1f = amq[mq].y, a2f = amq[mq].z, a3f = amq[mq].w;
#pragma unroll
        for (int nq = 0; nq < 2; nq++) {
          float b0 = bnq[nq].x, b1 = bnq[nq].y, b2 = bnq[nq].z, b3 = bnq[nq].w;
          acc[mq][nq][0][0] += a0f * b0; acc[mq][nq][0][1] += a0f * b1;
          acc[mq][nq][0][2] += a0f * b2; acc[mq][nq][0][3] += a0f * b3;
          acc[mq][nq][1][0] += a1f * b0; acc[mq][nq][1][1] += a1f * b1;
          acc[mq][nq][1][2] += a1f * b2; acc[mq][nq][1][3] += a1f * b3;
          acc[mq][nq][2][0] += a2f * b0; acc[mq][nq][2][1] += a2f * b1;
          acc[mq][nq][2][2] += a2f * b2; acc[mq][nq][2][3] += a2f * b3;
          acc[mq][nq][3][0] += a3f * b0; acc[mq][nq][3][1] += a3f * b1;
          acc[mq][nq][3][2] += a3f * b2; acc[mq][nq][3][3] += a3f * b3;
        }
      }
    }
    __syncthreads();
  }

#pragma unroll
  for (int mq = 0; mq < 2; mq++) {
#pragma unroll
    for (int i = 0; i < 4; i++) {
      int row = row0 + mq * 64 + tr * 4 + i;
#pragma unroll
      for (int nq = 0; nq < 2; nq++) {
        float* cp = Cout + (size_t)row * N + col0 + nq * 64 + tc * 4;
        float4 vv;
        vv.x = acc[mq][nq][i][0]; vv.y = acc[mq][nq][i][1];
        vv.z = acc[mq][nq][i][2]; vv.w = acc[mq][nq][i][3];
        *(float4*)cp = vv;
      }
    }
  }
}

// ---------------------------------------------------------------------------
// rotW2[d][h*32+j] = sum_f Wq[d][h*64+f] * rot[h][f][j]  (f64 acc, f32 store)
// ---------------------------------------------------------------------------
__global__ __launch_bounds__(256) void rotw_kernel(const float* __restrict__ Wq,
                                                   const float* __restrict__ rot,
                                                   float* __restrict__ rotW2) {
  int idx = blockIdx.x * 256 + threadIdx.x;   // d*256 + h*32 + j, 512*256 total
  int n = idx & 255;
  int d = idx >> 8;
  int h = n >> 5;
  int j = n & 31;
  double a = 0.0;
#pragma unroll 8
  for (int f = 0; f < 64; f++) {
    a += (double)Wq[(size_t)d * D_ + h * 64 + f] * (double)rot[((size_t)h * 64 + f) * 32 + j];
  }
  rotW2[idx] = (float)a;
}

// ---------------------------------------------------------------------------
// Per-token bucket argmax over [r, -r] (first-index ties, like np.argmax).
// ---------------------------------------------------------------------------
__global__ __launch_bounds__(256) void argmax_kernel(const float* __restrict__ rbuf,
                                                     int* __restrict__ buckets) {
  int gid = blockIdx.x * 256 + threadIdx.x;   // b*H*S + h*S + s
  int s = gid & (S_ - 1);
  int bh = gid >> 12;
  int h = bh & (H_ - 1);
  int b = bh >> 3;
  const float* rp = rbuf + ((size_t)b * S_ + s) * 256 + h * 32;
  float r[32];
#pragma unroll
  for (int j4 = 0; j4 < 8; j4++) {
    float4 t4 = *(const float4*)(rp + j4 * 4);
    r[j4 * 4 + 0] = t4.x; r[j4 * 4 + 1] = t4.y;
    r[j4 * 4 + 2] = t4.z; r[j4 * 4 + 3] = t4.w;
  }
  float best = r[0];
  int bi = 0;
#pragma unroll
  for (int j = 1; j < 64; j++) {
    float val = (j < 32) ? r[j] : -r[j - 32];
    if (val > best) { best = val; bi = j; }
  }
  buckets[gid] = bi;
}

// ---------------------------------------------------------------------------
// Stable counting sort by bucket (== argsort(bucket*S + pos)).
// ---------------------------------------------------------------------------
__global__ __launch_bounds__(64) void sort_kernel(const int* __restrict__ buckets,
                                                  int* __restrict__ st) {
  __shared__ int hist[64][64];   // [thread][bucket]
  __shared__ int boff[64];
  int bh = blockIdx.x;
  const int* bk = buckets + (size_t)bh * S_;
  int* stb = st + (size_t)bh * S_;
  int t = threadIdx.x;
  for (int j = 0; j < 64; j++) hist[t][j] = 0;
  __syncthreads();
  for (int i = 0; i < 64; i++) {
    int s = t * 64 + i;
    hist[t][bk[s]]++;
  }
  __syncthreads();
  int run = 0;
  for (int tt = 0; tt < 64; tt++) {
    int c = hist[tt][t];
    hist[tt][t] = run;
    run += c;
  }
  boff[t] = run;
  __syncthreads();
  if (t == 0) {
    int acc = 0;
    for (int j = 0; j < 64; j++) { int c = boff[j]; boff[j] = acc; acc += c; }
  }
  __syncthreads();
  for (int i = 0; i < 64; i++) {
    int s = t * 64 + i;
    int bkt = bk[s];
    int pos = boff[bkt] + hist[t][bkt];
    hist[t][bkt] = hist[t][bkt] + 1;
    stb[pos] = s;
  }
}

// ---------------------------------------------------------------------------
// MFMA chunked shared-QK attention (fp16x3, f32-class error).
// One block per (b,h,chunk), 4 waves. Wave w owns query rows w*16..w*16+15.
// LDS (halfs): Khi[128][72] @0, Klo @9216, VThi[64][136] @18432, VTlo @27136.
// P planes alias the K region after the post-QK barrier (K dead by then):
//   wave w: Phi @ w*4352, Plo @ w*4352+2176, pitch 136.
// Fragment layouts (m89, same as gemm_h): A row=lane&15,k=(lane>>4)*8+j;
// B col=lane&15, same k (storage [col][k]); C/D col=lane&15,row=(lane>>4)*4+reg.
// ---------------------------------------------------------------------------
#define KP 72
#define VP 136
__global__ __launch_bounds__(256) void attn_mfma(const _Float16* __restrict__ qhi,
                                                 const _Float16* __restrict__ qlo,
                                                 const _Float16* __restrict__ vhi,
                                                 const _Float16* __restrict__ vlo,
                                                 const int* __restrict__ st,
                                                 _Float16* __restrict__ ohi,
                                                 _Float16* __restrict__ olo) {
  __shared__ _Float16 lds[35840];   // 71680 B
  const int KH = 0, KL = 9216, VH = 18432, VL = 27136;
  int blk = blockIdx.x;
  int n = blk & (NC_ - 1);
  int bh = blk >> 6;
  int h = bh & (H_ - 1);
  int b = bh >> 3;
  const int* stbh = st + (size_t)bh * S_;
  int tid = threadIdx.x;
  int pn = (n + NC_ - 1) & (NC_ - 1);

  // ---- stage K (=Q) rows and V^T into LDS ----
  {
    int r = tid >> 1, dseg = (tid & 1) * 32;
    int si = (r < 64) ? (n * 64 + r) : (pn * 64 + (r - 64));
    int p = stbh[si];
    size_t gb = ((size_t)b * S_ + p) * D_ + h * 64 + dseg;
    half8 kh[4], kl[4], vh8[4], vl8[4];
#pragma unroll
    for (int j = 0; j < 4; j++) {
      kh[j] = *(const half8*)&qhi[gb + j * 8];
      kl[j] = *(const half8*)&qlo[gb + j * 8];
      vh8[j] = *(const half8*)&vhi[gb + j * 8];
      vl8[j] = *(const half8*)&vlo[gb + j * 8];
    }
#pragma unroll
    for (int j = 0; j < 4; j++) {
      *(half8*)&lds[KH + r * KP + dseg + j * 8] = kh[j];
      *(half8*)&lds[KL + r * KP + dseg + j * 8] = kl[j];
    }
#pragma unroll
    for (int j = 0; j < 4; j++) {
#pragma unroll
      for (int e = 0; e < 8; e++) {
        int dim = dseg + j * 8 + e;
        lds[VH + dim * VP + r] = vh8[j][e];
        lds[VL + dim * VP + r] = vl8[j][e];
      }
    }
  }
  __syncthreads();

  int lane = tid & 63, w = tid >> 6;
  int fr = lane & 15, fk8 = (lane >> 4) * 8;

  // ---- QK^T: wave w computes S[w*16..+16][0..128] ----
  int qrow = w * 16 + fr;
  half8 qh0 = *(half8*)&lds[KH + qrow * KP + fk8];
  half8 qh1 = *(half8*)&lds[KH + qrow * KP + 32 + fk8];
  half8 ql0 = *(half8*)&lds[KL + qrow * KP + fk8];
  half8 ql1 = *(half8*)&lds[KL + qrow * KP + 32 + fk8];

  f32x4 sa[8];
#pragma unroll
  for (int nc = 0; nc < 8; nc++) {
    int key = nc * 16 + fr;
    half8 bh0 = *(half8*)&lds[KH + key * KP + fk8];
    half8 bh1 = *(half8*)&lds[KH + key * KP + 32 + fk8];
    half8 bl0 = *(half8*)&lds[KL + key * KP + fk8];
    half8 bl1 = *(half8*)&lds[KL + key * KP + 32 + fk8];
    f32x4 a = (f32x4){0.f, 0.f, 0.f, 0.f};
    a = __builtin_amdgcn_mfma_f32_16x16x32_f16(qh0, bh0, a, 0, 0, 0);
    a = __builtin_amdgcn_mfma_f32_16x16x32_f16(qh1, bh1, a, 0, 0, 0);
    a = __builtin_amdgcn_mfma_f32_16x16x32_f16(ql0, bh0, a, 0, 0, 0);
    a = __builtin_amdgcn_mfma_f32_16x16x32_f16(ql1, bh1, a, 0, 0, 0);
    a = __builtin_amdgcn_mfma_f32_16x16x32_f16(qh0, bl0, a, 0, 0, 0);
    a = __builtin_amdgcn_mfma_f32_16x16x32_f16(qh1, bl1, a, 0, 0, 0);
    sa[nc] = a;
  }

  // ---- softmax over 128 keys per query row (row = (lane>>4)*4+reg) ----
  float inv[4];
#pragma unroll
  for (int reg = 0; reg < 4; reg++) {
    float m = sa[0][reg];
#pragma unroll
    for (int nc = 1; nc < 8; nc++) m = fmaxf(m, sa[nc][reg]);
    m = fmaxf(m, __shfl_xor(m, 1));
    m = fmaxf(m, __shfl_xor(m, 2));
    m = fmaxf(m, __shfl_xor(m, 4));
    m = fmaxf(m, __shfl_xor(m, 8));
    float s = 0.f;
#pragma unroll
    for (int nc = 0; nc < 8; nc++) {
      float e = expf(0.125f * (sa[nc][reg] - m));
      sa[nc][reg] = e;
      s += e;
    }
    s += __shfl_xor(s, 1);
    s += __shfl_xor(s, 2);
    s += __shfl_xor(s, 4);
    s += __shfl_xor(s, 8);
    inv[reg] = 1.0f / s;
  }

  __syncthreads();   // all waves done reading K region; safe to alias with P

  // ---- write P (= e/sum) hi/lo into per-wave LDS region ----
  int PW = w * 4352;
#pragma unroll
  for (int nc = 0; nc < 8; nc++) {
#pragma unroll
    for (int reg = 0; reg < 4; reg++) {
      float pv = sa[nc][reg] * inv[reg];
      _Float16 ph = (_Float16)pv;
      _Float16 pl = (_Float16)(pv - (float)ph);
      int prow = (lane >> 4) * 4 + reg;
      int key = nc * 16 + fr;
      lds[PW + prow * VP + key] = ph;
      lds[PW + 2176 + prow * VP + key] = pl;
    }
  }

  // ---- PV: O[16][64] per wave ----
  half8 ph8[4], pl8[4];
#pragma unroll
  for (int kt = 0; kt < 4; kt++) {
    ph8[kt] = *(half8*)&lds[PW + fr * VP + kt * 32 + fk8];
    pl8[kt] = *(half8*)&lds[PW + 2176 + fr * VP + kt * 32 + fk8];
  }
  f32x4 oa[4];
#pragma unroll
  for (int nco = 0; nco < 4; nco++) {
    int dim = nco * 16 + fr;
    f32x4 a = (f32x4){0.f, 0.f, 0.f, 0.f};
#pragma unroll
    for (int kt = 0; kt < 4; kt++) {
      half8 bvh = *(half8*)&lds[VH + dim * VP + kt * 32 + fk8];
      half8 bvl = *(half8*)&lds[VL + dim * VP + kt * 32 + fk8];
      a = __builtin_amdgcn_mfma_f32_16x16x32_f16(ph8[kt], bvh, a, 0, 0, 0);
      a = __builtin_amdgcn_mfma_f32_16x16x32_f16(pl8[kt], bvh, a, 0, 0, 0);
      a = __builtin_amdgcn_mfma_f32_16x16x32_f16(ph8[kt], bvl, a, 0, 0, 0);
    }
    oa[nco] = a;
  }

  // ---- epilogue: scatter to output planes (unsorted order) ----
#pragma unroll
  for (int reg = 0; reg < 4; reg++) {
    int qq = w * 16 + (lane >> 4) * 4 + reg;
    int p = stbh[n * 64 + qq];
    size_t ob = ((size_t)b * S_ + p) * D_ + h * 64;
#pragma unroll
    for (int nco = 0; nco < 4; nco++) {
      float val = oa[nco][reg];
      _Float16 hv = (_Float16)val;
      ohi[ob + nco * 16 + fr] = hv;
      olo[ob + nco * 16 + fr] = (_Float16)(val - (float)hv);
    }
  }
}

// ---------------------------------------------------------------------------
extern "C" void kernel_launch(void* const* d_in, const int* in_sizes, int n_in,
                              void* d_out, int out_size, void* d_ws, size_t ws_size,
                              hipStream_t stream) {
  const int*   tokens = (const int*)d_in[0];
  const float* emb    = (const float*)d_in[1];
  const float* rot    = (const float*)d_in[2];
  const float* ln1_s  = (const float*)d_in[3];
  const float* ln1_b  = (const float*)d_in[4];
  const float* Wq     = (const float*)d_in[5];
  const float* Wv     = (const float*)d_in[6];
  const float* Wo     = (const float*)d_in[7];
  const float* ln2_s  = (const float*)d_in[8];
  const float* ln2_b  = (const float*)d_in[9];
  const float* W1     = (const float*)d_in[10];
  const float* b1     = (const float*)d_in[11];
  const float* W2     = (const float*)d_in[12];
  const float* b2     = (const float*)d_in[13];
  const float* lnf_s  = (const float*)d_in[14];
  const float* lnf_b  = (const float*)d_in[15];

  float* x = (float*)d_out;                  // residual stream lives in d_out
  const size_t RS = (size_t)B_ * S_ * D_;    // 8388608 elements
  const size_t WTOT = 3 * (size_t)D_ * D_ + 2 * (size_t)D_ * M_;  // 2883584

  char* wsb = (char*)d_ws;
  // region: 14RS bytes, phase-aliased.
  //   attn phase: q planes[RS f32-equiv] | v planes[RS] | obuf planes[RS] | rbuf[0.5RS f32]
  //   FFN phase:  mid hi/lo planes [16384][1024] each
  float* region = (float*)wsb;
  _Float16* q_hi = (_Float16*)region;                 // [RS] halfs
  _Float16* q_lo = q_hi + RS;
  _Float16* v_hi = (_Float16*)(region + RS);
  _Float16* v_lo = v_hi + RS;
  _Float16* obuf_hi = (_Float16*)(region + 2 * RS);
  _Float16* obuf_lo = obuf_hi + RS;
  float* rbuf = region + 3 * RS;                      // 16384*256 f32 = 0.5RS
  _Float16* mid_hi = (_Float16*)region;               // [16384*1024] halfs (FFN phase)
  _Float16* mid_lo = mid_hi + (size_t)B_ * S_ * (M_ / 2);
  // hbuf planes at 14RS bytes
  _Float16* hbuf_hi = (_Float16*)(wsb + 14 * RS);
  _Float16* hbuf_lo = hbuf_hi + RS;
  // weight planes (per layer, transposed [n][k]) at 18RS bytes
  _Float16* whi = (_Float16*)(wsb + 18 * RS);
  _Float16* wlo = whi + WTOT;
  float* rotW2 = (float*)(wlo + WTOT);                // [512*256] f32
  int* buckets = (int*)(rotW2 + 512 * 256);
  int* stbuf   = buckets + B_ * H_ * S_;
  // total: 18RS bytes (151.0MB) + 11.5MB + 1.6MB ~= 164.1MB

  const size_t OQ = 0;
  const size_t OV = (size_t)D_ * D_;
  const size_t OO = 2 * (size_t)D_ * D_;
  const size_t O1 = 3 * (size_t)D_ * D_;              // W1_T: [M][D]
  const size_t O2 = O1 + (size_t)D_ * M_;             // W2_T: [D][M]

  const int rows = B_ * S_;                  // 16384
  const int Mh = M_ / 2;                     // 1024

  embed_kernel<<<rows, 128, 0, stream>>>(tokens, emb, x);

  for (int l = 0; l < L_; l++) {
    transp_cvt<<<dim3(D_ / 32, D_ / 32), 256, 0, stream>>>(Wq + (size_t)l * D_ * D_, whi + OQ, wlo + OQ, D_, D_);
    transp_cvt<<<dim3(D_ / 32, D_ / 32), 256, 0, stream>>>(Wv + (size_t)l * D_ * D_, whi + OV, wlo + OV, D_, D_);
    transp_cvt<<<dim3(D_ / 32, D_ / 32), 256, 0, stream>>>(Wo + (size_t)l * D_ * D_, whi + OO, wlo + OO, D_, D_);
    transp_cvt<<<dim3(M_ / 32, D_ / 32), 256, 0, stream>>>(W1 + (size_t)l * D_ * M_, whi + O1, wlo + O1, D_, M_);
    transp_cvt<<<dim3(D_ / 32, M_ / 32), 256, 0, stream>>>(W2 + (size_t)l * M_ * D_, whi + O2, wlo + O2, M_, D_);

    ln_h<<<rows, 64, 0, stream>>>(x, hbuf_hi, hbuf_lo, ln1_s + (size_t)l * D_, ln1_b + (size_t)l * D_);

    dim3 g1(D_ / 128, rows / 128);
    gemm_h<0, 0, 0, 1><<<g1, 256, 0, stream>>>(hbuf_hi, hbuf_lo, whi + OQ, wlo + OQ, nullptr,
                                               nullptr, q_hi, q_lo, rows, D_, D_, D_, D_);
    gemm_h<0, 0, 0, 1><<<g1, 256, 0, stream>>>(hbuf_hi, hbuf_lo, whi + OV, wlo + OV, nullptr,
                                               nullptr, v_hi, v_lo, rows, D_, D_, D_, D_);

    rotw_kernel<<<(D_ * 256) / 256, 256, 0, stream>>>(Wq + (size_t)l * D_ * D_,
                                                      rot + (size_t)l * H_ * DH_ * 32, rotW2);
    dim3 gh(256 / 128, rows / 128);
    gemm_hash<<<gh, 256, 0, stream>>>(hbuf_hi, hbuf_lo, rotW2, rbuf, rows, 256, D_);
    argmax_kernel<<<(B_ * H_ * S_) / 256, 256, 0, stream>>>(rbuf, buckets);
    sort_kernel<<<B_ * H_, 64, 0, stream>>>(buckets, stbuf);
    attn_mfma<<<B_ * H_ * NC_, 256, 0, stream>>>(q_hi, q_lo, v_hi, v_lo, stbuf, obuf_hi, obuf_lo);

    gemm_h<0, 1, 0, 0><<<g1, 256, 0, stream>>>(obuf_hi, obuf_lo, whi + OO, wlo + OO, nullptr,
                                               x, nullptr, nullptr, rows, D_, D_, D_, D_);

    ln_h<<<rows, 64, 0, stream>>>(x, hbuf_hi, hbuf_lo, ln2_s + (size_t)l * D_, ln2_b + (size_t)l * D_);

    // FFN in two 1024-column halves (mid planes sized [rows][1024])
    for (int ch = 0; ch < 2; ch++) {
      dim3 gf1(Mh / 128, rows / 128);
      gemm_h<1, 0, 1, 1><<<gf1, 256, 0, stream>>>(hbuf_hi, hbuf_lo,
                                                  whi + O1 + (size_t)ch * Mh * D_,
                                                  wlo + O1 + (size_t)ch * Mh * D_,
                                                  b1 + (size_t)l * M_ + ch * Mh,
                                                  nullptr, mid_hi, mid_lo, rows, Mh, D_, D_, D_);
      dim3 gf2(D_ / 128, rows / 128);
      if (ch == 0) {
        gemm_h<0, 1, 0, 0><<<gf2, 256, 0, stream>>>(mid_hi, mid_lo,
                                                    whi + O2 + (size_t)ch * Mh,
                                                    wlo + O2 + (size_t)ch * Mh,
                                                    nullptr, x, nullptr, nullptr,
                                                    rows, D_, Mh, Mh, M_);
      } else {
        gemm_h<1, 1, 0, 0><<<gf2, 256, 0, stream>>>(mid_hi, mid_lo,
                                                    whi + O2 + (size_t)ch * Mh,
                                                    wlo + O2 + (size_t)ch * Mh,
                                                    b2 + (size_t)l * D_, x, nullptr, nullptr,
                                                    rows, D_, Mh, Mh, M_);
      }
    }
  }

  ln_f<<<rows, 64, 0, stream>>>(x, x, lnf_s, lnf_b);
}

// Round 10
// 3671.177 us; speedup vs baseline: 3.4199x; 1.0562x over previous
//
#include <hip/hip_runtime.h>

#define B_ 4
#define S_ 4096
#define D_ 512
#define H_ 8
#define L_ 6
#define M_ 2048
#define DH_ 64
#define NC_ 64   // number of chunks = S/C
#define C_ 64    // chunk length

typedef _Float16 half8 __attribute__((ext_vector_type(8)));
typedef _Float16 half4 __attribute__((ext_vector_type(4)));
typedef float f32x4 __attribute__((ext_vector_type(4)));

typedef const __attribute__((address_space(1))) unsigned int gu32;
typedef __attribute__((address_space(3))) unsigned int lu32;

// ---------------------------------------------------------------------------
// Embedding + sinusoidal positional encoding (f64 PE recipe — r3 fix)
// ---------------------------------------------------------------------------
__global__ __launch_bounds__(128) void embed_kernel(const int* __restrict__ tokens,
                                                    const float* __restrict__ emb,
                                                    float* __restrict__ x) {
  int row = blockIdx.x;            // b*S + s
  int s = row & (S_ - 1);
  int tok = tokens[row];
  const float4* e = (const float4*)(emb + (size_t)tok * D_);
  float4* xo = (float4*)(x + (size_t)row * D_);
  int t = threadIdx.x;             // 128 threads, 4 floats each
  float4 ev = e[t];
  int d0 = t * 4;
  const double c64 = -9.210340371976184 / 255.0;   // -ln(10000)/(half-1)
  float pe[4];
#pragma unroll
  for (int j = 0; j < 4; j++) {
    int d = d0 + j;
    int i = (d < 256) ? d : d - 256;
    double freq = exp((double)i * c64);
    double arg = (double)s * freq;
    pe[j] = (d < 256) ? (float)sin(arg) : (float)cos(arg);
  }
  float4 o;
  o.x = ev.x + pe[0];
  o.y = ev.y + pe[1];
  o.z = ev.z + pe[2];
  o.w = ev.w + pe[3];
  xo[t] = o;
}

// ---------------------------------------------------------------------------
// LayerNorm variants. ln_h writes fp16 hi/lo planes; ln_f writes f32.
// ---------------------------------------------------------------------------
__device__ __forceinline__ void ln_core(const float* __restrict__ in, int row, int t,
                                        const float* __restrict__ sc,
                                        const float* __restrict__ bi,
                                        float4& o1, float4& o2) {
  const float4* ir = (const float4*)(in + (size_t)row * D_);
  float4 a = ir[t];
  float4 b4 = ir[t + 64];
  float sum = a.x + a.y + a.z + a.w + b4.x + b4.y + b4.z + b4.w;
  float sq  = a.x*a.x + a.y*a.y + a.z*a.z + a.w*a.w
            + b4.x*b4.x + b4.y*b4.y + b4.z*b4.z + b4.w*b4.w;
#pragma unroll
  for (int m = 1; m < 64; m <<= 1) {
    sum += __shfl_xor(sum, m);
    sq  += __shfl_xor(sq, m);
  }
  float mean = sum * (1.0f / 512.0f);
  float var  = sq * (1.0f / 512.0f) - mean * mean;
  float rstd = 1.0f / sqrtf(var + 1e-6f);
  float4 s1 = ((const float4*)sc)[t], s2 = ((const float4*)sc)[t + 64];
  float4 g1 = ((const float4*)bi)[t], g2 = ((const float4*)bi)[t + 64];
  o1.x = (a.x - mean) * rstd * s1.x + g1.x;
  o1.y = (a.y - mean) * rstd * s1.y + g1.y;
  o1.z = (a.z - mean) * rstd * s1.z + g1.z;
  o1.w = (a.w - mean) * rstd * s1.w + g1.w;
  o2.x = (b4.x - mean) * rstd * s2.x + g2.x;
  o2.y = (b4.y - mean) * rstd * s2.y + g2.y;
  o2.z = (b4.z - mean) * rstd * s2.z + g2.z;
  o2.w = (b4.w - mean) * rstd * s2.w + g2.w;
}

__global__ __launch_bounds__(64) void ln_h(const float* __restrict__ in,
                                           _Float16* __restrict__ hi,
                                           _Float16* __restrict__ lo,
                                           const float* __restrict__ sc,
                                           const float* __restrict__ bi) {
  int row = blockIdx.x, t = threadIdx.x;
  float4 o1, o2;
  ln_core(in, row, t, sc, bi, o1, o2);
  float v1[4] = {o1.x, o1.y, o1.z, o1.w};
  float v2[4] = {o2.x, o2.y, o2.z, o2.w};
  half4 h1, l1, h2, l2;
#pragma unroll
  for (int j = 0; j < 4; j++) {
    _Float16 h = (_Float16)v1[j];
    h1[j] = h; l1[j] = (_Float16)(v1[j] - (float)h);
    _Float16 g = (_Float16)v2[j];
    h2[j] = g; l2[j] = (_Float16)(v2[j] - (float)g);
  }
  size_t base = (size_t)row * D_;
  *(half4*)&hi[base + t * 4] = h1;
  *(half4*)&hi[base + 256 + t * 4] = h2;
  *(half4*)&lo[base + t * 4] = l1;
  *(half4*)&lo[base + 256 + t * 4] = l2;
}

__global__ __launch_bounds__(64) void ln_f(const float* __restrict__ in,
                                           float* __restrict__ out,
                                           const float* __restrict__ sc,
                                           const float* __restrict__ bi) {
  int row = blockIdx.x, t = threadIdx.x;
  float4 o1, o2;
  ln_core(in, row, t, sc, bi, o1, o2);
  float4* orow = (float4*)(out + (size_t)row * D_);
  orow[t] = o1;
  orow[t + 64] = o2;
}

__device__ __forceinline__ float gelu_f(float v) {
  float v3 = v * v * v;
  return 0.5f * v * (1.0f + tanhf(0.7978845608028654f * (v + 0.044715f * v3)));
}

// ---------------------------------------------------------------------------
// Weight convert+transpose: src f32 [K][N] -> dst hi/lo fp16 [N][K].
// ---------------------------------------------------------------------------
__global__ __launch_bounds__(256) void transp_cvt(const float* __restrict__ src,
                                                  _Float16* __restrict__ dhi,
                                                  _Float16* __restrict__ dlo,
                                                  int K, int N) {
  __shared__ float tile[32][33];
  int n0 = blockIdx.x * 32, k0 = blockIdx.y * 32;
  int tx = threadIdx.x & 31, ty = threadIdx.x >> 5;   // ty 0..7
#pragma unroll
  for (int i = 0; i < 4; i++)
    tile[ty + 8 * i][tx] = src[(size_t)(k0 + ty + 8 * i) * N + n0 + tx];
  __syncthreads();
#pragma unroll
  for (int i = 0; i < 4; i++) {
    int n = n0 + ty + 8 * i;
    float v = tile[tx][ty + 8 * i];
    _Float16 h = (_Float16)v;
    dhi[(size_t)n * K + k0 + tx] = h;
    dlo[(size_t)n * K + k0 + tx] = (_Float16)(v - (float)h);
  }
}

// ---------------------------------------------------------------------------
// fp16x3 split MFMA GEMM, global_load_lds double-buffered (m97 structure).
// A: [M][lda] planes, B: [N][ldb] planes. 128x128 tile, BK=32, 4 waves.
// LDS: 2 buffers x 4 planes x [128][32] halfs, linear (gload requirement).
// Wave w stages plane w (8 x 1KB gload calls); one barrier per K-step.
// ---------------------------------------------------------------------------
template <int HAS_BIAS, int RESID, int DO_GELU, int OUT_HALF>
__global__ __launch_bounds__(256) void gemm_h(const _Float16* __restrict__ Ahi,
                                              const _Float16* __restrict__ Alo,
                                              const _Float16* __restrict__ Bhi,
                                              const _Float16* __restrict__ Blo,
                                              const float* __restrict__ bias,
                                              float* __restrict__ C,
                                              _Float16* __restrict__ Chi,
                                              _Float16* __restrict__ Clo,
                                              int M, int N, int K, int lda, int ldb) {
  __shared__ _Float16 lds[2][4][128 * 32];   // 64 KB
  int tid = threadIdx.x;
  int row0 = blockIdx.y * 128, col0 = blockIdx.x * 128;
  int lane = tid & 63, w = tid >> 6;
  int wm = w >> 1, wn = w & 1;
  int fr = lane & 15, fk = (lane >> 4) * 8;

  // per-lane global source: wave w stages plane w
  int sld = (w < 2) ? lda : ldb;
  int sbase = (w < 2) ? row0 : col0;
  const _Float16* plane = (w == 0) ? Ahi : (w == 1) ? Alo : (w == 2) ? Bhi : Blo;
  const _Float16* gsrc = plane + (size_t)(sbase + (lane >> 2)) * sld + (lane & 3) * 8;
  size_t rowstep = (size_t)16 * sld;   // 16 rows per 1KB chunk

  f32x4 acc[4][4];
#pragma unroll
  for (int m = 0; m < 4; m++)
#pragma unroll
    for (int n = 0; n < 4; n++) acc[m][n] = (f32x4){0.f, 0.f, 0.f, 0.f};

  int nst = K >> 5;
  // prologue: stage step 0 into buffer 0
#pragma unroll
  for (int i = 0; i < 8; i++) {
    __builtin_amdgcn_global_load_lds((gu32*)(gsrc + (size_t)i * rowstep),
                                     (lu32*)&lds[0][w][i * 512], 16, 0, 0);
  }
  __syncthreads();

  int cur = 0;
  for (int s = 0; s < nst; ++s) {
    if (s + 1 < nst) {
      const _Float16* g = gsrc + (size_t)(s + 1) * 32;
#pragma unroll
      for (int i = 0; i < 8; i++) {
        __builtin_amdgcn_global_load_lds((gu32*)(g + (size_t)i * rowstep),
                                         (lu32*)&lds[cur ^ 1][w][i * 512], 16, 0, 0);
      }
    }
    const _Float16* Ah_ = lds[cur][0];
    const _Float16* Al_ = lds[cur][1];
    const _Float16* Bh_ = lds[cur][2];
    const _Float16* Bl_ = lds[cur][3];
    half8 bhf[4], blf[4];
#pragma unroll
    for (int n = 0; n < 4; n++) {
      int col = wn * 64 + n * 16 + fr;
      bhf[n] = *(const half8*)&Bh_[col * 32 + fk];
      blf[n] = *(const half8*)&Bl_[col * 32 + fk];
    }
#pragma unroll
    for (int m = 0; m < 4; m++) {
      int row = wm * 64 + m * 16 + fr;
      half8 ah = *(const half8*)&Ah_[row * 32 + fk];
      half8 al = *(const half8*)&Al_[row * 32 + fk];
#pragma unroll
      for (int n = 0; n < 4; n++)
        acc[m][n] = __builtin_amdgcn_mfma_f32_16x16x32_f16(ah, bhf[n], acc[m][n], 0, 0, 0);
#pragma unroll
      for (int n = 0; n < 4; n++)
        acc[m][n] = __builtin_amdgcn_mfma_f32_16x16x32_f16(al, bhf[n], acc[m][n], 0, 0, 0);
#pragma unroll
      for (int n = 0; n < 4; n++)
        acc[m][n] = __builtin_amdgcn_mfma_f32_16x16x32_f16(ah, blf[n], acc[m][n], 0, 0, 0);
    }
    __syncthreads();   // drains gload vmcnt + lds reads; flips buffer safely
    cur ^= 1;
  }

  // ---- epilogue ----
#pragma unroll
  for (int n = 0; n < 4; n++) {
    int col = col0 + wn * 64 + n * 16 + fr;
    float bv = HAS_BIAS ? bias[col] : 0.f;
#pragma unroll
    for (int m = 0; m < 4; m++) {
      int rowb = row0 + wm * 64 + m * 16 + (lane >> 4) * 4;
#pragma unroll
      for (int r = 0; r < 4; r++) {
        float val = acc[m][n][r] + bv;
        if (DO_GELU) val = gelu_f(val);
        size_t idx = (size_t)(rowb + r) * N + col;
        if (OUT_HALF) {
          _Float16 h = (_Float16)val;
          Chi[idx] = h;
          Clo[idx] = (_Float16)(val - (float)h);
        } else {
          if (RESID) val += C[idx];
          C[idx] = val;
        }
      }
    }
  }
}

// ---------------------------------------------------------------------------
// f32 hash GEMM: A reconstructed from hi/lo planes (exact f32 sum),
// W (rotW2) f32. Bucket-decision path.
// ---------------------------------------------------------------------------
__global__ __launch_bounds__(256) void gemm_hash(const _Float16* __restrict__ Ahi,
                                                 const _Float16* __restrict__ Alo,
                                                 const float* __restrict__ W,
                                                 float* __restrict__ Cout,
                                                 int M, int N, int K) {
  __shared__ float As[16][132];   // [k][m], padded
  __shared__ float Bs[16][132];   // [k][n], padded
  int tid = threadIdx.x;
  int bn = blockIdx.x, bm = blockIdx.y;
  int row0 = bm * 128, col0 = bn * 128;
  int tr = tid >> 4, tc = tid & 15;       // 16x16 threads
  float acc[2][2][4][4] = {};             // [mq][nq][i][j]

  int la_r = tid >> 1;               // 0..127  A row within tile
  int la_c = (tid & 1) * 8;          // 0 or 8
  int lb_r = tid >> 4;               // 0..15   B row within tile
  int lb_c = (tid & 15) * 8;         // 0..120

  for (int k0 = 0; k0 < K; k0 += 16) {
    half8 hv = *(const half8*)(Ahi + (size_t)(row0 + la_r) * K + k0 + la_c);
    half8 lv = *(const half8*)(Alo + (size_t)(row0 + la_r) * K + k0 + la_c);
#pragma unroll
    for (int j = 0; j < 8; j++)
      As[la_c + j][la_r] = (float)hv[j] + (float)lv[j];
    const float* wp = W + (size_t)(k0 + lb_r) * N + col0 + lb_c;
    *(float4*)&Bs[lb_r][lb_c] = *(const float4*)wp;
    *(float4*)&Bs[lb_r][lb_c + 4] = *(const float4*)(wp + 4);
    __syncthreads();
#pragma unroll
    for (int kk = 0; kk < 16; kk++) {
      float4 amq[2], bnq[2];
      amq[0] = *(const float4*)&As[kk][tr * 4];
      amq[1] = *(const float4*)&As[kk][64 + tr * 4];
      bnq[0] = *(const float4*)&Bs[kk][tc * 4];
      bnq[1] = *(const float4*)&Bs[kk][64 + tc * 4];
#pragma unroll
      for (int mq = 0; mq < 2; mq++) {
        float a0f = amq[mq].x, a1f = amq[mq].y, a2f = amq[mq].z, a3f = amq[mq].w;
#pragma unroll
        for (int nq = 0; nq < 2; nq++) {
          float b0 = bnq[nq].x, b1 = bnq[nq].y, b2 = bnq[nq].z, b3 = bnq[nq].w;
          acc[mq][nq][0][0] += a0f * b0; acc[mq][nq][0][1] += a0f * b1;
          acc[mq][nq][0][2] += a0f * b2; acc[mq][nq][0][3] += a0f * b3;
          acc[mq][nq][1][0] += a1f * b0; acc[mq][nq][1][1] += a1f * b1;
          acc[mq][nq][1][2] += a1f * b2; acc[mq][nq][1][3] += a1f * b3;
          acc[mq][nq][2][0] += a2f * b0; acc[mq][nq][2][1] += a2f * b1;
          acc[mq][nq][2][2] += a2f * b2; acc[mq][nq][2][3] += a2f * b3;
          acc[mq][nq][3][0] += a3f * b0; acc[mq][nq][3][1] += a3f * b1;
          acc[mq][nq][3][2] += a3f * b2; acc[mq][nq][3][3] += a3f * b3;
        }
      }
    }
    __syncthreads();
  }

#pragma unroll
  for (int mq = 0; mq < 2; mq++) {
#pragma unroll
    for (int i = 0; i < 4; i++) {
      int row = row0 + mq * 64 + tr * 4 + i;
#pragma unroll
      for (int nq = 0; nq < 2; nq++) {
        float* cp = Cout + (size_t)row * N + col0 + nq * 64 + tc * 4;
        float4 vv;
        vv.x = acc[mq][nq][i][0]; vv.y = acc[mq][nq][i][1];
        vv.z = acc[mq][nq][i][2]; vv.w = acc[mq][nq][i][3];
        *(float4*)cp = vv;
      }
    }
  }
}

// ---------------------------------------------------------------------------
// rotW2[d][h*32+j] = sum_f Wq[d][h*64+f] * rot[h][f][j]  (f64 acc, f32 store)
// ---------------------------------------------------------------------------
__global__ __launch_bounds__(256) void rotw_kernel(const float* __restrict__ Wq,
                                                   const float* __restrict__ rot,
                                                   float* __restrict__ rotW2) {
  int idx = blockIdx.x * 256 + threadIdx.x;   // d*256 + h*32 + j, 512*256 total
  int n = idx & 255;
  int d = idx >> 8;
  int h = n >> 5;
  int j = n & 31;
  double a = 0.0;
#pragma unroll 8
  for (int f = 0; f < 64; f++) {
    a += (double)Wq[(size_t)d * D_ + h * 64 + f] * (double)rot[((size_t)h * 64 + f) * 32 + j];
  }
  rotW2[idx] = (float)a;
}

// ---------------------------------------------------------------------------
// Per-token bucket argmax over [r, -r] (first-index ties, like np.argmax).
// ---------------------------------------------------------------------------
__global__ __launch_bounds__(256) void argmax_kernel(const float* __restrict__ rbuf,
                                                     int* __restrict__ buckets) {
  int gid = blockIdx.x * 256 + threadIdx.x;   // b*H*S + h*S + s
  int s = gid & (S_ - 1);
  int bh = gid >> 12;
  int h = bh & (H_ - 1);
  int b = bh >> 3;
  const float* rp = rbuf + ((size_t)b * S_ + s) * 256 + h * 32;
  float r[32];
#pragma unroll
  for (int j4 = 0; j4 < 8; j4++) {
    float4 t4 = *(const float4*)(rp + j4 * 4);
    r[j4 * 4 + 0] = t4.x; r[j4 * 4 + 1] = t4.y;
    r[j4 * 4 + 2] = t4.z; r[j4 * 4 + 3] = t4.w;
  }
  float best = r[0];
  int bi = 0;
#pragma unroll
  for (int j = 1; j < 64; j++) {
    float val = (j < 32) ? r[j] : -r[j - 32];
    if (val > best) { best = val; bi = j; }
  }
  buckets[gid] = bi;
}

// ---------------------------------------------------------------------------
// Stable counting sort by bucket (== argsort(bucket*S + pos)).
// ---------------------------------------------------------------------------
__global__ __launch_bounds__(64) void sort_kernel(const int* __restrict__ buckets,
                                                  int* __restrict__ st) {
  __shared__ int hist[64][64];   // [thread][bucket]
  __shared__ int boff[64];
  int bh = blockIdx.x;
  const int* bk = buckets + (size_t)bh * S_;
  int* stb = st + (size_t)bh * S_;
  int t = threadIdx.x;
  for (int j = 0; j < 64; j++) hist[t][j] = 0;
  __syncthreads();
  for (int i = 0; i < 64; i++) {
    int s = t * 64 + i;
    hist[t][bk[s]]++;
  }
  __syncthreads();
  int run = 0;
  for (int tt = 0; tt < 64; tt++) {
    int c = hist[tt][t];
    hist[tt][t] = run;
    run += c;
  }
  boff[t] = run;
  __syncthreads();
  if (t == 0) {
    int acc = 0;
    for (int j = 0; j < 64; j++) { int c = boff[j]; boff[j] = acc; acc += c; }
  }
  __syncthreads();
  for (int i = 0; i < 64; i++) {
    int s = t * 64 + i;
    int bkt = bk[s];
    int pos = boff[bkt] + hist[t][bkt];
    hist[t][bkt] = hist[t][bkt] + 1;
    stb[pos] = s;
  }
}

// ---------------------------------------------------------------------------
// MFMA chunked shared-QK attention (fp16x3). Reads fused qv planes
// (pitch 1024: q at col h*64, v at col 512+h*64).
// ---------------------------------------------------------------------------
#define KP 72
#define VP 136
__global__ __launch_bounds__(256) void attn_mfma(const _Float16* __restrict__ qvhi,
                                                 const _Float16* __restrict__ qvlo,
                                                 const int* __restrict__ st,
                                                 _Float16* __restrict__ ohi,
                                                 _Float16* __restrict__ olo) {
  __shared__ _Float16 lds[35840];   // 71680 B
  const int KH = 0, KL = 9216, VH = 18432, VL = 27136;
  int blk = blockIdx.x;
  int n = blk & (NC_ - 1);
  int bh = blk >> 6;
  int h = bh & (H_ - 1);
  int b = bh >> 3;
  const int* stbh = st + (size_t)bh * S_;
  int tid = threadIdx.x;
  int pn = (n + NC_ - 1) & (NC_ - 1);

  // ---- stage K (=Q) rows and V^T into LDS ----
  {
    int r = tid >> 1, dseg = (tid & 1) * 32;
    int si = (r < 64) ? (n * 64 + r) : (pn * 64 + (r - 64));
    int p = stbh[si];
    size_t gb = ((size_t)b * S_ + p) * 1024 + h * 64 + dseg;
    half8 kh[4], kl[4], vh8[4], vl8[4];
#pragma unroll
    for (int j = 0; j < 4; j++) {
      kh[j] = *(const half8*)&qvhi[gb + j * 8];
      kl[j] = *(const half8*)&qvlo[gb + j * 8];
      vh8[j] = *(const half8*)&qvhi[gb + 512 + j * 8];
      vl8[j] = *(const half8*)&qvlo[gb + 512 + j * 8];
    }
#pragma unroll
    for (int j = 0; j < 4; j++) {
      *(half8*)&lds[KH + r * KP + dseg + j * 8] = kh[j];
      *(half8*)&lds[KL + r * KP + dseg + j * 8] = kl[j];
    }
#pragma unroll
    for (int j = 0; j < 4; j++) {
#pragma unroll
      for (int e = 0; e < 8; e++) {
        int dim = dseg + j * 8 + e;
        lds[VH + dim * VP + r] = vh8[j][e];
        lds[VL + dim * VP + r] = vl8[j][e];
      }
    }
  }
  __syncthreads();

  int lane = tid & 63, w = tid >> 6;
  int fr = lane & 15, fk8 = (lane >> 4) * 8;

  // ---- QK^T: wave w computes S[w*16..+16][0..128] ----
  int qrow = w * 16 + fr;
  half8 qh0 = *(half8*)&lds[KH + qrow * KP + fk8];
  half8 qh1 = *(half8*)&lds[KH + qrow * KP + 32 + fk8];
  half8 ql0 = *(half8*)&lds[KL + qrow * KP + fk8];
  half8 ql1 = *(half8*)&lds[KL + qrow * KP + 32 + fk8];

  f32x4 sa[8];
#pragma unroll
  for (int nc = 0; nc < 8; nc++) {
    int key = nc * 16 + fr;
    half8 bh0 = *(half8*)&lds[KH + key * KP + fk8];
    half8 bh1 = *(half8*)&lds[KH + key * KP + 32 + fk8];
    half8 bl0 = *(half8*)&lds[KL + key * KP + fk8];
    half8 bl1 = *(half8*)&lds[KL + key * KP + 32 + fk8];
    f32x4 a = (f32x4){0.f, 0.f, 0.f, 0.f};
    a = __builtin_amdgcn_mfma_f32_16x16x32_f16(qh0, bh0, a, 0, 0, 0);
    a = __builtin_amdgcn_mfma_f32_16x16x32_f16(qh1, bh1, a, 0, 0, 0);
    a = __builtin_amdgcn_mfma_f32_16x16x32_f16(ql0, bh0, a, 0, 0, 0);
    a = __builtin_amdgcn_mfma_f32_16x16x32_f16(ql1, bh1, a, 0, 0, 0);
    a = __builtin_amdgcn_mfma_f32_16x16x32_f16(qh0, bl0, a, 0, 0, 0);
    a = __builtin_amdgcn_mfma_f32_16x16x32_f16(qh1, bl1, a, 0, 0, 0);
    sa[nc] = a;
  }

  // ---- softmax over 128 keys per query row (row = (lane>>4)*4+reg) ----
  float inv[4];
#pragma unroll
  for (int reg = 0; reg < 4; reg++) {
    float m = sa[0][reg];
#pragma unroll
    for (int nc = 1; nc < 8; nc++) m = fmaxf(m, sa[nc][reg]);
    m = fmaxf(m, __shfl_xor(m, 1));
    m = fmaxf(m, __shfl_xor(m, 2));
    m = fmaxf(m, __shfl_xor(m, 4));
    m = fmaxf(m, __shfl_xor(m, 8));
    float s = 0.f;
#pragma unroll
    for (int nc = 0; nc < 8; nc++) {
      float e = expf(0.125f * (sa[nc][reg] - m));
      sa[nc][reg] = e;
      s += e;
    }
    s += __shfl_xor(s, 1);
    s += __shfl_xor(s, 2);
    s += __shfl_xor(s, 4);
    s += __shfl_xor(s, 8);
    inv[reg] = 1.0f / s;
  }

  __syncthreads();   // all waves done reading K region; safe to alias with P

  // ---- write P (= e/sum) hi/lo into per-wave LDS region ----
  int PW = w * 4352;
#pragma unroll
  for (int nc = 0; nc < 8; nc++) {
#pragma unroll
    for (int reg = 0; reg < 4; reg++) {
      float pv = sa[nc][reg] * inv[reg];
      _Float16 ph = (_Float16)pv;
      _Float16 pl = (_Float16)(pv - (float)ph);
      int prow = (lane >> 4) * 4 + reg;
      int key = nc * 16 + fr;
      lds[PW + prow * VP + key] = ph;
      lds[PW + 2176 + prow * VP + key] = pl;
    }
  }

  // ---- PV: O[16][64] per wave ----
  half8 ph8[4], pl8[4];
#pragma unroll
  for (int kt = 0; kt < 4; kt++) {
    ph8[kt] = *(half8*)&lds[PW + fr * VP + kt * 32 + fk8];
    pl8[kt] = *(half8*)&lds[PW + 2176 + fr * VP + kt * 32 + fk8];
  }
  f32x4 oa[4];
#pragma unroll
  for (int nco = 0; nco < 4; nco++) {
    int dim = nco * 16 + fr;
    f32x4 a = (f32x4){0.f, 0.f, 0.f, 0.f};
#pragma unroll
    for (int kt = 0; kt < 4; kt++) {
      half8 bvh = *(half8*)&lds[VH + dim * VP + kt * 32 + fk8];
      half8 bvl = *(half8*)&lds[VL + dim * VP + kt * 32 + fk8];
      a = __builtin_amdgcn_mfma_f32_16x16x32_f16(ph8[kt], bvh, a, 0, 0, 0);
      a = __builtin_amdgcn_mfma_f32_16x16x32_f16(pl8[kt], bvh, a, 0, 0, 0);
      a = __builtin_amdgcn_mfma_f32_16x16x32_f16(ph8[kt], bvl, a, 0, 0, 0);
    }
    oa[nco] = a;
  }

  // ---- epilogue: scatter to output planes (unsorted order) ----
#pragma unroll
  for (int reg = 0; reg < 4; reg++) {
    int qq = w * 16 + (lane >> 4) * 4 + reg;
    int p = stbh[n * 64 + qq];
    size_t ob = ((size_t)b * S_ + p) * D_ + h * 64;
#pragma unroll
    for (int nco = 0; nco < 4; nco++) {
      float val = oa[nco][reg];
      _Float16 hv = (_Float16)val;
      ohi[ob + nco * 16 + fr] = hv;
      olo[ob + nco * 16 + fr] = (_Float16)(val - (float)hv);
    }
  }
}

// ---------------------------------------------------------------------------
extern "C" void kernel_launch(void* const* d_in, const int* in_sizes, int n_in,
                              void* d_out, int out_size, void* d_ws, size_t ws_size,
                              hipStream_t stream) {
  const int*   tokens = (const int*)d_in[0];
  const float* emb    = (const float*)d_in[1];
  const float* rot    = (const float*)d_in[2];
  const float* ln1_s  = (const float*)d_in[3];
  const float* ln1_b  = (const float*)d_in[4];
  const float* Wq     = (const float*)d_in[5];
  const float* Wv     = (const float*)d_in[6];
  const float* Wo     = (const float*)d_in[7];
  const float* ln2_s  = (const float*)d_in[8];
  const float* ln2_b  = (const float*)d_in[9];
  const float* W1     = (const float*)d_in[10];
  const float* b1     = (const float*)d_in[11];
  const float* W2     = (const float*)d_in[12];
  const float* b2     = (const float*)d_in[13];
  const float* lnf_s  = (const float*)d_in[14];
  const float* lnf_b  = (const float*)d_in[15];

  float* x = (float*)d_out;                  // residual stream lives in d_out
  const size_t RS = (size_t)B_ * S_ * D_;    // 8388608 elements
  const size_t WTOT = 3 * (size_t)D_ * D_ + 2 * (size_t)D_ * M_;  // 2883584

  char* wsb = (char*)d_ws;
  // region: 14RS bytes, phase-aliased.
  //   attn phase: qv_hi [rows][1024] (4RS B) | qv_lo (4RS B) |
  //               obuf hi/lo [rows][512] (2RS B each) | rbuf (2RS B)
  //   FFN phase:  mid hi/lo planes [rows][1024] each (8RS B total)
  _Float16* qv_hi = (_Float16*)wsb;
  _Float16* qv_lo = (_Float16*)(wsb + 4 * RS);
  _Float16* obuf_hi = (_Float16*)(wsb + 8 * RS);
  _Float16* obuf_lo = (_Float16*)(wsb + 10 * RS);
  float* rbuf = (float*)(wsb + 12 * RS);              // 16384*256 f32
  _Float16* mid_hi = (_Float16*)wsb;                  // [rows][1024] (FFN phase)
  _Float16* mid_lo = (_Float16*)(wsb + 4 * RS);
  // hbuf planes at 14RS bytes
  _Float16* hbuf_hi = (_Float16*)(wsb + 14 * RS);
  _Float16* hbuf_lo = (_Float16*)(wsb + 16 * RS);
  // weight planes (per layer, transposed [n][k]) at 18RS bytes
  _Float16* whi = (_Float16*)(wsb + 18 * RS);
  _Float16* wlo = whi + WTOT;
  float* rotW2 = (float*)(wlo + WTOT);                // [512*256] f32
  int* buckets = (int*)(rotW2 + 512 * 256);
  int* stbuf   = buckets + B_ * H_ * S_;
  // total: 18RS bytes (151.0MB) + 11.5MB + 1.6MB ~= 164.1MB (r8-proven)

  const size_t OQ = 0;
  const size_t OV = (size_t)D_ * D_;                  // contiguous after OQ
  const size_t OO = 2 * (size_t)D_ * D_;
  const size_t O1 = 3 * (size_t)D_ * D_;              // W1_T: [M][D]
  const size_t O2 = O1 + (size_t)D_ * M_;             // W2_T: [D][M]

  const int rows = B_ * S_;                  // 16384
  const int Mh = M_ / 2;                     // 1024

  embed_kernel<<<rows, 128, 0, stream>>>(tokens, emb, x);

  for (int l = 0; l < L_; l++) {
    transp_cvt<<<dim3(D_ / 32, D_ / 32), 256, 0, stream>>>(Wq + (size_t)l * D_ * D_, whi + OQ, wlo + OQ, D_, D_);
    transp_cvt<<<dim3(D_ / 32, D_ / 32), 256, 0, stream>>>(Wv + (size_t)l * D_ * D_, whi + OV, wlo + OV, D_, D_);
    transp_cvt<<<dim3(D_ / 32, D_ / 32), 256, 0, stream>>>(Wo + (size_t)l * D_ * D_, whi + OO, wlo + OO, D_, D_);
    transp_cvt<<<dim3(M_ / 32, D_ / 32), 256, 0, stream>>>(W1 + (size_t)l * D_ * M_, whi + O1, wlo + O1, D_, M_);
    transp_cvt<<<dim3(D_ / 32, M_ / 32), 256, 0, stream>>>(W2 + (size_t)l * M_ * D_, whi + O2, wlo + O2, M_, D_);

    ln_h<<<rows, 64, 0, stream>>>(x, hbuf_hi, hbuf_lo, ln1_s + (size_t)l * D_, ln1_b + (size_t)l * D_);

    // fused Q+V projection: B = [WqT ; WvT] (contiguous, 1024 rows of pitch 512)
    dim3 gqv(1024 / 128, rows / 128);
    gemm_h<0, 0, 0, 1><<<gqv, 256, 0, stream>>>(hbuf_hi, hbuf_lo, whi + OQ, wlo + OQ, nullptr,
                                                nullptr, qv_hi, qv_lo, rows, 1024, D_, D_, D_);

    rotw_kernel<<<(D_ * 256) / 256, 256, 0, stream>>>(Wq + (size_t)l * D_ * D_,
                                                      rot + (size_t)l * H_ * DH_ * 32, rotW2);
    dim3 gh(256 / 128, rows / 128);
    gemm_hash<<<gh, 256, 0, stream>>>(hbuf_hi, hbuf_lo, rotW2, rbuf, rows, 256, D_);
    argmax_kernel<<<(B_ * H_ * S_) / 256, 256, 0, stream>>>(rbuf, buckets);
    sort_kernel<<<B_ * H_, 64, 0, stream>>>(buckets, stbuf);
    attn_mfma<<<B_ * H_ * NC_, 256, 0, stream>>>(qv_hi, qv_lo, stbuf, obuf_hi, obuf_lo);

    dim3 g1(D_ / 128, rows / 128);
    gemm_h<0, 1, 0, 0><<<g1, 256, 0, stream>>>(obuf_hi, obuf_lo, whi + OO, wlo + OO, nullptr,
                                               x, nullptr, nullptr, rows, D_, D_, D_, D_);

    ln_h<<<rows, 64, 0, stream>>>(x, hbuf_hi, hbuf_lo, ln2_s + (size_t)l * D_, ln2_b + (size_t)l * D_);

    // FFN in two 1024-column halves (mid planes sized [rows][1024])
    for (int ch = 0; ch < 2; ch++) {
      dim3 gf1(Mh / 128, rows / 128);
      gemm_h<1, 0, 1, 1><<<gf1, 256, 0, stream>>>(hbuf_hi, hbuf_lo,
                                                  whi + O1 + (size_t)ch * Mh * D_,
                                                  wlo + O1 + (size_t)ch * Mh * D_,
                                                  b1 + (size_t)l * M_ + ch * Mh,
                                                  nullptr, mid_hi, mid_lo, rows, Mh, D_, D_, D_);
      dim3 gf2(D_ / 128, rows / 128);
      if (ch == 0) {
        gemm_h<0, 1, 0, 0><<<gf2, 256, 0, stream>>>(mid_hi, mid_lo,
                                                    whi + O2,
                                                    wlo + O2,
                                                    nullptr, x, nullptr, nullptr,
                                                    rows, D_, Mh, Mh, M_);
      } else {
        gemm_h<1, 1, 0, 0><<<gf2, 256, 0, stream>>>(mid_hi, mid_lo,
                                                    whi + O2 + (size_t)ch * Mh,
                                                    wlo + O2 + (size_t)ch * Mh,
                                                    b2 + (size_t)l * D_, x, nullptr, nullptr,
                                                    rows, D_, Mh, Mh, M_);
      }
    }
  }

  ln_f<<<rows, 64, 0, stream>>>(x, x, lnf_s, lnf_b);
}

// Round 11
// 3071.643 us; speedup vs baseline: 4.0874x; 1.1952x over previous
//
#include <hip/hip_runtime.h>

#define B_ 4
#define S_ 4096
#define D_ 512
#define H_ 8
#define L_ 6
#define M_ 2048
#define DH_ 64
#define NC_ 64   // number of chunks = S/C
#define C_ 64    // chunk length

typedef _Float16 half8 __attribute__((ext_vector_type(8)));
typedef _Float16 half4 __attribute__((ext_vector_type(4)));
typedef float f32x4 __attribute__((ext_vector_type(4)));

typedef const __attribute__((address_space(1))) unsigned int gu32;
typedef __attribute__((address_space(3))) unsigned int lu32;

// ---------------------------------------------------------------------------
// Embedding + sinusoidal positional encoding (f64 PE recipe — r3 fix)
// ---------------------------------------------------------------------------
__global__ __launch_bounds__(128) void embed_kernel(const int* __restrict__ tokens,
                                                    const float* __restrict__ emb,
                                                    float* __restrict__ x) {
  int row = blockIdx.x;            // b*S + s
  int s = row & (S_ - 1);
  int tok = tokens[row];
  const float4* e = (const float4*)(emb + (size_t)tok * D_);
  float4* xo = (float4*)(x + (size_t)row * D_);
  int t = threadIdx.x;             // 128 threads, 4 floats each
  float4 ev = e[t];
  int d0 = t * 4;
  const double c64 = -9.210340371976184 / 255.0;   // -ln(10000)/(half-1)
  float pe[4];
#pragma unroll
  for (int j = 0; j < 4; j++) {
    int d = d0 + j;
    int i = (d < 256) ? d : d - 256;
    double freq = exp((double)i * c64);
    double arg = (double)s * freq;
    pe[j] = (d < 256) ? (float)sin(arg) : (float)cos(arg);
  }
  float4 o;
  o.x = ev.x + pe[0];
  o.y = ev.y + pe[1];
  o.z = ev.z + pe[2];
  o.w = ev.w + pe[3];
  xo[t] = o;
}

// ---------------------------------------------------------------------------
// LayerNorm variants. ln_h writes fp16 hi/lo planes; ln_f writes f32.
// ---------------------------------------------------------------------------
__device__ __forceinline__ void ln_core(const float* __restrict__ in, int row, int t,
                                        const float* __restrict__ sc,
                                        const float* __restrict__ bi,
                                        float4& o1, float4& o2) {
  const float4* ir = (const float4*)(in + (size_t)row * D_);
  float4 a = ir[t];
  float4 b4 = ir[t + 64];
  float sum = a.x + a.y + a.z + a.w + b4.x + b4.y + b4.z + b4.w;
  float sq  = a.x*a.x + a.y*a.y + a.z*a.z + a.w*a.w
            + b4.x*b4.x + b4.y*b4.y + b4.z*b4.z + b4.w*b4.w;
#pragma unroll
  for (int m = 1; m < 64; m <<= 1) {
    sum += __shfl_xor(sum, m);
    sq  += __shfl_xor(sq, m);
  }
  float mean = sum * (1.0f / 512.0f);
  float var  = sq * (1.0f / 512.0f) - mean * mean;
  float rstd = 1.0f / sqrtf(var + 1e-6f);
  float4 s1 = ((const float4*)sc)[t], s2 = ((const float4*)sc)[t + 64];
  float4 g1 = ((const float4*)bi)[t], g2 = ((const float4*)bi)[t + 64];
  o1.x = (a.x - mean) * rstd * s1.x + g1.x;
  o1.y = (a.y - mean) * rstd * s1.y + g1.y;
  o1.z = (a.z - mean) * rstd * s1.z + g1.z;
  o1.w = (a.w - mean) * rstd * s1.w + g1.w;
  o2.x = (b4.x - mean) * rstd * s2.x + g2.x;
  o2.y = (b4.y - mean) * rstd * s2.y + g2.y;
  o2.z = (b4.z - mean) * rstd * s2.z + g2.z;
  o2.w = (b4.w - mean) * rstd * s2.w + g2.w;
}

__global__ __launch_bounds__(64) void ln_h(const float* __restrict__ in,
                                           _Float16* __restrict__ hi,
                                           _Float16* __restrict__ lo,
                                           const float* __restrict__ sc,
                                           const float* __restrict__ bi) {
  int row = blockIdx.x, t = threadIdx.x;
  float4 o1, o2;
  ln_core(in, row, t, sc, bi, o1, o2);
  float v1[4] = {o1.x, o1.y, o1.z, o1.w};
  float v2[4] = {o2.x, o2.y, o2.z, o2.w};
  half4 h1, l1, h2, l2;
#pragma unroll
  for (int j = 0; j < 4; j++) {
    _Float16 h = (_Float16)v1[j];
    h1[j] = h; l1[j] = (_Float16)(v1[j] - (float)h);
    _Float16 g = (_Float16)v2[j];
    h2[j] = g; l2[j] = (_Float16)(v2[j] - (float)g);
  }
  size_t base = (size_t)row * D_;
  *(half4*)&hi[base + t * 4] = h1;
  *(half4*)&hi[base + 256 + t * 4] = h2;
  *(half4*)&lo[base + t * 4] = l1;
  *(half4*)&lo[base + 256 + t * 4] = l2;
}

__global__ __launch_bounds__(64) void ln_f(const float* __restrict__ in,
                                           float* __restrict__ out,
                                           const float* __restrict__ sc,
                                           const float* __restrict__ bi) {
  int row = blockIdx.x, t = threadIdx.x;
  float4 o1, o2;
  ln_core(in, row, t, sc, bi, o1, o2);
  float4* orow = (float4*)(out + (size_t)row * D_);
  orow[t] = o1;
  orow[t + 64] = o2;
}

__device__ __forceinline__ float gelu_f(float v) {
  float v3 = v * v * v;
  return 0.5f * v * (1.0f + tanhf(0.7978845608028654f * (v + 0.044715f * v3)));
}

// ---------------------------------------------------------------------------
// Weight convert+transpose: src f32 [K][N] -> dst hi/lo fp16 [N][K].
// ---------------------------------------------------------------------------
__global__ __launch_bounds__(256) void transp_cvt(const float* __restrict__ src,
                                                  _Float16* __restrict__ dhi,
                                                  _Float16* __restrict__ dlo,
                                                  int K, int N) {
  __shared__ float tile[32][33];
  int n0 = blockIdx.x * 32, k0 = blockIdx.y * 32;
  int tx = threadIdx.x & 31, ty = threadIdx.x >> 5;   // ty 0..7
#pragma unroll
  for (int i = 0; i < 4; i++)
    tile[ty + 8 * i][tx] = src[(size_t)(k0 + ty + 8 * i) * N + n0 + tx];
  __syncthreads();
#pragma unroll
  for (int i = 0; i < 4; i++) {
    int n = n0 + ty + 8 * i;
    float v = tile[tx][ty + 8 * i];
    _Float16 h = (_Float16)v;
    dhi[(size_t)n * K + k0 + tx] = h;
    dlo[(size_t)n * K + k0 + tx] = (_Float16)(v - (float)h);
  }
}

// ---------------------------------------------------------------------------
// fp16x3 split MFMA GEMM, global_load_lds double-buffered (m97 structure)
// + bijective XCD-aware block swizzle (requires gridDim.x*gridDim.y % 8 == 0).
// A: [M][lda] planes, B: [N][ldb] planes. 128x128 tile, BK=32, 4 waves.
// ---------------------------------------------------------------------------
template <int HAS_BIAS, int RESID, int DO_GELU, int OUT_HALF>
__global__ __launch_bounds__(256) void gemm_h(const _Float16* __restrict__ Ahi,
                                              const _Float16* __restrict__ Alo,
                                              const _Float16* __restrict__ Bhi,
                                              const _Float16* __restrict__ Blo,
                                              const float* __restrict__ bias,
                                              float* __restrict__ C,
                                              _Float16* __restrict__ Chi,
                                              _Float16* __restrict__ Clo,
                                              int M, int N, int K, int lda, int ldb) {
  __shared__ _Float16 lds[2][4][128 * 32];   // 64 KB
  int tid = threadIdx.x;
  // XCD-aware bijective swizzle: each XCD gets a contiguous chunk of the
  // x-fastest linearization -> neighboring tiles (sharing A-panels) co-locate
  // on one XCD's L2 instead of scattering across 8 non-coherent L2s.
  int nwg = gridDim.x * gridDim.y;
  int flat = blockIdx.y * gridDim.x + blockIdx.x;
  int chunk = nwg >> 3;                       // nwg % 8 == 0 guaranteed by host
  int nf = (flat & 7) * chunk + (flat >> 3);
  int bx = nf % gridDim.x, by = nf / gridDim.x;
  int row0 = by * 128, col0 = bx * 128;
  int lane = tid & 63, w = tid >> 6;
  int wm = w >> 1, wn = w & 1;
  int fr = lane & 15, fk = (lane >> 4) * 8;

  // per-lane global source: wave w stages plane w
  int sld = (w < 2) ? lda : ldb;
  int sbase = (w < 2) ? row0 : col0;
  const _Float16* plane = (w == 0) ? Ahi : (w == 1) ? Alo : (w == 2) ? Bhi : Blo;
  const _Float16* gsrc = plane + (size_t)(sbase + (lane >> 2)) * sld + (lane & 3) * 8;
  size_t rowstep = (size_t)16 * sld;   // 16 rows per 1KB chunk

  f32x4 acc[4][4];
#pragma unroll
  for (int m = 0; m < 4; m++)
#pragma unroll
    for (int n = 0; n < 4; n++) acc[m][n] = (f32x4){0.f, 0.f, 0.f, 0.f};

  int nst = K >> 5;
  // prologue: stage step 0 into buffer 0
#pragma unroll
  for (int i = 0; i < 8; i++) {
    __builtin_amdgcn_global_load_lds((gu32*)(gsrc + (size_t)i * rowstep),
                                     (lu32*)&lds[0][w][i * 512], 16, 0, 0);
  }
  __syncthreads();

  int cur = 0;
  for (int s = 0; s < nst; ++s) {
    if (s + 1 < nst) {
      const _Float16* g = gsrc + (size_t)(s + 1) * 32;
#pragma unroll
      for (int i = 0; i < 8; i++) {
        __builtin_amdgcn_global_load_lds((gu32*)(g + (size_t)i * rowstep),
                                         (lu32*)&lds[cur ^ 1][w][i * 512], 16, 0, 0);
      }
    }
    const _Float16* Ah_ = lds[cur][0];
    const _Float16* Al_ = lds[cur][1];
    const _Float16* Bh_ = lds[cur][2];
    const _Float16* Bl_ = lds[cur][3];
    half8 bhf[4], blf[4];
#pragma unroll
    for (int n = 0; n < 4; n++) {
      int col = wn * 64 + n * 16 + fr;
      bhf[n] = *(const half8*)&Bh_[col * 32 + fk];
      blf[n] = *(const half8*)&Bl_[col * 32 + fk];
    }
#pragma unroll
    for (int m = 0; m < 4; m++) {
      int row = wm * 64 + m * 16 + fr;
      half8 ah = *(const half8*)&Ah_[row * 32 + fk];
      half8 al = *(const half8*)&Al_[row * 32 + fk];
#pragma unroll
      for (int n = 0; n < 4; n++)
        acc[m][n] = __builtin_amdgcn_mfma_f32_16x16x32_f16(ah, bhf[n], acc[m][n], 0, 0, 0);
#pragma unroll
      for (int n = 0; n < 4; n++)
        acc[m][n] = __builtin_amdgcn_mfma_f32_16x16x32_f16(al, bhf[n], acc[m][n], 0, 0, 0);
#pragma unroll
      for (int n = 0; n < 4; n++)
        acc[m][n] = __builtin_amdgcn_mfma_f32_16x16x32_f16(ah, blf[n], acc[m][n], 0, 0, 0);
    }
    __syncthreads();   // drains gload vmcnt + lds reads; flips buffer safely
    cur ^= 1;
  }

  // ---- epilogue ----
#pragma unroll
  for (int n = 0; n < 4; n++) {
    int col = col0 + wn * 64 + n * 16 + fr;
    float bv = HAS_BIAS ? bias[col] : 0.f;
#pragma unroll
    for (int m = 0; m < 4; m++) {
      int rowb = row0 + wm * 64 + m * 16 + (lane >> 4) * 4;
#pragma unroll
      for (int r = 0; r < 4; r++) {
        float val = acc[m][n][r] + bv;
        if (DO_GELU) val = gelu_f(val);
        size_t idx = (size_t)(rowb + r) * N + col;
        if (OUT_HALF) {
          _Float16 h = (_Float16)val;
          Chi[idx] = h;
          Clo[idx] = (_Float16)(val - (float)h);
        } else {
          if (RESID) val += C[idx];
          C[idx] = val;
        }
      }
    }
  }
}

// ---------------------------------------------------------------------------
// rotW2[d][h*32+j] = sum_f Wq[d][h*64+f] * rot[h][f][j]  (f64 acc, f32 store)
// ---------------------------------------------------------------------------
__global__ __launch_bounds__(256) void rotw_kernel(const float* __restrict__ Wq,
                                                   const float* __restrict__ rot,
                                                   float* __restrict__ rotW2) {
  int idx = blockIdx.x * 256 + threadIdx.x;   // d*256 + h*32 + j, 512*256 total
  int n = idx & 255;
  int d = idx >> 8;
  int h = n >> 5;
  int j = n & 31;
  double a = 0.0;
#pragma unroll 8
  for (int f = 0; f < 64; f++) {
    a += (double)Wq[(size_t)d * D_ + h * 64 + f] * (double)rot[((size_t)h * 64 + f) * 32 + j];
  }
  rotW2[idx] = (float)a;
}

// ---------------------------------------------------------------------------
// Per-token bucket argmax over [r, -r] (first-index ties, like np.argmax).
// Reads hash scores from the fused qvr planes (cols 1024..1279, pitch 1280),
// reconstructing f32 = (float)hi + (float)lo (2^-21-class, bucket-safe).
// ---------------------------------------------------------------------------
__global__ __launch_bounds__(256) void argmax_kernel(const _Float16* __restrict__ qvr_hi,
                                                     const _Float16* __restrict__ qvr_lo,
                                                     int* __restrict__ buckets) {
  int gid = blockIdx.x * 256 + threadIdx.x;   // b*H*S + h*S + s
  int s = gid & (S_ - 1);
  int bh = gid >> 12;
  int h = bh & (H_ - 1);
  int b = bh >> 3;
  size_t base = ((size_t)b * S_ + s) * 1280 + 1024 + h * 32;
  float r[32];
#pragma unroll
  for (int j8 = 0; j8 < 4; j8++) {
    half8 hv = *(const half8*)&qvr_hi[base + j8 * 8];
    half8 lv = *(const half8*)&qvr_lo[base + j8 * 8];
#pragma unroll
    for (int e = 0; e < 8; e++)
      r[j8 * 8 + e] = (float)hv[e] + (float)lv[e];
  }
  float best = r[0];
  int bi = 0;
#pragma unroll
  for (int j = 1; j < 64; j++) {
    float val = (j < 32) ? r[j] : -r[j - 32];
    if (val > best) { best = val; bi = j; }
  }
  buckets[gid] = bi;
}

// ---------------------------------------------------------------------------
// Stable counting sort by bucket (== argsort(bucket*S + pos)).
// ---------------------------------------------------------------------------
__global__ __launch_bounds__(64) void sort_kernel(const int* __restrict__ buckets,
                                                  int* __restrict__ st) {
  __shared__ int hist[64][64];   // [thread][bucket]
  __shared__ int boff[64];
  int bh = blockIdx.x;
  const int* bk = buckets + (size_t)bh * S_;
  int* stb = st + (size_t)bh * S_;
  int t = threadIdx.x;
  for (int j = 0; j < 64; j++) hist[t][j] = 0;
  __syncthreads();
  for (int i = 0; i < 64; i++) {
    int s = t * 64 + i;
    hist[t][bk[s]]++;
  }
  __syncthreads();
  int run = 0;
  for (int tt = 0; tt < 64; tt++) {
    int c = hist[tt][t];
    hist[tt][t] = run;
    run += c;
  }
  boff[t] = run;
  __syncthreads();
  if (t == 0) {
    int acc = 0;
    for (int j = 0; j < 64; j++) { int c = boff[j]; boff[j] = acc; acc += c; }
  }
  __syncthreads();
  for (int i = 0; i < 64; i++) {
    int s = t * 64 + i;
    int bkt = bk[s];
    int pos = boff[bkt] + hist[t][bkt];
    hist[t][bkt] = hist[t][bkt] + 1;
    stb[pos] = s;
  }
}

// ---------------------------------------------------------------------------
// MFMA chunked shared-QK attention (fp16x3). Reads fused qvr planes
// (pitch 1280: q at col h*64, v at col 512+h*64; hash cols 1024+ unused here).
// ---------------------------------------------------------------------------
#define KP 72
#define VP 136
__global__ __launch_bounds__(256) void attn_mfma(const _Float16* __restrict__ qvhi,
                                                 const _Float16* __restrict__ qvlo,
                                                 const int* __restrict__ st,
                                                 _Float16* __restrict__ ohi,
                                                 _Float16* __restrict__ olo) {
  __shared__ _Float16 lds[35840];   // 71680 B
  const int KH = 0, KL = 9216, VH = 18432, VL = 27136;
  int blk = blockIdx.x;
  int n = blk & (NC_ - 1);
  int bh = blk >> 6;
  int h = bh & (H_ - 1);
  int b = bh >> 3;
  const int* stbh = st + (size_t)bh * S_;
  int tid = threadIdx.x;
  int pn = (n + NC_ - 1) & (NC_ - 1);

  // ---- stage K (=Q) rows and V^T into LDS ----
  {
    int r = tid >> 1, dseg = (tid & 1) * 32;
    int si = (r < 64) ? (n * 64 + r) : (pn * 64 + (r - 64));
    int p = stbh[si];
    size_t gb = ((size_t)b * S_ + p) * 1280 + h * 64 + dseg;
    half8 kh[4], kl[4], vh8[4], vl8[4];
#pragma unroll
    for (int j = 0; j < 4; j++) {
      kh[j] = *(const half8*)&qvhi[gb + j * 8];
      kl[j] = *(const half8*)&qvlo[gb + j * 8];
      vh8[j] = *(const half8*)&qvhi[gb + 512 + j * 8];
      vl8[j] = *(const half8*)&qvlo[gb + 512 + j * 8];
    }
#pragma unroll
    for (int j = 0; j < 4; j++) {
      *(half8*)&lds[KH + r * KP + dseg + j * 8] = kh[j];
      *(half8*)&lds[KL + r * KP + dseg + j * 8] = kl[j];
    }
#pragma unroll
    for (int j = 0; j < 4; j++) {
#pragma unroll
      for (int e = 0; e < 8; e++) {
        int dim = dseg + j * 8 + e;
        lds[VH + dim * VP + r] = vh8[j][e];
        lds[VL + dim * VP + r] = vl8[j][e];
      }
    }
  }
  __syncthreads();

  int lane = tid & 63, w = tid >> 6;
  int fr = lane & 15, fk8 = (lane >> 4) * 8;

  // ---- QK^T: wave w computes S[w*16..+16][0..128] ----
  int qrow = w * 16 + fr;
  half8 qh0 = *(half8*)&lds[KH + qrow * KP + fk8];
  half8 qh1 = *(half8*)&lds[KH + qrow * KP + 32 + fk8];
  half8 ql0 = *(half8*)&lds[KL + qrow * KP + fk8];
  half8 ql1 = *(half8*)&lds[KL + qrow * KP + 32 + fk8];

  f32x4 sa[8];
#pragma unroll
  for (int nc = 0; nc < 8; nc++) {
    int key = nc * 16 + fr;
    half8 bh0 = *(half8*)&lds[KH + key * KP + fk8];
    half8 bh1 = *(half8*)&lds[KH + key * KP + 32 + fk8];
    half8 bl0 = *(half8*)&lds[KL + key * KP + fk8];
    half8 bl1 = *(half8*)&lds[KL + key * KP + 32 + fk8];
    f32x4 a = (f32x4){0.f, 0.f, 0.f, 0.f};
    a = __builtin_amdgcn_mfma_f32_16x16x32_f16(qh0, bh0, a, 0, 0, 0);
    a = __builtin_amdgcn_mfma_f32_16x16x32_f16(qh1, bh1, a, 0, 0, 0);
    a = __builtin_amdgcn_mfma_f32_16x16x32_f16(ql0, bh0, a, 0, 0, 0);
    a = __builtin_amdgcn_mfma_f32_16x16x32_f16(ql1, bh1, a, 0, 0, 0);
    a = __builtin_amdgcn_mfma_f32_16x16x32_f16(qh0, bl0, a, 0, 0, 0);
    a = __builtin_amdgcn_mfma_f32_16x16x32_f16(qh1, bl1, a, 0, 0, 0);
    sa[nc] = a;
  }

  // ---- softmax over 128 keys per query row (row = (lane>>4)*4+reg) ----
  float inv[4];
#pragma unroll
  for (int reg = 0; reg < 4; reg++) {
    float m = sa[0][reg];
#pragma unroll
    for (int nc = 1; nc < 8; nc++) m = fmaxf(m, sa[nc][reg]);
    m = fmaxf(m, __shfl_xor(m, 1));
    m = fmaxf(m, __shfl_xor(m, 2));
    m = fmaxf(m, __shfl_xor(m, 4));
    m = fmaxf(m, __shfl_xor(m, 8));
    float s = 0.f;
#pragma unroll
    for (int nc = 0; nc < 8; nc++) {
      float e = expf(0.125f * (sa[nc][reg] - m));
      sa[nc][reg] = e;
      s += e;
    }
    s += __shfl_xor(s, 1);
    s += __shfl_xor(s, 2);
    s += __shfl_xor(s, 4);
    s += __shfl_xor(s, 8);
    inv[reg] = 1.0f / s;
  }

  __syncthreads();   // all waves done reading K region; safe to alias with P

  // ---- write P (= e/sum) hi/lo into per-wave LDS region ----
  int PW = w * 4352;
#pragma unroll
  for (int nc = 0; nc < 8; nc++) {
#pragma unroll
    for (int reg = 0; reg < 4; reg++) {
      float pv = sa[nc][reg] * inv[reg];
      _Float16 ph = (_Float16)pv;
      _Float16 pl = (_Float16)(pv - (float)ph);
      int prow = (lane >> 4) * 4 + reg;
      int key = nc * 16 + fr;
      lds[PW + prow * VP + key] = ph;
      lds[PW + 2176 + prow * VP + key] = pl;
    }
  }

  // ---- PV: O[16][64] per wave ----
  half8 ph8[4], pl8[4];
#pragma unroll
  for (int kt = 0; kt < 4; kt++) {
    ph8[kt] = *(half8*)&lds[PW + fr * VP + kt * 32 + fk8];
    pl8[kt] = *(half8*)&lds[PW + 2176 + fr * VP + kt * 32 + fk8];
  }
  f32x4 oa[4];
#pragma unroll
  for (int nco = 0; nco < 4; nco++) {
    int dim = nco * 16 + fr;
    f32x4 a = (f32x4){0.f, 0.f, 0.f, 0.f};
#pragma unroll
    for (int kt = 0; kt < 4; kt++) {
      half8 bvh = *(half8*)&lds[VH + dim * VP + kt * 32 + fk8];
      half8 bvl = *(half8*)&lds[VL + dim * VP + kt * 32 + fk8];
      a = __builtin_amdgcn_mfma_f32_16x16x32_f16(ph8[kt], bvh, a, 0, 0, 0);
      a = __builtin_amdgcn_mfma_f32_16x16x32_f16(pl8[kt], bvh, a, 0, 0, 0);
      a = __builtin_amdgcn_mfma_f32_16x16x32_f16(ph8[kt], bvl, a, 0, 0, 0);
    }
    oa[nco] = a;
  }

  // ---- epilogue: scatter to output planes (unsorted order) ----
#pragma unroll
  for (int reg = 0; reg < 4; reg++) {
    int qq = w * 16 + (lane >> 4) * 4 + reg;
    int p = stbh[n * 64 + qq];
    size_t ob = ((size_t)b * S_ + p) * D_ + h * 64;
#pragma unroll
    for (int nco = 0; nco < 4; nco++) {
      float val = oa[nco][reg];
      _Float16 hv = (_Float16)val;
      ohi[ob + nco * 16 + fr] = hv;
      olo[ob + nco * 16 + fr] = (_Float16)(val - (float)hv);
    }
  }
}

// ---------------------------------------------------------------------------
extern "C" void kernel_launch(void* const* d_in, const int* in_sizes, int n_in,
                              void* d_out, int out_size, void* d_ws, size_t ws_size,
                              hipStream_t stream) {
  const int*   tokens = (const int*)d_in[0];
  const float* emb    = (const float*)d_in[1];
  const float* rot    = (const float*)d_in[2];
  const float* ln1_s  = (const float*)d_in[3];
  const float* ln1_b  = (const float*)d_in[4];
  const float* Wq     = (const float*)d_in[5];
  const float* Wv     = (const float*)d_in[6];
  const float* Wo     = (const float*)d_in[7];
  const float* ln2_s  = (const float*)d_in[8];
  const float* ln2_b  = (const float*)d_in[9];
  const float* W1     = (const float*)d_in[10];
  const float* b1     = (const float*)d_in[11];
  const float* W2     = (const float*)d_in[12];
  const float* b2     = (const float*)d_in[13];
  const float* lnf_s  = (const float*)d_in[14];
  const float* lnf_b  = (const float*)d_in[15];

  float* x = (float*)d_out;                  // residual stream lives in d_out
  const size_t RS = (size_t)B_ * S_ * D_;    // 8388608 elements
  // weight planes: WqT|WvT|rotW2T|WoT|W1T|W2T  (transposed [n][k])
  const size_t WTOT = 3 * (size_t)D_ * D_ + 2 * (size_t)D_ * M_ + 256 * 512;

  char* wsb = (char*)d_ws;
  const int rows = B_ * S_;                  // 16384
  // region: 14RS bytes, phase-aliased.
  //   attn phase: qvr hi/lo [rows][1280] (2x 41.94MB) | obuf hi/lo [rows][512]
  //   FFN phase:  mid hi/lo planes [rows][1024] each
  _Float16* qvr_hi = (_Float16*)wsb;
  _Float16* qvr_lo = qvr_hi + (size_t)rows * 1280;
  _Float16* obuf_hi = (_Float16*)(wsb + 2 * (size_t)rows * 1280 * 2);
  _Float16* obuf_lo = obuf_hi + RS;
  _Float16* mid_hi = (_Float16*)wsb;                  // [rows][1024] (FFN phase)
  _Float16* mid_lo = (_Float16*)(wsb + 4 * RS);
  // hbuf planes at 14RS bytes
  _Float16* hbuf_hi = (_Float16*)(wsb + 14 * RS);
  _Float16* hbuf_lo = (_Float16*)(wsb + 16 * RS);
  // weight planes at 18RS bytes
  _Float16* whi = (_Float16*)(wsb + 18 * RS);
  _Float16* wlo = whi + WTOT;
  float* rotW2 = (float*)(wlo + WTOT);                // [512*256] f32
  int* buckets = (int*)(rotW2 + 512 * 256);
  int* stbuf   = buckets + B_ * H_ * S_;
  // total: 18RS (151.0MB) + 12.06MB + 1.6MB ~= 164.7MB

  const size_t OQ = 0;                                // WqT [512][512]
  const size_t OV = (size_t)D_ * D_;                  // WvT [512][512]
  const size_t OR = 2 * (size_t)D_ * D_;              // rotW2T [256][512]
  const size_t OO = OR + (size_t)256 * 512;           // WoT [512][512]
  const size_t O1 = OO + (size_t)D_ * D_;             // W1T [2048][512]
  const size_t O2 = O1 + (size_t)D_ * M_;             // W2T [512][2048]

  const int Mh = M_ / 2;                     // 1024

  embed_kernel<<<rows, 128, 0, stream>>>(tokens, emb, x);

  for (int l = 0; l < L_; l++) {
    transp_cvt<<<dim3(D_ / 32, D_ / 32), 256, 0, stream>>>(Wq + (size_t)l * D_ * D_, whi + OQ, wlo + OQ, D_, D_);
    transp_cvt<<<dim3(D_ / 32, D_ / 32), 256, 0, stream>>>(Wv + (size_t)l * D_ * D_, whi + OV, wlo + OV, D_, D_);
    transp_cvt<<<dim3(D_ / 32, D_ / 32), 256, 0, stream>>>(Wo + (size_t)l * D_ * D_, whi + OO, wlo + OO, D_, D_);
    transp_cvt<<<dim3(M_ / 32, D_ / 32), 256, 0, stream>>>(W1 + (size_t)l * D_ * M_, whi + O1, wlo + O1, D_, M_);
    transp_cvt<<<dim3(D_ / 32, M_ / 32), 256, 0, stream>>>(W2 + (size_t)l * M_ * D_, whi + O2, wlo + O2, M_, D_);
    rotw_kernel<<<(D_ * 256) / 256, 256, 0, stream>>>(Wq + (size_t)l * D_ * D_,
                                                      rot + (size_t)l * H_ * DH_ * 32, rotW2);
    transp_cvt<<<dim3(256 / 32, D_ / 32), 256, 0, stream>>>(rotW2, whi + OR, wlo + OR, D_, 256);

    ln_h<<<rows, 64, 0, stream>>>(x, hbuf_hi, hbuf_lo, ln1_s + (size_t)l * D_, ln1_b + (size_t)l * D_);

    // fused Q+V+hash projection: B = [WqT ; WvT ; rotW2T] (1280 rows, pitch 512)
    dim3 gqv(1280 / 128, rows / 128);
    gemm_h<0, 0, 0, 1><<<gqv, 256, 0, stream>>>(hbuf_hi, hbuf_lo, whi + OQ, wlo + OQ, nullptr,
                                                nullptr, qvr_hi, qvr_lo, rows, 1280, D_, D_, D_);

    argmax_kernel<<<(B_ * H_ * S_) / 256, 256, 0, stream>>>(qvr_hi, qvr_lo, buckets);
    sort_kernel<<<B_ * H_, 64, 0, stream>>>(buckets, stbuf);
    attn_mfma<<<B_ * H_ * NC_, 256, 0, stream>>>(qvr_hi, qvr_lo, stbuf, obuf_hi, obuf_lo);

    dim3 g1(D_ / 128, rows / 128);
    gemm_h<0, 1, 0, 0><<<g1, 256, 0, stream>>>(obuf_hi, obuf_lo, whi + OO, wlo + OO, nullptr,
                                               x, nullptr, nullptr, rows, D_, D_, D_, D_);

    ln_h<<<rows, 64, 0, stream>>>(x, hbuf_hi, hbuf_lo, ln2_s + (size_t)l * D_, ln2_b + (size_t)l * D_);

    // FFN in two 1024-column halves (mid planes sized [rows][1024])
    for (int ch = 0; ch < 2; ch++) {
      dim3 gf1(Mh / 128, rows / 128);
      gemm_h<1, 0, 1, 1><<<gf1, 256, 0, stream>>>(hbuf_hi, hbuf_lo,
                                                  whi + O1 + (size_t)ch * Mh * D_,
                                                  wlo + O1 + (size_t)ch * Mh * D_,
                                                  b1 + (size_t)l * M_ + ch * Mh,
                                                  nullptr, mid_hi, mid_lo, rows, Mh, D_, D_, D_);
      dim3 gf2(D_ / 128, rows / 128);
      if (ch == 0) {
        gemm_h<0, 1, 0, 0><<<gf2, 256, 0, stream>>>(mid_hi, mid_lo,
                                                    whi + O2,
                                                    wlo + O2,
                                                    nullptr, x, nullptr, nullptr,
                                                    rows, D_, Mh, Mh, M_);
      } else {
        gemm_h<1, 1, 0, 0><<<gf2, 256, 0, stream>>>(mid_hi, mid_lo,
                                                    whi + O2 + (size_t)ch * Mh,
                                                    wlo + O2 + (size_t)ch * Mh,
                                                    b2 + (size_t)l * D_, x, nullptr, nullptr,
                                                    rows, D_, Mh, Mh, M_);
      }
    }
  }

  ln_f<<<rows, 64, 0, stream>>>(x, x, lnf_s, lnf_b);
}

// Round 12
// 2880.185 us; speedup vs baseline: 4.3592x; 1.0665x over previous
//
#include <hip/hip_runtime.h>

#define B_ 4
#define S_ 4096
#define D_ 512
#define H_ 8
#define L_ 6
#define M_ 2048
#define DH_ 64
#define NC_ 64   // number of chunks = S/C
#define C_ 64    // chunk length

typedef _Float16 half8 __attribute__((ext_vector_type(8)));
typedef _Float16 half4 __attribute__((ext_vector_type(4)));
typedef float f32x4 __attribute__((ext_vector_type(4)));

typedef const __attribute__((address_space(1))) unsigned int gu32;
typedef __attribute__((address_space(3))) unsigned int lu32;

// ---------------------------------------------------------------------------
// Embedding + sinusoidal positional encoding (f64 PE recipe — r3 fix)
// ---------------------------------------------------------------------------
__global__ __launch_bounds__(128) void embed_kernel(const int* __restrict__ tokens,
                                                    const float* __restrict__ emb,
                                                    float* __restrict__ x) {
  int row = blockIdx.x;            // b*S + s
  int s = row & (S_ - 1);
  int tok = tokens[row];
  const float4* e = (const float4*)(emb + (size_t)tok * D_);
  float4* xo = (float4*)(x + (size_t)row * D_);
  int t = threadIdx.x;             // 128 threads, 4 floats each
  float4 ev = e[t];
  int d0 = t * 4;
  const double c64 = -9.210340371976184 / 255.0;   // -ln(10000)/(half-1)
  float pe[4];
#pragma unroll
  for (int j = 0; j < 4; j++) {
    int d = d0 + j;
    int i = (d < 256) ? d : d - 256;
    double freq = exp((double)i * c64);
    double arg = (double)s * freq;
    pe[j] = (d < 256) ? (float)sin(arg) : (float)cos(arg);
  }
  float4 o;
  o.x = ev.x + pe[0];
  o.y = ev.y + pe[1];
  o.z = ev.z + pe[2];
  o.w = ev.w + pe[3];
  xo[t] = o;
}

// ---------------------------------------------------------------------------
// LayerNorm variants. ln_h writes fp16 hi/lo planes; ln_f writes f32.
// ---------------------------------------------------------------------------
__device__ __forceinline__ void ln_core(const float* __restrict__ in, int row, int t,
                                        const float* __restrict__ sc,
                                        const float* __restrict__ bi,
                                        float4& o1, float4& o2) {
  const float4* ir = (const float4*)(in + (size_t)row * D_);
  float4 a = ir[t];
  float4 b4 = ir[t + 64];
  float sum = a.x + a.y + a.z + a.w + b4.x + b4.y + b4.z + b4.w;
  float sq  = a.x*a.x + a.y*a.y + a.z*a.z + a.w*a.w
            + b4.x*b4.x + b4.y*b4.y + b4.z*b4.z + b4.w*b4.w;
#pragma unroll
  for (int m = 1; m < 64; m <<= 1) {
    sum += __shfl_xor(sum, m);
    sq  += __shfl_xor(sq, m);
  }
  float mean = sum * (1.0f / 512.0f);
  float var  = sq * (1.0f / 512.0f) - mean * mean;
  float rstd = 1.0f / sqrtf(var + 1e-6f);
  float4 s1 = ((const float4*)sc)[t], s2 = ((const float4*)sc)[t + 64];
  float4 g1 = ((const float4*)bi)[t], g2 = ((const float4*)bi)[t + 64];
  o1.x = (a.x - mean) * rstd * s1.x + g1.x;
  o1.y = (a.y - mean) * rstd * s1.y + g1.y;
  o1.z = (a.z - mean) * rstd * s1.z + g1.z;
  o1.w = (a.w - mean) * rstd * s1.w + g1.w;
  o2.x = (b4.x - mean) * rstd * s2.x + g2.x;
  o2.y = (b4.y - mean) * rstd * s2.y + g2.y;
  o2.z = (b4.z - mean) * rstd * s2.z + g2.z;
  o2.w = (b4.w - mean) * rstd * s2.w + g2.w;
}

__global__ __launch_bounds__(64) void ln_h(const float* __restrict__ in,
                                           _Float16* __restrict__ hi,
                                           _Float16* __restrict__ lo,
                                           const float* __restrict__ sc,
                                           const float* __restrict__ bi) {
  int row = blockIdx.x, t = threadIdx.x;
  float4 o1, o2;
  ln_core(in, row, t, sc, bi, o1, o2);
  float v1[4] = {o1.x, o1.y, o1.z, o1.w};
  float v2[4] = {o2.x, o2.y, o2.z, o2.w};
  half4 h1, l1, h2, l2;
#pragma unroll
  for (int j = 0; j < 4; j++) {
    _Float16 h = (_Float16)v1[j];
    h1[j] = h; l1[j] = (_Float16)(v1[j] - (float)h);
    _Float16 g = (_Float16)v2[j];
    h2[j] = g; l2[j] = (_Float16)(v2[j] - (float)g);
  }
  size_t base = (size_t)row * D_;
  *(half4*)&hi[base + t * 4] = h1;
  *(half4*)&hi[base + 256 + t * 4] = h2;
  *(half4*)&lo[base + t * 4] = l1;
  *(half4*)&lo[base + 256 + t * 4] = l2;
}

__global__ __launch_bounds__(64) void ln_f(const float* __restrict__ in,
                                           float* __restrict__ out,
                                           const float* __restrict__ sc,
                                           const float* __restrict__ bi) {
  int row = blockIdx.x, t = threadIdx.x;
  float4 o1, o2;
  ln_core(in, row, t, sc, bi, o1, o2);
  float4* orow = (float4*)(out + (size_t)row * D_);
  orow[t] = o1;
  orow[t + 64] = o2;
}

__device__ __forceinline__ float gelu_f(float v) {
  float v3 = v * v * v;
  return 0.5f * v * (1.0f + tanhf(0.7978845608028654f * (v + 0.044715f * v3)));
}

// ---------------------------------------------------------------------------
// Weight convert+transpose: src f32 [K][N] -> dst hi/lo fp16 [N][K].
// ---------------------------------------------------------------------------
__global__ __launch_bounds__(256) void transp_cvt(const float* __restrict__ src,
                                                  _Float16* __restrict__ dhi,
                                                  _Float16* __restrict__ dlo,
                                                  int K, int N) {
  __shared__ float tile[32][33];
  int n0 = blockIdx.x * 32, k0 = blockIdx.y * 32;
  int tx = threadIdx.x & 31, ty = threadIdx.x >> 5;   // ty 0..7
#pragma unroll
  for (int i = 0; i < 4; i++)
    tile[ty + 8 * i][tx] = src[(size_t)(k0 + ty + 8 * i) * N + n0 + tx];
  __syncthreads();
#pragma unroll
  for (int i = 0; i < 4; i++) {
    int n = n0 + ty + 8 * i;
    float v = tile[tx][ty + 8 * i];
    _Float16 h = (_Float16)v;
    dhi[(size_t)n * K + k0 + tx] = h;
    dlo[(size_t)n * K + k0 + tx] = (_Float16)(v - (float)h);
  }
}

// ---------------------------------------------------------------------------
// fp16x3 split MFMA GEMM, global_load_lds double-buffered + XCD swizzle.
// OPERAND-SWAPPED MFMA: acc = mfma(b_frag, a_frag) -> lane reg-dim indexes 4
// consecutive N-cols at fixed M-row (fr). Bit-identical accumulator values
// (commuted products, same k-order); enables half4/float4 epilogue stores.
// A: [M][lda] planes, B: [N][ldb] planes. 128x128 tile, BK=32, 4 waves.
// ---------------------------------------------------------------------------
template <int HAS_BIAS, int RESID, int DO_GELU, int OUT_HALF>
__global__ __launch_bounds__(256) void gemm_h(const _Float16* __restrict__ Ahi,
                                              const _Float16* __restrict__ Alo,
                                              const _Float16* __restrict__ Bhi,
                                              const _Float16* __restrict__ Blo,
                                              const float* __restrict__ bias,
                                              float* __restrict__ C,
                                              _Float16* __restrict__ Chi,
                                              _Float16* __restrict__ Clo,
                                              int M, int N, int K, int lda, int ldb) {
  __shared__ _Float16 lds[2][4][128 * 32];   // 64 KB
  int tid = threadIdx.x;
  // XCD-aware bijective swizzle (nwg % 8 == 0 guaranteed by host).
  int nwg = gridDim.x * gridDim.y;
  int flat = blockIdx.y * gridDim.x + blockIdx.x;
  int chunk = nwg >> 3;
  int nf = (flat & 7) * chunk + (flat >> 3);
  int bx = nf % gridDim.x, by = nf / gridDim.x;
  int row0 = by * 128, col0 = bx * 128;
  int lane = tid & 63, w = tid >> 6;
  int wm = w >> 1, wn = w & 1;
  int fr = lane & 15, fk = (lane >> 4) * 8;
  int q4 = (lane >> 4) * 4;

  // per-lane global source: wave w stages plane w
  int sld = (w < 2) ? lda : ldb;
  int sbase = (w < 2) ? row0 : col0;
  const _Float16* plane = (w == 0) ? Ahi : (w == 1) ? Alo : (w == 2) ? Bhi : Blo;
  const _Float16* gsrc = plane + (size_t)(sbase + (lane >> 2)) * sld + (lane & 3) * 8;
  size_t rowstep = (size_t)16 * sld;   // 16 rows per 1KB chunk

  f32x4 acc[4][4];
#pragma unroll
  for (int m = 0; m < 4; m++)
#pragma unroll
    for (int n = 0; n < 4; n++) acc[m][n] = (f32x4){0.f, 0.f, 0.f, 0.f};

  int nst = K >> 5;
#pragma unroll
  for (int i = 0; i < 8; i++) {
    __builtin_amdgcn_global_load_lds((gu32*)(gsrc + (size_t)i * rowstep),
                                     (lu32*)&lds[0][w][i * 512], 16, 0, 0);
  }
  __syncthreads();

  int cur = 0;
  for (int s = 0; s < nst; ++s) {
    if (s + 1 < nst) {
      const _Float16* g = gsrc + (size_t)(s + 1) * 32;
#pragma unroll
      for (int i = 0; i < 8; i++) {
        __builtin_amdgcn_global_load_lds((gu32*)(g + (size_t)i * rowstep),
                                         (lu32*)&lds[cur ^ 1][w][i * 512], 16, 0, 0);
      }
    }
    const _Float16* Ah_ = lds[cur][0];
    const _Float16* Al_ = lds[cur][1];
    const _Float16* Bh_ = lds[cur][2];
    const _Float16* Bl_ = lds[cur][3];
    half8 bhf[4], blf[4];
#pragma unroll
    for (int n = 0; n < 4; n++) {
      int col = wn * 64 + n * 16 + fr;
      bhf[n] = *(const half8*)&Bh_[col * 32 + fk];
      blf[n] = *(const half8*)&Bl_[col * 32 + fk];
    }
#pragma unroll
    for (int m = 0; m < 4; m++) {
      int row = wm * 64 + m * 16 + fr;
      half8 ah = *(const half8*)&Ah_[row * 32 + fk];
      half8 al = *(const half8*)&Al_[row * 32 + fk];
      // operand-swapped: same products, same order as (ah,b),(al,b),(ah,bl)
#pragma unroll
      for (int n = 0; n < 4; n++)
        acc[m][n] = __builtin_amdgcn_mfma_f32_16x16x32_f16(bhf[n], ah, acc[m][n], 0, 0, 0);
#pragma unroll
      for (int n = 0; n < 4; n++)
        acc[m][n] = __builtin_amdgcn_mfma_f32_16x16x32_f16(bhf[n], al, acc[m][n], 0, 0, 0);
#pragma unroll
      for (int n = 0; n < 4; n++)
        acc[m][n] = __builtin_amdgcn_mfma_f32_16x16x32_f16(blf[n], ah, acc[m][n], 0, 0, 0);
    }
    __syncthreads();
    cur ^= 1;
  }

  // ---- epilogue: lane holds C[row][colb..colb+3] per (m,n) ----
#pragma unroll
  for (int m = 0; m < 4; m++) {
    int row = row0 + wm * 64 + m * 16 + fr;
#pragma unroll
    for (int n = 0; n < 4; n++) {
      int colb = col0 + wn * 64 + n * 16 + q4;
      float4 bq = {0.f, 0.f, 0.f, 0.f};
      if (HAS_BIAS) bq = *(const float4*)&bias[colb];
      float v[4];
      v[0] = acc[m][n][0] + bq.x;
      v[1] = acc[m][n][1] + bq.y;
      v[2] = acc[m][n][2] + bq.z;
      v[3] = acc[m][n][3] + bq.w;
      if (DO_GELU) {
        v[0] = gelu_f(v[0]); v[1] = gelu_f(v[1]);
        v[2] = gelu_f(v[2]); v[3] = gelu_f(v[3]);
      }
      size_t idx = (size_t)row * N + colb;
      if (OUT_HALF) {
        half4 hv, lv;
#pragma unroll
        for (int r = 0; r < 4; r++) {
          _Float16 h = (_Float16)v[r];
          hv[r] = h;
          lv[r] = (_Float16)(v[r] - (float)h);
        }
        *(half4*)&Chi[idx] = hv;
        *(half4*)&Clo[idx] = lv;
      } else {
        float4 vv;
        vv.x = v[0]; vv.y = v[1]; vv.z = v[2]; vv.w = v[3];
        if (RESID) {
          float4 old = *(const float4*)&C[idx];
          vv.x += old.x; vv.y += old.y; vv.z += old.z; vv.w += old.w;
        }
        *(float4*)&C[idx] = vv;
      }
    }
  }
}

// ---------------------------------------------------------------------------
// rotW2[d][h*32+j] = sum_f Wq[d][h*64+f] * rot[h][f][j]  (f64 acc, f32 store)
// ---------------------------------------------------------------------------
__global__ __launch_bounds__(256) void rotw_kernel(const float* __restrict__ Wq,
                                                   const float* __restrict__ rot,
                                                   float* __restrict__ rotW2) {
  int idx = blockIdx.x * 256 + threadIdx.x;   // d*256 + h*32 + j, 512*256 total
  int n = idx & 255;
  int d = idx >> 8;
  int h = n >> 5;
  int j = n & 31;
  double a = 0.0;
#pragma unroll 8
  for (int f = 0; f < 64; f++) {
    a += (double)Wq[(size_t)d * D_ + h * 64 + f] * (double)rot[((size_t)h * 64 + f) * 32 + j];
  }
  rotW2[idx] = (float)a;
}

// ---------------------------------------------------------------------------
// Per-token bucket argmax over [r, -r] (first-index ties, like np.argmax).
// Reads hash scores from the fused qvr planes (cols 1024..1279, pitch 1280).
// ---------------------------------------------------------------------------
__global__ __launch_bounds__(256) void argmax_kernel(const _Float16* __restrict__ qvr_hi,
                                                     const _Float16* __restrict__ qvr_lo,
                                                     int* __restrict__ buckets) {
  int gid = blockIdx.x * 256 + threadIdx.x;   // b*H*S + h*S + s
  int s = gid & (S_ - 1);
  int bh = gid >> 12;
  int h = bh & (H_ - 1);
  int b = bh >> 3;
  size_t base = ((size_t)b * S_ + s) * 1280 + 1024 + h * 32;
  float r[32];
#pragma unroll
  for (int j8 = 0; j8 < 4; j8++) {
    half8 hv = *(const half8*)&qvr_hi[base + j8 * 8];
    half8 lv = *(const half8*)&qvr_lo[base + j8 * 8];
#pragma unroll
    for (int e = 0; e < 8; e++)
      r[j8 * 8 + e] = (float)hv[e] + (float)lv[e];
  }
  float best = r[0];
  int bi = 0;
#pragma unroll
  for (int j = 1; j < 64; j++) {
    float val = (j < 32) ? r[j] : -r[j - 32];
    if (val > best) { best = val; bi = j; }
  }
  buckets[gid] = bi;
}

// ---------------------------------------------------------------------------
// Stable counting sort by bucket (== argsort(bucket*S + pos)).
// ---------------------------------------------------------------------------
__global__ __launch_bounds__(64) void sort_kernel(const int* __restrict__ buckets,
                                                  int* __restrict__ st) {
  __shared__ int hist[64][64];   // [thread][bucket]
  __shared__ int boff[64];
  int bh = blockIdx.x;
  const int* bk = buckets + (size_t)bh * S_;
  int* stb = st + (size_t)bh * S_;
  int t = threadIdx.x;
  for (int j = 0; j < 64; j++) hist[t][j] = 0;
  __syncthreads();
  for (int i = 0; i < 64; i++) {
    int s = t * 64 + i;
    hist[t][bk[s]]++;
  }
  __syncthreads();
  int run = 0;
  for (int tt = 0; tt < 64; tt++) {
    int c = hist[tt][t];
    hist[tt][t] = run;
    run += c;
  }
  boff[t] = run;
  __syncthreads();
  if (t == 0) {
    int acc = 0;
    for (int j = 0; j < 64; j++) { int c = boff[j]; boff[j] = acc; acc += c; }
  }
  __syncthreads();
  for (int i = 0; i < 64; i++) {
    int s = t * 64 + i;
    int bkt = bk[s];
    int pos = boff[bkt] + hist[t][bkt];
    hist[t][bkt] = hist[t][bkt] + 1;
    stb[pos] = s;
  }
}

// ---------------------------------------------------------------------------
// MFMA chunked shared-QK attention (fp16x3). Reads fused qvr planes
// (pitch 1280). PV uses operand-swapped MFMA -> half4 epilogue stores.
// ---------------------------------------------------------------------------
#define KP 72
#define VP 136
__global__ __launch_bounds__(256) void attn_mfma(const _Float16* __restrict__ qvhi,
                                                 const _Float16* __restrict__ qvlo,
                                                 const int* __restrict__ st,
                                                 _Float16* __restrict__ ohi,
                                                 _Float16* __restrict__ olo) {
  __shared__ _Float16 lds[35840];   // 71680 B
  const int KH = 0, KL = 9216, VH = 18432, VL = 27136;
  int blk = blockIdx.x;
  int n = blk & (NC_ - 1);
  int bh = blk >> 6;
  int h = bh & (H_ - 1);
  int b = bh >> 3;
  const int* stbh = st + (size_t)bh * S_;
  int tid = threadIdx.x;
  int pn = (n + NC_ - 1) & (NC_ - 1);

  // ---- stage K (=Q) rows and V^T into LDS ----
  {
    int r = tid >> 1, dseg = (tid & 1) * 32;
    int si = (r < 64) ? (n * 64 + r) : (pn * 64 + (r - 64));
    int p = stbh[si];
    size_t gb = ((size_t)b * S_ + p) * 1280 + h * 64 + dseg;
    half8 kh[4], kl[4], vh8[4], vl8[4];
#pragma unroll
    for (int j = 0; j < 4; j++) {
      kh[j] = *(const half8*)&qvhi[gb + j * 8];
      kl[j] = *(const half8*)&qvlo[gb + j * 8];
      vh8[j] = *(const half8*)&qvhi[gb + 512 + j * 8];
      vl8[j] = *(const half8*)&qvlo[gb + 512 + j * 8];
    }
#pragma unroll
    for (int j = 0; j < 4; j++) {
      *(half8*)&lds[KH + r * KP + dseg + j * 8] = kh[j];
      *(half8*)&lds[KL + r * KP + dseg + j * 8] = kl[j];
    }
#pragma unroll
    for (int j = 0; j < 4; j++) {
#pragma unroll
      for (int e = 0; e < 8; e++) {
        int dim = dseg + j * 8 + e;
        lds[VH + dim * VP + r] = vh8[j][e];
        lds[VL + dim * VP + r] = vl8[j][e];
      }
    }
  }
  __syncthreads();

  int lane = tid & 63, w = tid >> 6;
  int fr = lane & 15, fk8 = (lane >> 4) * 8;
  int q4 = (lane >> 4) * 4;

  // ---- QK^T: wave w computes S[w*16..+16][0..128] ----
  int qrow = w * 16 + fr;
  half8 qh0 = *(half8*)&lds[KH + qrow * KP + fk8];
  half8 qh1 = *(half8*)&lds[KH + qrow * KP + 32 + fk8];
  half8 ql0 = *(half8*)&lds[KL + qrow * KP + fk8];
  half8 ql1 = *(half8*)&lds[KL + qrow * KP + 32 + fk8];

  f32x4 sa[8];
#pragma unroll
  for (int nc = 0; nc < 8; nc++) {
    int key = nc * 16 + fr;
    half8 bh0 = *(half8*)&lds[KH + key * KP + fk8];
    half8 bh1 = *(half8*)&lds[KH + key * KP + 32 + fk8];
    half8 bl0 = *(half8*)&lds[KL + key * KP + fk8];
    half8 bl1 = *(half8*)&lds[KL + key * KP + 32 + fk8];
    f32x4 a = (f32x4){0.f, 0.f, 0.f, 0.f};
    a = __builtin_amdgcn_mfma_f32_16x16x32_f16(qh0, bh0, a, 0, 0, 0);
    a = __builtin_amdgcn_mfma_f32_16x16x32_f16(qh1, bh1, a, 0, 0, 0);
    a = __builtin_amdgcn_mfma_f32_16x16x32_f16(ql0, bh0, a, 0, 0, 0);
    a = __builtin_amdgcn_mfma_f32_16x16x32_f16(ql1, bh1, a, 0, 0, 0);
    a = __builtin_amdgcn_mfma_f32_16x16x32_f16(qh0, bl0, a, 0, 0, 0);
    a = __builtin_amdgcn_mfma_f32_16x16x32_f16(qh1, bl1, a, 0, 0, 0);
    sa[nc] = a;
  }

  // ---- softmax over 128 keys per query row (row = (lane>>4)*4+reg) ----
  float inv[4];
#pragma unroll
  for (int reg = 0; reg < 4; reg++) {
    float m = sa[0][reg];
#pragma unroll
    for (int nc = 1; nc < 8; nc++) m = fmaxf(m, sa[nc][reg]);
    m = fmaxf(m, __shfl_xor(m, 1));
    m = fmaxf(m, __shfl_xor(m, 2));
    m = fmaxf(m, __shfl_xor(m, 4));
    m = fmaxf(m, __shfl_xor(m, 8));
    float s = 0.f;
#pragma unroll
    for (int nc = 0; nc < 8; nc++) {
      float e = expf(0.125f * (sa[nc][reg] - m));
      sa[nc][reg] = e;
      s += e;
    }
    s += __shfl_xor(s, 1);
    s += __shfl_xor(s, 2);
    s += __shfl_xor(s, 4);
    s += __shfl_xor(s, 8);
    inv[reg] = 1.0f / s;
  }

  __syncthreads();   // all waves done reading K region; safe to alias with P

  // ---- write P (= e/sum) hi/lo into per-wave LDS region ----
  int PW = w * 4352;
#pragma unroll
  for (int nc = 0; nc < 8; nc++) {
#pragma unroll
    for (int reg = 0; reg < 4; reg++) {
      float pv = sa[nc][reg] * inv[reg];
      _Float16 ph = (_Float16)pv;
      _Float16 pl = (_Float16)(pv - (float)ph);
      int prow = (lane >> 4) * 4 + reg;
      int key = nc * 16 + fr;
      lds[PW + prow * VP + key] = ph;
      lds[PW + 2176 + prow * VP + key] = pl;
    }
  }

  // ---- PV: O[16][64] per wave (operand-swapped: reg-dim = 4 consec dims) ----
  half8 ph8[4], pl8[4];
#pragma unroll
  for (int kt = 0; kt < 4; kt++) {
    ph8[kt] = *(half8*)&lds[PW + fr * VP + kt * 32 + fk8];
    pl8[kt] = *(half8*)&lds[PW + 2176 + fr * VP + kt * 32 + fk8];
  }
  f32x4 oa[4];
#pragma unroll
  for (int nco = 0; nco < 4; nco++) {
    int dim = nco * 16 + fr;
    f32x4 a = (f32x4){0.f, 0.f, 0.f, 0.f};
#pragma unroll
    for (int kt = 0; kt < 4; kt++) {
      half8 bvh = *(half8*)&lds[VH + dim * VP + kt * 32 + fk8];
      half8 bvl = *(half8*)&lds[VL + dim * VP + kt * 32 + fk8];
      a = __builtin_amdgcn_mfma_f32_16x16x32_f16(bvh, ph8[kt], a, 0, 0, 0);
      a = __builtin_amdgcn_mfma_f32_16x16x32_f16(bvh, pl8[kt], a, 0, 0, 0);
      a = __builtin_amdgcn_mfma_f32_16x16x32_f16(bvl, ph8[kt], a, 0, 0, 0);
    }
    oa[nco] = a;
  }

  // ---- epilogue: lane owns query fr, dims nco*16+q4..+3 -> half4 stores ----
  {
    int qq = w * 16 + fr;
    int p = stbh[n * 64 + qq];
    size_t ob = ((size_t)b * S_ + p) * D_ + h * 64;
#pragma unroll
    for (int nco = 0; nco < 4; nco++) {
      half4 hv, lv;
#pragma unroll
      for (int r = 0; r < 4; r++) {
        float val = oa[nco][r];
        _Float16 h16 = (_Float16)val;
        hv[r] = h16;
        lv[r] = (_Float16)(val - (float)h16);
      }
      *(half4*)&ohi[ob + nco * 16 + q4] = hv;
      *(half4*)&olo[ob + nco * 16 + q4] = lv;
    }
  }
}

// ---------------------------------------------------------------------------
extern "C" void kernel_launch(void* const* d_in, const int* in_sizes, int n_in,
                              void* d_out, int out_size, void* d_ws, size_t ws_size,
                              hipStream_t stream) {
  const int*   tokens = (const int*)d_in[0];
  const float* emb    = (const float*)d_in[1];
  const float* rot    = (const float*)d_in[2];
  const float* ln1_s  = (const float*)d_in[3];
  const float* ln1_b  = (const float*)d_in[4];
  const float* Wq     = (const float*)d_in[5];
  const float* Wv     = (const float*)d_in[6];
  const float* Wo     = (const float*)d_in[7];
  const float* ln2_s  = (const float*)d_in[8];
  const float* ln2_b  = (const float*)d_in[9];
  const float* W1     = (const float*)d_in[10];
  const float* b1     = (const float*)d_in[11];
  const float* W2     = (const float*)d_in[12];
  const float* b2     = (const float*)d_in[13];
  const float* lnf_s  = (const float*)d_in[14];
  const float* lnf_b  = (const float*)d_in[15];

  float* x = (float*)d_out;                  // residual stream lives in d_out
  const size_t RS = (size_t)B_ * S_ * D_;    // 8388608 elements
  // weight planes: WqT|WvT|rotW2T|WoT|W1T|W2T  (transposed [n][k])
  const size_t WTOT = 3 * (size_t)D_ * D_ + 2 * (size_t)D_ * M_ + 256 * 512;

  char* wsb = (char*)d_ws;
  const int rows = B_ * S_;                  // 16384
  // region: 14RS bytes, phase-aliased.
  _Float16* qvr_hi = (_Float16*)wsb;
  _Float16* qvr_lo = qvr_hi + (size_t)rows * 1280;
  _Float16* obuf_hi = (_Float16*)(wsb + 2 * (size_t)rows * 1280 * 2);
  _Float16* obuf_lo = obuf_hi + RS;
  _Float16* mid_hi = (_Float16*)wsb;                  // [rows][1024] (FFN phase)
  _Float16* mid_lo = (_Float16*)(wsb + 4 * RS);
  _Float16* hbuf_hi = (_Float16*)(wsb + 14 * RS);
  _Float16* hbuf_lo = (_Float16*)(wsb + 16 * RS);
  _Float16* whi = (_Float16*)(wsb + 18 * RS);
  _Float16* wlo = whi + WTOT;
  float* rotW2 = (float*)(wlo + WTOT);                // [512*256] f32
  int* buckets = (int*)(rotW2 + 512 * 256);
  int* stbuf   = buckets + B_ * H_ * S_;
  // total: 18RS (151.0MB) + 12.06MB + 1.6MB ~= 164.7MB

  const size_t OQ = 0;                                // WqT [512][512]
  const size_t OV = (size_t)D_ * D_;                  // WvT [512][512]
  const size_t OR = 2 * (size_t)D_ * D_;              // rotW2T [256][512]
  const size_t OO = OR + (size_t)256 * 512;           // WoT [512][512]
  const size_t O1 = OO + (size_t)D_ * D_;             // W1T [2048][512]
  const size_t O2 = O1 + (size_t)D_ * M_;             // W2T [512][2048]

  const int Mh = M_ / 2;                     // 1024

  embed_kernel<<<rows, 128, 0, stream>>>(tokens, emb, x);

  for (int l = 0; l < L_; l++) {
    transp_cvt<<<dim3(D_ / 32, D_ / 32), 256, 0, stream>>>(Wq + (size_t)l * D_ * D_, whi + OQ, wlo + OQ, D_, D_);
    transp_cvt<<<dim3(D_ / 32, D_ / 32), 256, 0, stream>>>(Wv + (size_t)l * D_ * D_, whi + OV, wlo + OV, D_, D_);
    transp_cvt<<<dim3(D_ / 32, D_ / 32), 256, 0, stream>>>(Wo + (size_t)l * D_ * D_, whi + OO, wlo + OO, D_, D_);
    transp_cvt<<<dim3(M_ / 32, D_ / 32), 256, 0, stream>>>(W1 + (size_t)l * D_ * M_, whi + O1, wlo + O1, D_, M_);
    transp_cvt<<<dim3(D_ / 32, M_ / 32), 256, 0, stream>>>(W2 + (size_t)l * M_ * D_, whi + O2, wlo + O2, M_, D_);
    rotw_kernel<<<(D_ * 256) / 256, 256, 0, stream>>>(Wq + (size_t)l * D_ * D_,
                                                      rot + (size_t)l * H_ * DH_ * 32, rotW2);
    transp_cvt<<<dim3(256 / 32, D_ / 32), 256, 0, stream>>>(rotW2, whi + OR, wlo + OR, D_, 256);

    ln_h<<<rows, 64, 0, stream>>>(x, hbuf_hi, hbuf_lo, ln1_s + (size_t)l * D_, ln1_b + (size_t)l * D_);

    // fused Q+V+hash projection: B = [WqT ; WvT ; rotW2T] (1280 rows, pitch 512)
    dim3 gqv(1280 / 128, rows / 128);
    gemm_h<0, 0, 0, 1><<<gqv, 256, 0, stream>>>(hbuf_hi, hbuf_lo, whi + OQ, wlo + OQ, nullptr,
                                                nullptr, qvr_hi, qvr_lo, rows, 1280, D_, D_, D_);

    argmax_kernel<<<(B_ * H_ * S_) / 256, 256, 0, stream>>>(qvr_hi, qvr_lo, buckets);
    sort_kernel<<<B_ * H_, 64, 0, stream>>>(buckets, stbuf);
    attn_mfma<<<B_ * H_ * NC_, 256, 0, stream>>>(qvr_hi, qvr_lo, stbuf, obuf_hi, obuf_lo);

    dim3 g1(D_ / 128, rows / 128);
    gemm_h<0, 1, 0, 0><<<g1, 256, 0, stream>>>(obuf_hi, obuf_lo, whi + OO, wlo + OO, nullptr,
                                               x, nullptr, nullptr, rows, D_, D_, D_, D_);

    ln_h<<<rows, 64, 0, stream>>>(x, hbuf_hi, hbuf_lo, ln2_s + (size_t)l * D_, ln2_b + (size_t)l * D_);

    // FFN in two 1024-column halves (mid planes sized [rows][1024])
    for (int ch = 0; ch < 2; ch++) {
      dim3 gf1(Mh / 128, rows / 128);
      gemm_h<1, 0, 1, 1><<<gf1, 256, 0, stream>>>(hbuf_hi, hbuf_lo,
                                                  whi + O1 + (size_t)ch * Mh * D_,
                                                  wlo + O1 + (size_t)ch * Mh * D_,
                                                  b1 + (size_t)l * M_ + ch * Mh,
                                                  nullptr, mid_hi, mid_lo, rows, Mh, D_, D_, D_);
      dim3 gf2(D_ / 128, rows / 128);
      if (ch == 0) {
        gemm_h<0, 1, 0, 0><<<gf2, 256, 0, stream>>>(mid_hi, mid_lo,
                                                    whi + O2,
                                                    wlo + O2,
                                                    nullptr, x, nullptr, nullptr,
                                                    rows, D_, Mh, Mh, M_);
      } else {
        gemm_h<1, 1, 0, 0><<<gf2, 256, 0, stream>>>(mid_hi, mid_lo,
                                                    whi + O2 + (size_t)ch * Mh,
                                                    wlo + O2 + (size_t)ch * Mh,
                                                    b2 + (size_t)l * D_, x, nullptr, nullptr,
                                                    rows, D_, Mh, Mh, M_);
      }
    }
  }

  ln_f<<<rows, 64, 0, stream>>>(x, x, lnf_s, lnf_b);
}